// Round 1
// baseline (1600.818 us; speedup 1.0000x reference)
//
#include <hip/hip_runtime.h>
#include <hip/hip_bf16.h>
#include <cstdint>
#include <cstddef>

#define NN 50000        // nodes
#define NE 400000       // edges (without self loops)
#define ET (NE + NN)    // edges incl self loops
#define NG 128          // graphs
#define INCH 768
#define CONDCH 768
#define HIDD 128
#define NHEAD 4
#define F1 (NHEAD * HIDD)   // 512
#define F2 HIDD             // 128

// ---------------- utility ----------------
__global__ void k_fill_u32(uint32_t* __restrict__ p, uint32_t v, int n) {
    int i = blockIdx.x * blockDim.x + threadIdx.x;
    if (i < n) p[i] = v;
}

__device__ inline unsigned f2enc(float f) {
    unsigned b = __float_as_uint(f);
    return (b & 0x80000000u) ? ~b : (b | 0x80000000u);
}
__device__ inline float enc2f(unsigned e) {
    unsigned b = (e & 0x80000000u) ? (e ^ 0x80000000u) : ~e;
    return __uint_as_float(b);
}

// ---------------- tiled f32 GEMM: C[M,N] = A[M,K] @ B[K,N] (+ gather G[gidx[m],:]) --------
// lda=K, ldb=N, N%64==0, K%16==0; M ragged.
template <bool ADD_GATHER>
__global__ __launch_bounds__(256) void k_gemm(
    const float* __restrict__ A, const float* __restrict__ B, float* __restrict__ C,
    int M, int N, int K, const float* __restrict__ G, const int* __restrict__ gidx)
{
    __shared__ float sA[16][65];
    __shared__ float sB[16][65];
    const int tid = threadIdx.x;
    const int ty = tid >> 4, tx = tid & 15;
    const int m0 = blockIdx.x * 64, n0 = blockIdx.y * 64;

    const int la_m = tid >> 2;          // 0..63
    const int la_k = (tid & 3) * 4;     // 0,4,8,12
    const int lb_k = tid >> 4;          // 0..15
    const int lb_n = (tid & 15) * 4;    // 0..60

    float acc[4][4] = {};

    for (int kt = 0; kt < K; kt += 16) {
        float4 av = make_float4(0.f, 0.f, 0.f, 0.f);
        int am = m0 + la_m;
        if (am < M) av = *(const float4*)(A + (size_t)am * K + kt + la_k);
        sA[la_k + 0][la_m] = av.x;
        sA[la_k + 1][la_m] = av.y;
        sA[la_k + 2][la_m] = av.z;
        sA[la_k + 3][la_m] = av.w;
        float4 bv = *(const float4*)(B + (size_t)(kt + lb_k) * N + n0 + lb_n);
        sB[lb_k][lb_n + 0] = bv.x;
        sB[lb_k][lb_n + 1] = bv.y;
        sB[lb_k][lb_n + 2] = bv.z;
        sB[lb_k][lb_n + 3] = bv.w;
        __syncthreads();
#pragma unroll
        for (int kk = 0; kk < 16; kk++) {
            float a[4], b[4];
#pragma unroll
            for (int i = 0; i < 4; i++) a[i] = sA[kk][ty * 4 + i];
#pragma unroll
            for (int j = 0; j < 4; j++) b[j] = sB[kk][tx * 4 + j];
#pragma unroll
            for (int i = 0; i < 4; i++)
#pragma unroll
                for (int j = 0; j < 4; j++)
                    acc[i][j] = fmaf(a[i], b[j], acc[i][j]);
        }
        __syncthreads();
    }

#pragma unroll
    for (int i = 0; i < 4; i++) {
        int m = m0 + ty * 4 + i;
        if (m >= M) continue;
        const float* grow = nullptr;
        if (ADD_GATHER) grow = G + (size_t)gidx[m] * N;
#pragma unroll
        for (int j = 0; j < 4; j++) {
            int n = n0 + tx * 4 + j;
            float v = acc[i][j];
            if (ADD_GATHER) v += grow[n];
            C[(size_t)m * N + n] = v;
        }
    }
}

// ---------------- attention logits layer1: [N,4] each --------------------
__global__ __launch_bounds__(256) void k_att1(
    const float* __restrict__ h1, const float* __restrict__ att_src,
    const float* __restrict__ att_dst, float* __restrict__ a_src, float* __restrict__ a_dst)
{
    int n = blockIdx.x;
    int head = threadIdx.x >> 6;
    int l = threadIdx.x & 63;
    const float* hrow = h1 + (size_t)n * F1 + head * HIDD;
    float v0 = hrow[l], v1 = hrow[64 + l];
    float vs = v0 * att_src[head * HIDD + l] + v1 * att_src[head * HIDD + 64 + l];
    float vd = v0 * att_dst[head * HIDD + l] + v1 * att_dst[head * HIDD + 64 + l];
    for (int off = 32; off; off >>= 1) { vs += __shfl_xor(vs, off); vd += __shfl_xor(vd, off); }
    if (l == 0) { a_src[n * NHEAD + head] = vs; a_dst[n * NHEAD + head] = vd; }
}

// ---------------- attention logits layer2 (H=1): [N] --------------------
__global__ __launch_bounds__(256) void k_att2(
    const float* __restrict__ h2, const float* __restrict__ att_src,
    const float* __restrict__ att_dst, float* __restrict__ a_src, float* __restrict__ a_dst)
{
    int n = blockIdx.x * 4 + (threadIdx.x >> 6);
    if (n >= NN) return;
    int l = threadIdx.x & 63;
    float v0 = h2[(size_t)n * F2 + l], v1 = h2[(size_t)n * F2 + 64 + l];
    float vs = v0 * att_src[l] + v1 * att_src[64 + l];
    float vd = v0 * att_dst[l] + v1 * att_dst[64 + l];
    for (int off = 32; off; off >>= 1) { vs += __shfl_xor(vs, off); vd += __shfl_xor(vd, off); }
    if (l == 0) { a_src[n] = vs; a_dst[n] = vd; }
}

// ---------------- edge pass 1: leaky-relu logit + segment max (+degree hist) -------
__global__ void k_edge_max(
    const int* __restrict__ ei, const float* __restrict__ a_src, const float* __restrict__ a_dst,
    float* __restrict__ w, unsigned* __restrict__ menc, int* __restrict__ deg, int H)
{
    int e = blockIdx.x * blockDim.x + threadIdx.x;
    if (e >= ET) return;
    int src = e < NE ? ei[e] : e - NE;
    int dst = e < NE ? ei[NE + e] : e - NE;
    for (int h = 0; h < H; h++) {
        float v = a_src[src * H + h] + a_dst[dst * H + h];
        v = v >= 0.f ? v : 0.2f * v;
        w[(size_t)e * H + h] = v;
        atomicMax(&menc[dst * H + h], f2enc(v));
    }
    if (deg) atomicAdd(&deg[dst], 1);
}

// ---------------- edge pass 2: exp + segment sum ----------------
__global__ void k_edge_expsum(
    const int* __restrict__ ei, float* __restrict__ w,
    const unsigned* __restrict__ menc, float* __restrict__ s, int H)
{
    int e = blockIdx.x * blockDim.x + threadIdx.x;
    if (e >= ET) return;
    int dst = e < NE ? ei[NE + e] : e - NE;
    for (int h = 0; h < H; h++) {
        float m = enc2f(menc[dst * H + h]);
        float wv = expf(w[(size_t)e * H + h] - m);
        w[(size_t)e * H + h] = wv;
        atomicAdd(&s[dst * H + h], wv);
    }
}

// ---------------- single-block exclusive scan over degrees ----------------
__global__ __launch_bounds__(1024) void k_scan(
    const int* __restrict__ deg, int* __restrict__ row_ptr, int* __restrict__ cursor, int n)
{
    __shared__ int tmp[1024];
    __shared__ int carry;
    if (threadIdx.x == 0) carry = 0;
    __syncthreads();
    for (int base = 0; base < n; base += 1024) {
        int i = base + threadIdx.x;
        int v = (i < n) ? deg[i] : 0;
        tmp[threadIdx.x] = v;
        __syncthreads();
        for (int off = 1; off < 1024; off <<= 1) {
            int t = (threadIdx.x >= off) ? tmp[threadIdx.x - off] : 0;
            __syncthreads();
            tmp[threadIdx.x] += t;
            __syncthreads();
        }
        int excl = tmp[threadIdx.x] - v;
        if (i < n) { row_ptr[i] = carry + excl; cursor[i] = carry + excl; }
        __syncthreads();
        if (threadIdx.x == 1023) carry += tmp[1023];
        __syncthreads();
    }
    if (threadIdx.x == 0) row_ptr[n] = carry;
}

// ---------------- scatter edge ids into CSR ----------------
__global__ void k_scatter(const int* __restrict__ ei, int* __restrict__ cursor, int* __restrict__ csr_eid)
{
    int e = blockIdx.x * blockDim.x + threadIdx.x;
    if (e >= ET) return;
    int dst = e < NE ? ei[NE + e] : e - NE;
    int pos = atomicAdd(&cursor[dst], 1);
    csr_eid[pos] = e;
}

// ---------------- aggregation layer1 (gather, fused +b1, relu) ----------------
__global__ __launch_bounds__(256) void k_agg1(
    const float* __restrict__ h1, const float* __restrict__ w, const float* __restrict__ s,
    const int* __restrict__ row_ptr, const int* __restrict__ csr_eid, const int* __restrict__ ei,
    const float* __restrict__ b1, float* __restrict__ g1)
{
    int n = blockIdx.x;
    int head = threadIdx.x >> 6;
    int l = threadIdx.x & 63;
    float inv = 1.0f / (s[n * NHEAD + head] + 1e-16f);
    float acc0 = 0.f, acc1 = 0.f;
    int beg = row_ptr[n], end = row_ptr[n + 1];
    for (int p = beg; p < end; p++) {
        int e = csr_eid[p];
        int src = e < NE ? ei[e] : e - NE;
        float c = w[(size_t)e * NHEAD + head] * inv;
        const float* hrow = h1 + (size_t)src * F1 + head * HIDD;
        acc0 = fmaf(c, hrow[l], acc0);
        acc1 = fmaf(c, hrow[64 + l], acc1);
    }
    int c0 = head * HIDD + l;
    float o0 = acc0 + b1[c0];
    float o1 = acc1 + b1[c0 + 64];
    g1[(size_t)n * F1 + c0] = o0 > 0.f ? o0 : 0.f;
    g1[(size_t)n * F1 + c0 + 64] = o1 > 0.f ? o1 : 0.f;
}

// ---------------- aggregation layer2 + final linear (fused) ----------------
__global__ __launch_bounds__(64) void k_agg2(
    const float* __restrict__ h2, const float* __restrict__ w, const float* __restrict__ s,
    const int* __restrict__ row_ptr, const int* __restrict__ csr_eid, const int* __restrict__ ei,
    const float* __restrict__ b2, const float* __restrict__ outW, const float* __restrict__ outb,
    float* __restrict__ out)
{
    int n = blockIdx.x;
    int l = threadIdx.x;
    float inv = 1.0f / (s[n] + 1e-16f);
    float acc0 = 0.f, acc1 = 0.f;
    int beg = row_ptr[n], end = row_ptr[n + 1];
    for (int p = beg; p < end; p++) {
        int e = csr_eid[p];
        int src = e < NE ? ei[e] : e - NE;
        float c = w[e] * inv;
        acc0 = fmaf(c, h2[(size_t)src * F2 + l], acc0);
        acc1 = fmaf(c, h2[(size_t)src * F2 + 64 + l], acc1);
    }
    float g0 = acc0 + b2[l];      g0 = g0 > 0.f ? g0 : 0.f;
    float g1v = acc1 + b2[64 + l]; g1v = g1v > 0.f ? g1v : 0.f;
    float p = g0 * outW[l] + g1v * outW[64 + l];
    for (int off = 32; off; off >>= 1) p += __shfl_xor(p, off);
    if (l == 0) out[n] = p + outb[0];
}

// =======================================================================
extern "C" void kernel_launch(void* const* d_in, const int* in_sizes, int n_in,
                              void* d_out, int out_size, void* d_ws, size_t ws_size,
                              hipStream_t stream)
{
    const float* x        = (const float*)d_in[0];   // [NN, INCH]
    const float* cond     = (const float*)d_in[1];   // [NG, CONDCH]
    const float* W1       = (const float*)d_in[2];   // [INCH+CONDCH, F1]
    const float* att_src1 = (const float*)d_in[3];   // [4,128]
    const float* att_dst1 = (const float*)d_in[4];
    const float* b1       = (const float*)d_in[5];   // [512]
    const float* W2       = (const float*)d_in[6];   // [512,128]
    const float* att_src2 = (const float*)d_in[7];   // [1,128]
    const float* att_dst2 = (const float*)d_in[8];
    const float* b2       = (const float*)d_in[9];   // [128]
    const float* outW     = (const float*)d_in[10];  // [128,1]
    const float* outb     = (const float*)d_in[11];  // [1]
    const int*   ei       = (const int*)d_in[12];    // [2, NE]
    const int*   batch    = (const int*)d_in[13];    // [NN]
    float* out = (float*)d_out;

    // ---- workspace layout ----
    char* ws = (char*)d_ws;
    size_t off = 0;
    auto alloc = [&](size_t bytes) { void* p = ws + off; off += (bytes + 255) & ~size_t(255); return p; };
    float*    C2      = (float*)alloc((size_t)NG * F1 * 4);       // 0.26 MB
    float*    h1      = (float*)alloc((size_t)NN * F1 * 4);       // 102.4 MB
    float*    a_src1  = (float*)alloc((size_t)NN * NHEAD * 4);
    float*    a_dst1  = (float*)alloc((size_t)NN * NHEAD * 4);
    unsigned* m1enc   = (unsigned*)alloc((size_t)NN * NHEAD * 4);
    float*    s1      = (float*)alloc((size_t)NN * NHEAD * 4);
    float*    w1      = (float*)alloc((size_t)ET * NHEAD * 4);    // 7.2 MB
    int*      deg     = (int*)alloc((size_t)NN * 4);
    int*      cursor  = (int*)alloc((size_t)NN * 4);
    int*      row_ptr = (int*)alloc((size_t)(NN + 1) * 4);
    int*      csr_eid = (int*)alloc((size_t)ET * 4);              // 1.8 MB
    float*    g1      = (float*)alloc((size_t)NN * F1 * 4);       // 102.4 MB
    float*    h2      = (float*)alloc((size_t)NN * F2 * 4);       // 25.6 MB
    float*    a_src2  = (float*)alloc((size_t)NN * 4);
    float*    a_dst2  = (float*)alloc((size_t)NN * 4);
    unsigned* m2enc   = (unsigned*)alloc((size_t)NN * 4);
    float*    s2      = (float*)alloc((size_t)NN * 4);
    float*    w2      = (float*)alloc((size_t)ET * 4);            // 1.8 MB
    (void)ws_size;  // total ~246 MB

    const unsigned ENC_NEG_INF = ~0xFF800000u;  // enc(-inf)

    // ---- init ----
    {
        int n;
        n = NN;          k_fill_u32<<<(n + 255) / 256, 256, 0, stream>>>((uint32_t*)deg, 0u, n);
        n = NN * NHEAD;  k_fill_u32<<<(n + 255) / 256, 256, 0, stream>>>((uint32_t*)m1enc, ENC_NEG_INF, n);
        n = NN * NHEAD;  k_fill_u32<<<(n + 255) / 256, 256, 0, stream>>>((uint32_t*)s1, 0u, n);
        n = NN;          k_fill_u32<<<(n + 255) / 256, 256, 0, stream>>>((uint32_t*)m2enc, ENC_NEG_INF, n);
        n = NN;          k_fill_u32<<<(n + 255) / 256, 256, 0, stream>>>((uint32_t*)s2, 0u, n);
    }

    // ---- C2 = cond @ W1[768:, :]  (tiny GEMM) ----
    {
        dim3 g((NG + 63) / 64, F1 / 64);
        k_gemm<false><<<g, 256, 0, stream>>>(cond, W1 + (size_t)INCH * F1, C2,
                                             NG, F1, CONDCH, nullptr, nullptr);
    }
    // ---- h1 = x @ W1[:768, :] + C2[batch] ----
    {
        dim3 g((NN + 63) / 64, F1 / 64);
        k_gemm<true><<<g, 256, 0, stream>>>(x, W1, h1, NN, F1, INCH, C2, batch);
    }
    // ---- attention logits layer1 ----
    k_att1<<<NN, 256, 0, stream>>>(h1, att_src1, att_dst1, a_src1, a_dst1);
    // ---- edge pass 1 (max + degree) ----
    k_edge_max<<<(ET + 255) / 256, 256, 0, stream>>>(ei, a_src1, a_dst1, w1, m1enc, deg, NHEAD);
    // ---- CSR build ----
    k_scan<<<1, 1024, 0, stream>>>(deg, row_ptr, cursor, NN);
    k_scatter<<<(ET + 255) / 256, 256, 0, stream>>>(ei, cursor, csr_eid);
    // ---- edge pass 2 (exp + sum) ----
    k_edge_expsum<<<(ET + 255) / 256, 256, 0, stream>>>(ei, w1, m1enc, s1, NHEAD);
    // ---- aggregate layer1 (+b1, relu) -> g1 ----
    k_agg1<<<NN, 256, 0, stream>>>(h1, w1, s1, row_ptr, csr_eid, ei, b1, g1);
    // ---- h2 = g1 @ W2 ----
    {
        dim3 g((NN + 63) / 64, F2 / 64);
        k_gemm<false><<<g, 256, 0, stream>>>(g1, W2, h2, NN, F2, F1, nullptr, nullptr);
    }
    // ---- attention logits layer2 ----
    k_att2<<<(NN + 3) / 4, 256, 0, stream>>>(h2, att_src2, att_dst2, a_src2, a_dst2);
    // ---- edge passes layer2 (H=1, reuse CSR) ----
    k_edge_max<<<(ET + 255) / 256, 256, 0, stream>>>(ei, a_src2, a_dst2, w2, m2enc, nullptr, 1);
    k_edge_expsum<<<(ET + 255) / 256, 256, 0, stream>>>(ei, w2, m2enc, s2, 1);
    // ---- aggregate layer2 + final linear -> out ----
    k_agg2<<<NN, 64, 0, stream>>>(h2, w2, s2, row_ptr, csr_eid, ei, b2, outW, outb, out);
}

// Round 2
// 715.141 us; speedup vs baseline: 2.2385x; 2.2385x over previous
//
#include <hip/hip_runtime.h>
#include <hip/hip_bf16.h>
#include <cstdint>
#include <cstddef>

#define NN 50000        // nodes
#define NE 400000       // edges (without self loops)
#define ET (NE + NN)    // edges incl self loops
#define NG 128          // graphs
#define INCH 768
#define CONDCH 768
#define HIDD 128
#define NHEAD 4
#define F1 (NHEAD * HIDD)   // 512
#define F2 HIDD             // 128
#define MPAD 50048          // 391 * 128

typedef unsigned short ushort_t;
typedef float f32x4 __attribute__((ext_vector_type(4)));
typedef __bf16 bf16x8 __attribute__((ext_vector_type(8)));

typedef const void __attribute__((address_space(1))) as1_void;
typedef void __attribute__((address_space(3))) as3_void;

__device__ __forceinline__ void gload_lds16(const void* g, void* l) {
    __builtin_amdgcn_global_load_lds((as1_void*)g, (as3_void*)l, 16, 0, 0);
}

__device__ __forceinline__ ushort_t f2bf(float f) {
    uint32_t u = __float_as_uint(f);
    uint32_t r = (u + 0x7fffu + ((u >> 16) & 1u)) >> 16;
    return (ushort_t)r;
}
__device__ __forceinline__ float bf2f(ushort_t h) {
    return __uint_as_float(((uint32_t)h) << 16);
}

// ---------------- utility ----------------
__global__ void k_fill_u32(uint32_t* __restrict__ p, uint32_t v, int n) {
    int i = blockIdx.x * blockDim.x + threadIdx.x;
    if (i < n) p[i] = v;
}

__device__ inline unsigned f2enc(float f) {
    unsigned b = __float_as_uint(f);
    return (b & 0x80000000u) ? ~b : (b | 0x80000000u);
}
__device__ inline float enc2f(unsigned e) {
    unsigned b = (e & 0x80000000u) ? (e ^ 0x80000000u) : ~e;
    return __uint_as_float(b);
}

// ---------------- f32 -> bf16 convert (vectorized) ----------------
__global__ __launch_bounds__(256) void k_cvt(const float* __restrict__ in,
                                             ushort_t* __restrict__ out, long n4) {
    long i = (long)blockIdx.x * blockDim.x + threadIdx.x;
    if (i >= n4) return;
    float4 v = *(const float4*)(in + i * 4);
    ushort4 o;
    o.x = f2bf(v.x); o.y = f2bf(v.y); o.z = f2bf(v.z); o.w = f2bf(v.w);
    *(ushort4*)(out + i * 4) = o;
}

// ---------------- transpose + convert: in[K][N] f32 -> out[N][K] bf16 --------
__global__ __launch_bounds__(256) void k_tcvt(const float* __restrict__ in,
                                              ushort_t* __restrict__ out, int K, int N) {
    int idx = blockIdx.x * blockDim.x + threadIdx.x;
    if (idx >= N * K) return;
    int n = idx / K, k = idx % K;
    out[idx] = f2bf(in[(size_t)k * N + n]);
}

// ---------------- bf16 MFMA GEMM: C[M,N] = A[M,K] @ BT[N,K]^T (+G[gidx[m],:]) ----
// A padded to 128-multiple rows. N%128==0, K%32==0. 128x128 tile, 4 waves (2x2).
template <bool ADD_GATHER, bool OUT_BF16>
__global__ __launch_bounds__(256) void k_mgemm(
    const ushort_t* __restrict__ A, const ushort_t* __restrict__ BT, void* __restrict__ Cv,
    int M, int N, int K, const float* __restrict__ G, const int* __restrict__ gidx)
{
    __shared__ __align__(16) char smem[16384];  // sA[128][32]bf16 + sB[128][32]bf16
    char* sA = smem;
    char* sB = smem + 8192;
    const int tid = threadIdx.x;
    const int lane = tid & 63;
    const int wave = tid >> 6;
    const int wr = wave >> 1, wc = wave & 1;
    const int m0 = blockIdx.x * 128, n0 = blockIdx.y * 128;

    // staging: thread t covers row (t>>2), k-chunk (t&3)*8 (16 bytes)
    const int sr = tid >> 2;
    const int sc = (tid & 3) * 8;
    const ushort_t* gA = A + (size_t)(m0 + sr) * K + sc;
    const ushort_t* gB = BT + (size_t)(n0 + sr) * K + sc;
    const int ldsw = wave * 1024;   // wave-uniform LDS base for issue 0

    // fragment read byte offsets (row stride = 64 B)
    const int a_off = (wr * 64 + (lane & 15)) * 64 + (lane >> 4) * 16;
    const int b_off = (wc * 64 + (lane & 15)) * 64 + (lane >> 4) * 16;

    f32x4 acc[4][4];
#pragma unroll
    for (int i = 0; i < 4; i++)
#pragma unroll
        for (int j = 0; j < 4; j++) acc[i][j] = 0.f;

    for (int kt = 0; kt < K; kt += 32) {
        gload_lds16(gA + kt,               sA + ldsw);
        gload_lds16(gA + (size_t)64 * K + kt, sA + 4096 + ldsw);
        gload_lds16(gB + kt,               sB + ldsw);
        gload_lds16(gB + (size_t)64 * K + kt, sB + 4096 + ldsw);
        __syncthreads();   // drains vmcnt before barrier
        bf16x8 af[4], bfr[4];
#pragma unroll
        for (int i = 0; i < 4; i++) af[i]  = *(const bf16x8*)(sA + a_off + i * 1024);
#pragma unroll
        for (int j = 0; j < 4; j++) bfr[j] = *(const bf16x8*)(sB + b_off + j * 1024);
#pragma unroll
        for (int i = 0; i < 4; i++)
#pragma unroll
            for (int j = 0; j < 4; j++)
                acc[i][j] = __builtin_amdgcn_mfma_f32_16x16x32_bf16(af[i], bfr[j], acc[i][j], 0, 0, 0);
        __syncthreads();
    }

#pragma unroll
    for (int i = 0; i < 4; i++) {
        int mbase = m0 + wr * 64 + i * 16 + (lane >> 4) * 4;
#pragma unroll
        for (int r = 0; r < 4; r++) {
            int m = mbase + r;
            if (m >= M) continue;
            const float* grow = nullptr;
            if (ADD_GATHER) grow = G + (size_t)gidx[m] * N;
#pragma unroll
            for (int j = 0; j < 4; j++) {
                int n = n0 + wc * 64 + j * 16 + (lane & 15);
                float v = acc[i][j][r];
                if (ADD_GATHER) v += grow[n];
                if (OUT_BF16) ((ushort_t*)Cv)[(size_t)m * N + n] = f2bf(v);
                else          ((float*)Cv)[(size_t)m * N + n] = v;
            }
        }
    }
}

// ---------------- attention logits layer1 (h1 bf16): [N,4] each ------------
__global__ __launch_bounds__(256) void k_att1(
    const ushort_t* __restrict__ h1, const float* __restrict__ att_src,
    const float* __restrict__ att_dst, float* __restrict__ a_src, float* __restrict__ a_dst)
{
    int n = blockIdx.x;
    int head = threadIdx.x >> 6;
    int l = threadIdx.x & 63;
    const ushort_t* hrow = h1 + (size_t)n * F1 + head * HIDD;
    float v0 = bf2f(hrow[l]), v1 = bf2f(hrow[64 + l]);
    float vs = v0 * att_src[head * HIDD + l] + v1 * att_src[head * HIDD + 64 + l];
    float vd = v0 * att_dst[head * HIDD + l] + v1 * att_dst[head * HIDD + 64 + l];
    for (int off = 32; off; off >>= 1) { vs += __shfl_xor(vs, off); vd += __shfl_xor(vd, off); }
    if (l == 0) { a_src[n * NHEAD + head] = vs; a_dst[n * NHEAD + head] = vd; }
}

// ---------------- attention logits layer2 (H=1, h2 f32): [N] ---------------
__global__ __launch_bounds__(256) void k_att2(
    const float* __restrict__ h2, const float* __restrict__ att_src,
    const float* __restrict__ att_dst, float* __restrict__ a_src, float* __restrict__ a_dst)
{
    int n = blockIdx.x * 4 + (threadIdx.x >> 6);
    if (n >= NN) return;
    int l = threadIdx.x & 63;
    float v0 = h2[(size_t)n * F2 + l], v1 = h2[(size_t)n * F2 + 64 + l];
    float vs = v0 * att_src[l] + v1 * att_src[64 + l];
    float vd = v0 * att_dst[l] + v1 * att_dst[64 + l];
    for (int off = 32; off; off >>= 1) { vs += __shfl_xor(vs, off); vd += __shfl_xor(vd, off); }
    if (l == 0) { a_src[n] = vs; a_dst[n] = vd; }
}

// ---------------- edge pass 1: leaky-relu logit + segment max (+degree) -----
__global__ void k_edge_max(
    const int* __restrict__ ei, const float* __restrict__ a_src, const float* __restrict__ a_dst,
    float* __restrict__ w, unsigned* __restrict__ menc, int* __restrict__ deg, int H)
{
    int e = blockIdx.x * blockDim.x + threadIdx.x;
    if (e >= ET) return;
    int src = e < NE ? ei[e] : e - NE;
    int dst = e < NE ? ei[NE + e] : e - NE;
    for (int h = 0; h < H; h++) {
        float v = a_src[src * H + h] + a_dst[dst * H + h];
        v = v >= 0.f ? v : 0.2f * v;
        w[(size_t)e * H + h] = v;
        atomicMax(&menc[dst * H + h], f2enc(v));
    }
    if (deg) atomicAdd(&deg[dst], 1);
}

// ---------------- edge pass 2: exp + segment sum ----------------
__global__ void k_edge_expsum(
    const int* __restrict__ ei, float* __restrict__ w,
    const unsigned* __restrict__ menc, float* __restrict__ s, int H)
{
    int e = blockIdx.x * blockDim.x + threadIdx.x;
    if (e >= ET) return;
    int dst = e < NE ? ei[NE + e] : e - NE;
    for (int h = 0; h < H; h++) {
        float m = enc2f(menc[dst * H + h]);
        float wv = expf(w[(size_t)e * H + h] - m);
        w[(size_t)e * H + h] = wv;
        atomicAdd(&s[dst * H + h], wv);
    }
}

// ---------------- 3-kernel block scan over degrees ----------------
#define SCB 196   // 196*256 = 50176 >= NN
__global__ __launch_bounds__(256) void k_deg_bsum(const int* __restrict__ deg, int* __restrict__ bsum) {
    int i = blockIdx.x * 256 + threadIdx.x;
    int v = (i < NN) ? deg[i] : 0;
    for (int o = 32; o; o >>= 1) v += __shfl_xor(v, o);
    __shared__ int wsum[4];
    if ((threadIdx.x & 63) == 0) wsum[threadIdx.x >> 6] = v;
    __syncthreads();
    if (threadIdx.x == 0) bsum[blockIdx.x] = wsum[0] + wsum[1] + wsum[2] + wsum[3];
}
__global__ __launch_bounds__(256) void k_bsum_scan(int* __restrict__ bsum, int* __restrict__ bbase,
                                                  int* __restrict__ row_ptr) {
    int t = threadIdx.x;
    int v = (t < SCB) ? bsum[t] : 0;
    int x = v;
    for (int o = 1; o < 64; o <<= 1) { int y = __shfl_up(x, o); if ((t & 63) >= o) x += y; }
    __shared__ int wsum[4];
    if ((t & 63) == 63) wsum[t >> 6] = x;
    __syncthreads();
    int base = 0;
    for (int w = 0; w < (t >> 6); w++) base += wsum[w];
    if (t < SCB) bbase[t] = base + x - v;    // exclusive
    if (t == 0) row_ptr[NN] = wsum[0] + wsum[1] + wsum[2] + wsum[3];
}
__global__ __launch_bounds__(256) void k_scan_final(const int* __restrict__ deg, const int* __restrict__ bbase,
                                                    int* __restrict__ row_ptr, int* __restrict__ cursor) {
    int b = blockIdx.x;
    int t = threadIdx.x;
    int i = b * 256 + t;
    int v = (i < NN) ? deg[i] : 0;
    int x = v;
    for (int o = 1; o < 64; o <<= 1) { int y = __shfl_up(x, o); if ((t & 63) >= o) x += y; }
    __shared__ int wsum[4];
    if ((t & 63) == 63) wsum[t >> 6] = x;
    __syncthreads();
    int base = bbase[b];
    for (int w = 0; w < (t >> 6); w++) base += wsum[w];
    int excl = base + x - v;
    if (i < NN) { row_ptr[i] = excl; cursor[i] = excl; }
}

// ---------------- scatter edge ids into CSR ----------------
__global__ void k_scatter(const int* __restrict__ ei, int* __restrict__ cursor, int* __restrict__ csr_eid)
{
    int e = blockIdx.x * blockDim.x + threadIdx.x;
    if (e >= ET) return;
    int dst = e < NE ? ei[NE + e] : e - NE;
    int pos = atomicAdd(&cursor[dst], 1);
    csr_eid[pos] = e;
}

// ---------------- aggregation layer1 (bf16 h1 in, bf16 g1 out, +b1, relu) ---
__global__ __launch_bounds__(256) void k_agg1(
    const ushort_t* __restrict__ h1, const float* __restrict__ w, const float* __restrict__ s,
    const int* __restrict__ row_ptr, const int* __restrict__ csr_eid, const int* __restrict__ ei,
    const float* __restrict__ b1, ushort_t* __restrict__ g1)
{
    int n = blockIdx.x;
    int head = threadIdx.x >> 6;
    int l = threadIdx.x & 63;
    float inv = 1.0f / (s[n * NHEAD + head] + 1e-16f);
    float acc0 = 0.f, acc1 = 0.f;
    int beg = row_ptr[n], end = row_ptr[n + 1];
    for (int p = beg; p < end; p++) {
        int e = csr_eid[p];
        int src = e < NE ? ei[e] : e - NE;
        float c = w[(size_t)e * NHEAD + head] * inv;
        const ushort_t* hrow = h1 + (size_t)src * F1 + head * HIDD;
        acc0 = fmaf(c, bf2f(hrow[l]), acc0);
        acc1 = fmaf(c, bf2f(hrow[64 + l]), acc1);
    }
    int c0 = head * HIDD + l;
    float o0 = acc0 + b1[c0];
    float o1 = acc1 + b1[c0 + 64];
    g1[(size_t)n * F1 + c0]      = f2bf(o0 > 0.f ? o0 : 0.f);
    g1[(size_t)n * F1 + c0 + 64] = f2bf(o1 > 0.f ? o1 : 0.f);
}

// ---------------- aggregation layer2 + final linear (fused) ----------------
__global__ __launch_bounds__(64) void k_agg2(
    const float* __restrict__ h2, const float* __restrict__ w, const float* __restrict__ s,
    const int* __restrict__ row_ptr, const int* __restrict__ csr_eid, const int* __restrict__ ei,
    const float* __restrict__ b2, const float* __restrict__ outW, const float* __restrict__ outb,
    float* __restrict__ out)
{
    int n = blockIdx.x;
    int l = threadIdx.x;
    float inv = 1.0f / (s[n] + 1e-16f);
    float acc0 = 0.f, acc1 = 0.f;
    int beg = row_ptr[n], end = row_ptr[n + 1];
    for (int p = beg; p < end; p++) {
        int e = csr_eid[p];
        int src = e < NE ? ei[e] : e - NE;
        float c = w[e] * inv;
        acc0 = fmaf(c, h2[(size_t)src * F2 + l], acc0);
        acc1 = fmaf(c, h2[(size_t)src * F2 + 64 + l], acc1);
    }
    float g0 = acc0 + b2[l];       g0 = g0 > 0.f ? g0 : 0.f;
    float g1v = acc1 + b2[64 + l]; g1v = g1v > 0.f ? g1v : 0.f;
    float p = g0 * outW[l] + g1v * outW[64 + l];
    for (int off = 32; off; off >>= 1) p += __shfl_xor(p, off);
    if (l == 0) out[n] = p + outb[0];
}

// =======================================================================
extern "C" void kernel_launch(void* const* d_in, const int* in_sizes, int n_in,
                              void* d_out, int out_size, void* d_ws, size_t ws_size,
                              hipStream_t stream)
{
    const float* x        = (const float*)d_in[0];   // [NN, INCH]
    const float* cond     = (const float*)d_in[1];   // [NG, CONDCH]
    const float* W1       = (const float*)d_in[2];   // [INCH+CONDCH, F1]
    const float* att_src1 = (const float*)d_in[3];
    const float* att_dst1 = (const float*)d_in[4];
    const float* b1       = (const float*)d_in[5];
    const float* W2       = (const float*)d_in[6];   // [F1, F2]
    const float* att_src2 = (const float*)d_in[7];
    const float* att_dst2 = (const float*)d_in[8];
    const float* b2       = (const float*)d_in[9];
    const float* outW     = (const float*)d_in[10];
    const float* outb     = (const float*)d_in[11];
    const int*   ei       = (const int*)d_in[12];    // [2, NE]
    const int*   batch    = (const int*)d_in[13];    // [NN]
    float* out = (float*)d_out;

    // ---- workspace layout ----
    char* ws = (char*)d_ws;
    size_t off = 0;
    auto alloc = [&](size_t bytes) { void* p = ws + off; off += (bytes + 255) & ~size_t(255); return p; };
    ushort_t* xb      = (ushort_t*)alloc((size_t)MPAD * INCH * 2);    // 76.9 MB
    ushort_t* condb   = (ushort_t*)alloc((size_t)NG * CONDCH * 2);
    ushort_t* W1aT    = (ushort_t*)alloc((size_t)F1 * INCH * 2);      // [512][768]
    ushort_t* W1cT    = (ushort_t*)alloc((size_t)F1 * CONDCH * 2);    // [512][768]
    ushort_t* W2T     = (ushort_t*)alloc((size_t)F2 * F1 * 2);        // [128][512]
    float*    C2      = (float*)alloc((size_t)NG * F1 * 4);           // [128][512]
    ushort_t* h1b     = (ushort_t*)alloc((size_t)NN * F1 * 2);        // 51.2 MB
    float*    a_src1  = (float*)alloc((size_t)NN * NHEAD * 4);
    float*    a_dst1  = (float*)alloc((size_t)NN * NHEAD * 4);
    unsigned* m1enc   = (unsigned*)alloc((size_t)NN * NHEAD * 4);
    float*    s1      = (float*)alloc((size_t)NN * NHEAD * 4);
    float*    w1      = (float*)alloc((size_t)ET * NHEAD * 4);        // 7.2 MB
    int*      deg     = (int*)alloc((size_t)NN * 4);
    int*      cursor  = (int*)alloc((size_t)NN * 4);
    int*      row_ptr = (int*)alloc((size_t)(NN + 1) * 4);
    int*      csr_eid = (int*)alloc((size_t)ET * 4);
    int*      bsum    = (int*)alloc((size_t)SCB * 4);
    int*      bbase   = (int*)alloc((size_t)SCB * 4);
    ushort_t* g1b     = (ushort_t*)alloc((size_t)MPAD * F1 * 2);      // 51.2 MB
    float*    h2      = (float*)alloc((size_t)NN * F2 * 4);           // 25.6 MB
    float*    a_src2  = (float*)alloc((size_t)NN * 4);
    float*    a_dst2  = (float*)alloc((size_t)NN * 4);
    unsigned* m2enc   = (unsigned*)alloc((size_t)NN * 4);
    float*    s2      = (float*)alloc((size_t)NN * 4);
    float*    w2      = (float*)alloc((size_t)ET * 4);
    (void)ws_size;

    const unsigned ENC_NEG_INF = ~0xFF800000u;

    // ---- init fills ----
    {
        int n;
        n = NN;          k_fill_u32<<<(n + 255) / 256, 256, 0, stream>>>((uint32_t*)deg, 0u, n);
        n = NN * NHEAD;  k_fill_u32<<<(n + 255) / 256, 256, 0, stream>>>((uint32_t*)m1enc, ENC_NEG_INF, n);
        n = NN * NHEAD;  k_fill_u32<<<(n + 255) / 256, 256, 0, stream>>>((uint32_t*)s1, 0u, n);
        n = NN;          k_fill_u32<<<(n + 255) / 256, 256, 0, stream>>>((uint32_t*)m2enc, ENC_NEG_INF, n);
        n = NN;          k_fill_u32<<<(n + 255) / 256, 256, 0, stream>>>((uint32_t*)s2, 0u, n);
    }

    // ---- dtype conversions ----
    {
        long n4 = (long)NN * INCH / 4;
        k_cvt<<<(int)((n4 + 255) / 256), 256, 0, stream>>>(x, xb, n4);
        n4 = (long)NG * CONDCH / 4;
        k_cvt<<<(int)((n4 + 255) / 256), 256, 0, stream>>>(cond, condb, n4);
        int ne;
        ne = F1 * INCH;   k_tcvt<<<(ne + 255) / 256, 256, 0, stream>>>(W1, W1aT, INCH, F1);
        ne = F1 * CONDCH; k_tcvt<<<(ne + 255) / 256, 256, 0, stream>>>(W1 + (size_t)INCH * F1, W1cT, CONDCH, F1);
        ne = F2 * F1;     k_tcvt<<<(ne + 255) / 256, 256, 0, stream>>>(W2, W2T, F1, F2);
    }

    // ---- C2 = cond @ W1c  -> f32 [128][512] ----
    k_mgemm<false, false><<<dim3(1, 4), 256, 0, stream>>>(condb, W1cT, C2, NG, F1, CONDCH, nullptr, nullptr);
    // ---- h1 = bf16( x @ W1a + C2[batch] ) ----
    k_mgemm<true, true><<<dim3(MPAD / 128, 4), 256, 0, stream>>>(xb, W1aT, h1b, NN, F1, INCH, C2, batch);
    // ---- attention logits layer1 ----
    k_att1<<<NN, 256, 0, stream>>>(h1b, att_src1, att_dst1, a_src1, a_dst1);
    // ---- edge pass 1 (max + degree) ----
    k_edge_max<<<(ET + 255) / 256, 256, 0, stream>>>(ei, a_src1, a_dst1, w1, m1enc, deg, NHEAD);
    // ---- CSR build (3-kernel scan + scatter) ----
    k_deg_bsum<<<SCB, 256, 0, stream>>>(deg, bsum);
    k_bsum_scan<<<1, 256, 0, stream>>>(bsum, bbase, row_ptr);
    k_scan_final<<<SCB, 256, 0, stream>>>(deg, bbase, row_ptr, cursor);
    k_scatter<<<(ET + 255) / 256, 256, 0, stream>>>(ei, cursor, csr_eid);
    // ---- edge pass 2 (exp + sum) ----
    k_edge_expsum<<<(ET + 255) / 256, 256, 0, stream>>>(ei, w1, m1enc, s1, NHEAD);
    // ---- aggregate layer1 (+b1, relu) -> g1 bf16 ----
    k_agg1<<<NN, 256, 0, stream>>>(h1b, w1, s1, row_ptr, csr_eid, ei, b1, g1b);
    // ---- h2 = g1 @ W2 -> f32 ----
    k_mgemm<false, false><<<dim3(MPAD / 128, 1), 256, 0, stream>>>(g1b, W2T, h2, NN, F2, F1, nullptr, nullptr);
    // ---- attention logits layer2 ----
    k_att2<<<(NN + 3) / 4, 256, 0, stream>>>(h2, att_src2, att_dst2, a_src2, a_dst2);
    // ---- edge passes layer2 (reuse CSR) ----
    k_edge_max<<<(ET + 255) / 256, 256, 0, stream>>>(ei, a_src2, a_dst2, w2, m2enc, nullptr, 1);
    k_edge_expsum<<<(ET + 255) / 256, 256, 0, stream>>>(ei, w2, m2enc, s2, 1);
    // ---- aggregate layer2 + final linear -> out ----
    k_agg2<<<NN, 64, 0, stream>>>(h2, w2, s2, row_ptr, csr_eid, ei, b2, outW, outb, out);
}

// Round 3
// 657.886 us; speedup vs baseline: 2.4333x; 1.0870x over previous
//
#include <hip/hip_runtime.h>
#include <hip/hip_bf16.h>
#include <cstdint>
#include <cstddef>

#define NN 50000        // nodes
#define NE 400000       // edges (without self loops)
#define ET (NE + NN)    // edges incl self loops
#define NG 128          // graphs
#define INCH 768
#define CONDCH 768
#define HIDD 128
#define NHEAD 4
#define F1 (NHEAD * HIDD)   // 512
#define F2 HIDD             // 128
#define MPAD 50048          // 391 * 128

typedef unsigned short ushort_t;
typedef float f32x4 __attribute__((ext_vector_type(4)));
typedef __bf16 bf16x8 __attribute__((ext_vector_type(8)));

typedef const void __attribute__((address_space(1))) as1_void;
typedef void __attribute__((address_space(3))) as3_void;

__device__ __forceinline__ void gload_lds16(const void* g, void* l) {
    __builtin_amdgcn_global_load_lds((as1_void*)g, (as3_void*)l, 16, 0, 0);
}

__device__ __forceinline__ ushort_t f2bf(float f) {
    uint32_t u = __float_as_uint(f);
    uint32_t r = (u + 0x7fffu + ((u >> 16) & 1u)) >> 16;
    return (ushort_t)r;
}
__device__ __forceinline__ float bf_lo(uint32_t u) { return __uint_as_float(u << 16); }
__device__ __forceinline__ float bf_hi(uint32_t u) { return __uint_as_float(u & 0xffff0000u); }

// ---------------- utility ----------------
__global__ void k_fill_u32(uint32_t* __restrict__ p, uint32_t v, int n) {
    int i = blockIdx.x * blockDim.x + threadIdx.x;
    if (i < n) p[i] = v;
}

__device__ inline unsigned f2enc(float f) {
    unsigned b = __float_as_uint(f);
    return (b & 0x80000000u) ? ~b : (b | 0x80000000u);
}
__device__ inline float enc2f(unsigned e) {
    unsigned b = (e & 0x80000000u) ? (e ^ 0x80000000u) : ~e;
    return __uint_as_float(b);
}

// ---------------- f32 -> bf16 convert (vectorized) ----------------
__global__ __launch_bounds__(256) void k_cvt(const float* __restrict__ in,
                                             ushort_t* __restrict__ out, long n4) {
    long i = (long)blockIdx.x * blockDim.x + threadIdx.x;
    if (i >= n4) return;
    float4 v = *(const float4*)(in + i * 4);
    ushort4 o;
    o.x = f2bf(v.x); o.y = f2bf(v.y); o.z = f2bf(v.z); o.w = f2bf(v.w);
    *(ushort4*)(out + i * 4) = o;
}

// ---------------- transpose + convert: in[K][N] f32 -> out[N][K] bf16 --------
__global__ __launch_bounds__(256) void k_tcvt(const float* __restrict__ in,
                                              ushort_t* __restrict__ out, int K, int N) {
    int idx = blockIdx.x * blockDim.x + threadIdx.x;
    if (idx >= N * K) return;
    int n = idx / K, k = idx % K;
    out[idx] = f2bf(in[(size_t)k * N + n]);
}

// ---------------- bf16 MFMA GEMM: C[M,N] = A[M,K] @ BT[N,K]^T (+G[gidx[m],:]) ----
// Optional fused per-row attention dots (layer1: head = blockIdx.y, needs N==512).
template <bool ADD_GATHER, bool OUT_BF16, bool FUSE_ATT>
__global__ __launch_bounds__(256) void k_mgemm(
    const ushort_t* __restrict__ A, const ushort_t* __restrict__ BT, void* __restrict__ Cv,
    int M, int N, int K, const float* __restrict__ G, const int* __restrict__ gidx,
    const float* __restrict__ attS, const float* __restrict__ attD,
    float* __restrict__ aS, float* __restrict__ aD)
{
    __shared__ __align__(16) char smem[16384];  // sA[128][32]bf16 + sB[128][32]bf16
    char* sA = smem;
    char* sB = smem + 8192;
    const int tid = threadIdx.x;
    const int lane = tid & 63;
    const int wave = tid >> 6;
    const int wr = wave >> 1, wc = wave & 1;
    const int m0 = blockIdx.x * 128, n0 = blockIdx.y * 128;

    const int sr = tid >> 2;
    const int sc = (tid & 3) * 8;
    const ushort_t* gA = A + (size_t)(m0 + sr) * K + sc;
    const ushort_t* gB = BT + (size_t)(n0 + sr) * K + sc;
    const int ldsw = wave * 1024;

    const int a_off = (wr * 64 + (lane & 15)) * 64 + (lane >> 4) * 16;
    const int b_off = (wc * 64 + (lane & 15)) * 64 + (lane >> 4) * 16;

    f32x4 acc[4][4];
#pragma unroll
    for (int i = 0; i < 4; i++)
#pragma unroll
        for (int j = 0; j < 4; j++) acc[i][j] = 0.f;

    for (int kt = 0; kt < K; kt += 32) {
        gload_lds16(gA + kt,                  sA + ldsw);
        gload_lds16(gA + (size_t)64 * K + kt, sA + 4096 + ldsw);
        gload_lds16(gB + kt,                  sB + ldsw);
        gload_lds16(gB + (size_t)64 * K + kt, sB + 4096 + ldsw);
        __syncthreads();
        bf16x8 af[4], bfr[4];
#pragma unroll
        for (int i = 0; i < 4; i++) af[i]  = *(const bf16x8*)(sA + a_off + i * 1024);
#pragma unroll
        for (int j = 0; j < 4; j++) bfr[j] = *(const bf16x8*)(sB + b_off + j * 1024);
#pragma unroll
        for (int i = 0; i < 4; i++)
#pragma unroll
            for (int j = 0; j < 4; j++)
                acc[i][j] = __builtin_amdgcn_mfma_f32_16x16x32_bf16(af[i], bfr[j], acc[i][j], 0, 0, 0);
        __syncthreads();
    }

    // att vectors per lane (layer1 fusion): column = wc*64 + j*16 + (lane&15) of this head
    float asv[4], adv[4];
    if (FUSE_ATT) {
#pragma unroll
        for (int j = 0; j < 4; j++) {
            int col = wc * 64 + j * 16 + (lane & 15);
            asv[j] = attS[blockIdx.y * 128 + col];
            adv[j] = attD[blockIdx.y * 128 + col];
        }
    }
    float* redS = (float*)smem;          // [2(wc)][128]
    float* redD = (float*)smem + 256;    // [2(wc)][128]

#pragma unroll
    for (int i = 0; i < 4; i++) {
        int mbase = m0 + wr * 64 + i * 16 + (lane >> 4) * 4;
#pragma unroll
        for (int r = 0; r < 4; r++) {
            int m = mbase + r;
            if (m >= M) continue;
            const float* grow = nullptr;
            if (ADD_GATHER) grow = G + (size_t)gidx[m] * N;
            float vs = 0.f, vd = 0.f;
#pragma unroll
            for (int j = 0; j < 4; j++) {
                int n = n0 + wc * 64 + j * 16 + (lane & 15);
                float v = acc[i][j][r];
                if (ADD_GATHER) v += grow[n];
                if (OUT_BF16) ((ushort_t*)Cv)[(size_t)m * N + n] = f2bf(v);
                else          ((float*)Cv)[(size_t)m * N + n] = v;
                if (FUSE_ATT) { vs = fmaf(v, asv[j], vs); vd = fmaf(v, adv[j], vd); }
            }
            if (FUSE_ATT) {
#pragma unroll
                for (int o = 1; o < 16; o <<= 1) { vs += __shfl_xor(vs, o); vd += __shfl_xor(vd, o); }
                if ((lane & 15) == 0) {
                    int mloc = wr * 64 + i * 16 + (lane >> 4) * 4 + r;
                    redS[wc * 128 + mloc] = vs;
                    redD[wc * 128 + mloc] = vd;
                }
            }
        }
    }
    if (FUSE_ATT) {
        __syncthreads();
        int sd = tid >> 7, mloc = tid & 127;
        int m = m0 + mloc;
        if (m < M) {
            const float* rb = sd ? redD : redS;
            float v = rb[mloc] + rb[128 + mloc];
            (sd ? aD : aS)[(size_t)m * NHEAD + blockIdx.y] = v;
        }
    }
}

// ---------------- attention logits layer2 (H=1, h2 bf16): [N] ---------------
__global__ __launch_bounds__(256) void k_att2(
    const ushort_t* __restrict__ h2, const float* __restrict__ att_src,
    const float* __restrict__ att_dst, float* __restrict__ a_src, float* __restrict__ a_dst)
{
    int n = blockIdx.x * 4 + (threadIdx.x >> 6);
    if (n >= NN) return;
    int l = threadIdx.x & 63;
    uint32_t u = *(const uint32_t*)(h2 + (size_t)n * F2 + l * 2);
    float v0 = bf_lo(u), v1 = bf_hi(u);
    float vs = v0 * att_src[l * 2] + v1 * att_src[l * 2 + 1];
    float vd = v0 * att_dst[l * 2] + v1 * att_dst[l * 2 + 1];
    for (int off = 32; off; off >>= 1) { vs += __shfl_xor(vs, off); vd += __shfl_xor(vd, off); }
    if (l == 0) { a_src[n] = vs; a_dst[n] = vd; }
}

// ---------------- edge pass 1 (H=4, vectorized): logit + segment max + degree -----
__global__ void k_edge_max4(
    const int* __restrict__ ei, const float* __restrict__ a_src, const float* __restrict__ a_dst,
    float* __restrict__ w, unsigned* __restrict__ menc, int* __restrict__ deg)
{
    int e = blockIdx.x * blockDim.x + threadIdx.x;
    if (e >= ET) return;
    int src = e < NE ? ei[e] : e - NE;
    int dst = e < NE ? ei[NE + e] : e - NE;
    float4 as = *(const float4*)(a_src + (size_t)src * 4);
    float4 ad = *(const float4*)(a_dst + (size_t)dst * 4);
    float4 v;
    v.x = as.x + ad.x; v.x = v.x >= 0.f ? v.x : 0.2f * v.x;
    v.y = as.y + ad.y; v.y = v.y >= 0.f ? v.y : 0.2f * v.y;
    v.z = as.z + ad.z; v.z = v.z >= 0.f ? v.z : 0.2f * v.z;
    v.w = as.w + ad.w; v.w = v.w >= 0.f ? v.w : 0.2f * v.w;
    *(float4*)(w + (size_t)e * 4) = v;
    atomicMax(&menc[dst * 4 + 0], f2enc(v.x));
    atomicMax(&menc[dst * 4 + 1], f2enc(v.y));
    atomicMax(&menc[dst * 4 + 2], f2enc(v.z));
    atomicMax(&menc[dst * 4 + 3], f2enc(v.w));
    atomicAdd(&deg[dst], 1);
}

// ---------------- edge pass 2 (H=4): exp + segment sum ----------------
__global__ void k_edge_expsum4(
    const int* __restrict__ ei, float* __restrict__ w,
    const unsigned* __restrict__ menc, float* __restrict__ s)
{
    int e = blockIdx.x * blockDim.x + threadIdx.x;
    if (e >= ET) return;
    int dst = e < NE ? ei[NE + e] : e - NE;
    uint4 me = *(const uint4*)(menc + (size_t)dst * 4);
    float4 wv = *(const float4*)(w + (size_t)e * 4);
    wv.x = expf(wv.x - enc2f(me.x));
    wv.y = expf(wv.y - enc2f(me.y));
    wv.z = expf(wv.z - enc2f(me.z));
    wv.w = expf(wv.w - enc2f(me.w));
    *(float4*)(w + (size_t)e * 4) = wv;
    atomicAdd(&s[dst * 4 + 0], wv.x);
    atomicAdd(&s[dst * 4 + 1], wv.y);
    atomicAdd(&s[dst * 4 + 2], wv.z);
    atomicAdd(&s[dst * 4 + 3], wv.w);
}

// ---------------- edge passes layer2 (H=1) ----------------
__global__ void k_edge_max1(
    const int* __restrict__ ei, const float* __restrict__ a_src, const float* __restrict__ a_dst,
    float* __restrict__ w, unsigned* __restrict__ menc)
{
    int e = blockIdx.x * blockDim.x + threadIdx.x;
    if (e >= ET) return;
    int src = e < NE ? ei[e] : e - NE;
    int dst = e < NE ? ei[NE + e] : e - NE;
    float v = a_src[src] + a_dst[dst];
    v = v >= 0.f ? v : 0.2f * v;
    w[e] = v;
    atomicMax(&menc[dst], f2enc(v));
}
__global__ void k_edge_expsum1(
    const int* __restrict__ ei, float* __restrict__ w,
    const unsigned* __restrict__ menc, float* __restrict__ s)
{
    int e = blockIdx.x * blockDim.x + threadIdx.x;
    if (e >= ET) return;
    int dst = e < NE ? ei[NE + e] : e - NE;
    float wv = expf(w[e] - enc2f(menc[dst]));
    w[e] = wv;
    atomicAdd(&s[dst], wv);
}

// ---------------- 3-kernel block scan over degrees ----------------
#define SCB 196   // 196*256 = 50176 >= NN
__global__ __launch_bounds__(256) void k_deg_bsum(const int* __restrict__ deg, int* __restrict__ bsum) {
    int i = blockIdx.x * 256 + threadIdx.x;
    int v = (i < NN) ? deg[i] : 0;
    for (int o = 32; o; o >>= 1) v += __shfl_xor(v, o);
    __shared__ int wsum[4];
    if ((threadIdx.x & 63) == 0) wsum[threadIdx.x >> 6] = v;
    __syncthreads();
    if (threadIdx.x == 0) bsum[blockIdx.x] = wsum[0] + wsum[1] + wsum[2] + wsum[3];
}
__global__ __launch_bounds__(256) void k_bsum_scan(int* __restrict__ bsum, int* __restrict__ bbase,
                                                  int* __restrict__ row_ptr) {
    int t = threadIdx.x;
    int v = (t < SCB) ? bsum[t] : 0;
    int x = v;
    for (int o = 1; o < 64; o <<= 1) { int y = __shfl_up(x, o); if ((t & 63) >= o) x += y; }
    __shared__ int wsum[4];
    if ((t & 63) == 63) wsum[t >> 6] = x;
    __syncthreads();
    int base = 0;
    for (int w = 0; w < (t >> 6); w++) base += wsum[w];
    if (t < SCB) bbase[t] = base + x - v;    // exclusive
    if (t == 0) row_ptr[NN] = wsum[0] + wsum[1] + wsum[2] + wsum[3];
}
__global__ __launch_bounds__(256) void k_scan_final(const int* __restrict__ deg, const int* __restrict__ bbase,
                                                    int* __restrict__ row_ptr, int* __restrict__ cursor) {
    int b = blockIdx.x;
    int t = threadIdx.x;
    int i = b * 256 + t;
    int v = (i < NN) ? deg[i] : 0;
    int x = v;
    for (int o = 1; o < 64; o <<= 1) { int y = __shfl_up(x, o); if ((t & 63) >= o) x += y; }
    __shared__ int wsum[4];
    if ((t & 63) == 63) wsum[t >> 6] = x;
    __syncthreads();
    int base = bbase[b];
    for (int w = 0; w < (t >> 6); w++) base += wsum[w];
    int excl = base + x - v;
    if (i < NN) { row_ptr[i] = excl; cursor[i] = excl; }
}

// ---------------- scatter edge ids into CSR ----------------
__global__ void k_scatter(const int* __restrict__ ei, int* __restrict__ cursor, int* __restrict__ csr_eid)
{
    int e = blockIdx.x * blockDim.x + threadIdx.x;
    if (e >= ET) return;
    int dst = e < NE ? ei[NE + e] : e - NE;
    int pos = atomicAdd(&cursor[dst], 1);
    csr_eid[pos] = e;
}

// ---------------- aggregation layer1: wave-per-edge, full-row vector loads ---
// block = 1 node, 4 waves; wave handles edges beg+wave, +4, ... Each lane loads
// 8 channels (16B). Cross-wave LDS reduce, +b1, relu, bf16 out.
__global__ __launch_bounds__(256) void k_agg1(
    const ushort_t* __restrict__ h1, const float* __restrict__ w, const float* __restrict__ s,
    const int* __restrict__ row_ptr, const int* __restrict__ csr_eid, const int* __restrict__ ei,
    const float* __restrict__ b1, ushort_t* __restrict__ g1)
{
    __shared__ float sred[4][F1];
    const int n = blockIdx.x;
    const int tid = threadIdx.x;
    const int wave = tid >> 6, lane = tid & 63;
    const int head = lane >> 4;                 // lane's 8 channels live in this head
    const float inv = 1.0f / (s[n * NHEAD + head] + 1e-16f);
    const int beg = row_ptr[n], end = row_ptr[n + 1];

    float a0 = 0.f, a1 = 0.f, a2 = 0.f, a3 = 0.f, a4 = 0.f, a5 = 0.f, a6 = 0.f, a7 = 0.f;
    for (int p = beg + wave; p < end; p += 4) {
        int e = csr_eid[p];
        int src = e < NE ? ei[e] : e - NE;
        float c = w[(size_t)e * NHEAD + head] * inv;
        uint4 u = *(const uint4*)(h1 + (size_t)src * F1 + lane * 8);
        a0 = fmaf(c, bf_lo(u.x), a0); a1 = fmaf(c, bf_hi(u.x), a1);
        a2 = fmaf(c, bf_lo(u.y), a2); a3 = fmaf(c, bf_hi(u.y), a3);
        a4 = fmaf(c, bf_lo(u.z), a4); a5 = fmaf(c, bf_hi(u.z), a5);
        a6 = fmaf(c, bf_lo(u.w), a6); a7 = fmaf(c, bf_hi(u.w), a7);
    }
    float* sw = &sred[wave][lane * 8];
    sw[0] = a0; sw[1] = a1; sw[2] = a2; sw[3] = a3;
    sw[4] = a4; sw[5] = a5; sw[6] = a6; sw[7] = a7;
    __syncthreads();
#pragma unroll
    for (int rep = 0; rep < 2; rep++) {
        int ch = tid + rep * 256;
        float v = sred[0][ch] + sred[1][ch] + sred[2][ch] + sred[3][ch] + b1[ch];
        g1[(size_t)n * F1 + ch] = f2bf(v > 0.f ? v : 0.f);
    }
}

// ---------------- aggregation layer2 + final linear (fused, bf16 h2) --------
__global__ __launch_bounds__(256) void k_agg2(
    const ushort_t* __restrict__ h2, const float* __restrict__ w, const float* __restrict__ s,
    const int* __restrict__ row_ptr, const int* __restrict__ csr_eid, const int* __restrict__ ei,
    const float* __restrict__ b2, const float* __restrict__ outW, const float* __restrict__ outb,
    float* __restrict__ out)
{
    __shared__ float sred[4][F2];
    const int n = blockIdx.x;
    const int tid = threadIdx.x;
    const int wave = tid >> 6, lane = tid & 63;
    const float inv = 1.0f / (s[n] + 1e-16f);
    const int beg = row_ptr[n], end = row_ptr[n + 1];

    float a0 = 0.f, a1 = 0.f;
    for (int p = beg + wave; p < end; p += 4) {
        int e = csr_eid[p];
        int src = e < NE ? ei[e] : e - NE;
        float c = w[e] * inv;
        uint32_t u = *(const uint32_t*)(h2 + (size_t)src * F2 + lane * 2);
        a0 = fmaf(c, bf_lo(u), a0);
        a1 = fmaf(c, bf_hi(u), a1);
    }
    sred[wave][lane * 2] = a0;
    sred[wave][lane * 2 + 1] = a1;
    __syncthreads();
    if (tid < F2) {
        float v = sred[0][tid] + sred[1][tid] + sred[2][tid] + sred[3][tid] + b2[tid];
        v = v > 0.f ? v : 0.f;
        sred[0][tid] = v * outW[tid];
    }
    __syncthreads();
    if (tid < 64) {
        float p = sred[0][tid] + sred[0][tid + 64];
        for (int off = 32; off; off >>= 1) p += __shfl_xor(p, off);
        if (tid == 0) out[n] = p + outb[0];
    }
}

// =======================================================================
extern "C" void kernel_launch(void* const* d_in, const int* in_sizes, int n_in,
                              void* d_out, int out_size, void* d_ws, size_t ws_size,
                              hipStream_t stream)
{
    const float* x        = (const float*)d_in[0];   // [NN, INCH]
    const float* cond     = (const float*)d_in[1];   // [NG, CONDCH]
    const float* W1       = (const float*)d_in[2];   // [INCH+CONDCH, F1]
    const float* att_src1 = (const float*)d_in[3];
    const float* att_dst1 = (const float*)d_in[4];
    const float* b1       = (const float*)d_in[5];
    const float* W2       = (const float*)d_in[6];   // [F1, F2]
    const float* att_src2 = (const float*)d_in[7];
    const float* att_dst2 = (const float*)d_in[8];
    const float* b2       = (const float*)d_in[9];
    const float* outW     = (const float*)d_in[10];
    const float* outb     = (const float*)d_in[11];
    const int*   ei       = (const int*)d_in[12];    // [2, NE]
    const int*   batch    = (const int*)d_in[13];    // [NN]
    float* out = (float*)d_out;

    // ---- workspace layout ----
    char* ws = (char*)d_ws;
    size_t off = 0;
    auto alloc = [&](size_t bytes) { void* p = ws + off; off += (bytes + 255) & ~size_t(255); return p; };
    ushort_t* xb      = (ushort_t*)alloc((size_t)MPAD * INCH * 2);    // 76.9 MB
    ushort_t* condb   = (ushort_t*)alloc((size_t)NG * CONDCH * 2);
    ushort_t* W1aT    = (ushort_t*)alloc((size_t)F1 * INCH * 2);      // [512][768]
    ushort_t* W1cT    = (ushort_t*)alloc((size_t)F1 * CONDCH * 2);    // [512][768]
    ushort_t* W2T     = (ushort_t*)alloc((size_t)F2 * F1 * 2);        // [128][512]
    float*    C2      = (float*)alloc((size_t)NG * F1 * 4);           // [128][512]
    ushort_t* h1b     = (ushort_t*)alloc((size_t)NN * F1 * 2);        // 51.2 MB
    float*    a_src1  = (float*)alloc((size_t)NN * NHEAD * 4);
    float*    a_dst1  = (float*)alloc((size_t)NN * NHEAD * 4);
    unsigned* m1enc   = (unsigned*)alloc((size_t)NN * NHEAD * 4);
    float*    s1      = (float*)alloc((size_t)NN * NHEAD * 4);
    float*    w1      = (float*)alloc((size_t)ET * NHEAD * 4);        // 7.2 MB
    int*      deg     = (int*)alloc((size_t)NN * 4);
    int*      cursor  = (int*)alloc((size_t)NN * 4);
    int*      row_ptr = (int*)alloc((size_t)(NN + 1) * 4);
    int*      csr_eid = (int*)alloc((size_t)ET * 4);
    int*      bsum    = (int*)alloc((size_t)SCB * 4);
    int*      bbase   = (int*)alloc((size_t)SCB * 4);
    ushort_t* g1b     = (ushort_t*)alloc((size_t)MPAD * F1 * 2);      // 51.2 MB
    ushort_t* h2b     = (ushort_t*)alloc((size_t)NN * F2 * 2);        // 12.8 MB
    float*    a_src2  = (float*)alloc((size_t)NN * 4);
    float*    a_dst2  = (float*)alloc((size_t)NN * 4);
    unsigned* m2enc   = (unsigned*)alloc((size_t)NN * 4);
    float*    s2      = (float*)alloc((size_t)NN * 4);
    float*    w2      = (float*)alloc((size_t)ET * 4);
    (void)ws_size;

    const unsigned ENC_NEG_INF = ~0xFF800000u;

    // ---- init fills ----
    {
        int n;
        n = NN;          k_fill_u32<<<(n + 255) / 256, 256, 0, stream>>>((uint32_t*)deg, 0u, n);
        n = NN * NHEAD;  k_fill_u32<<<(n + 255) / 256, 256, 0, stream>>>((uint32_t*)m1enc, ENC_NEG_INF, n);
        n = NN * NHEAD;  k_fill_u32<<<(n + 255) / 256, 256, 0, stream>>>((uint32_t*)s1, 0u, n);
        n = NN;          k_fill_u32<<<(n + 255) / 256, 256, 0, stream>>>((uint32_t*)m2enc, ENC_NEG_INF, n);
        n = NN;          k_fill_u32<<<(n + 255) / 256, 256, 0, stream>>>((uint32_t*)s2, 0u, n);
    }

    // ---- dtype conversions ----
    {
        long n4 = (long)NN * INCH / 4;
        k_cvt<<<(int)((n4 + 255) / 256), 256, 0, stream>>>(x, xb, n4);
        n4 = (long)NG * CONDCH / 4;
        k_cvt<<<(int)((n4 + 255) / 256), 256, 0, stream>>>(cond, condb, n4);
        int ne;
        ne = F1 * INCH;   k_tcvt<<<(ne + 255) / 256, 256, 0, stream>>>(W1, W1aT, INCH, F1);
        ne = F1 * CONDCH; k_tcvt<<<(ne + 255) / 256, 256, 0, stream>>>(W1 + (size_t)INCH * F1, W1cT, CONDCH, F1);
        ne = F2 * F1;     k_tcvt<<<(ne + 255) / 256, 256, 0, stream>>>(W2, W2T, F1, F2);
    }

    // ---- C2 = cond @ W1c  -> f32 [128][512] ----
    k_mgemm<false, false, false><<<dim3(1, 4), 256, 0, stream>>>(
        condb, W1cT, C2, NG, F1, CONDCH, nullptr, nullptr, nullptr, nullptr, nullptr, nullptr);
    // ---- h1 = bf16( x @ W1a + C2[batch] ), fused att1 logits ----
    k_mgemm<true, true, true><<<dim3(MPAD / 128, 4), 256, 0, stream>>>(
        xb, W1aT, h1b, NN, F1, INCH, C2, batch, att_src1, att_dst1, a_src1, a_dst1);
    // ---- edge pass 1 (max + degree) ----
    k_edge_max4<<<(ET + 255) / 256, 256, 0, stream>>>(ei, a_src1, a_dst1, w1, m1enc, deg);
    // ---- CSR build (3-kernel scan + scatter) ----
    k_deg_bsum<<<SCB, 256, 0, stream>>>(deg, bsum);
    k_bsum_scan<<<1, 256, 0, stream>>>(bsum, bbase, row_ptr);
    k_scan_final<<<SCB, 256, 0, stream>>>(deg, bbase, row_ptr, cursor);
    k_scatter<<<(ET + 255) / 256, 256, 0, stream>>>(ei, cursor, csr_eid);
    // ---- edge pass 2 (exp + sum) ----
    k_edge_expsum4<<<(ET + 255) / 256, 256, 0, stream>>>(ei, w1, m1enc, s1);
    // ---- aggregate layer1 (+b1, relu) -> g1 bf16 ----
    k_agg1<<<NN, 256, 0, stream>>>(h1b, w1, s1, row_ptr, csr_eid, ei, b1, g1b);
    // ---- h2 = bf16( g1 @ W2 ) ----
    k_mgemm<false, true, false><<<dim3(MPAD / 128, 1), 256, 0, stream>>>(
        g1b, W2T, h2b, NN, F2, F1, nullptr, nullptr, nullptr, nullptr, nullptr, nullptr);
    // ---- attention logits layer2 ----
    k_att2<<<(NN + 3) / 4, 256, 0, stream>>>(h2b, att_src2, att_dst2, a_src2, a_dst2);
    // ---- edge passes layer2 (reuse CSR) ----
    k_edge_max1<<<(ET + 255) / 256, 256, 0, stream>>>(ei, a_src2, a_dst2, w2, m2enc);
    k_edge_expsum1<<<(ET + 255) / 256, 256, 0, stream>>>(ei, w2, m2enc, s2);
    // ---- aggregate layer2 + final linear -> out ----
    k_agg2<<<NN, 256, 0, stream>>>(h2b, w2, s2, row_ptr, csr_eid, ei, b2, outW, outb, out);
}

// Round 4
// 548.117 us; speedup vs baseline: 2.9206x; 1.2003x over previous
//
#include <hip/hip_runtime.h>
#include <hip/hip_bf16.h>
#include <cstdint>
#include <cstddef>

#define NN 50000        // nodes
#define NE 400000       // edges (without self loops)
#define ET (NE + NN)    // edges incl self loops
#define NG 128          // graphs
#define INCH 768
#define CONDCH 768
#define HIDD 128
#define NHEAD 4
#define F1 (NHEAD * HIDD)   // 512
#define F2 HIDD             // 128
#define MPAD 50048          // 391 * 128

typedef unsigned short ushort_t;
typedef float f32x4 __attribute__((ext_vector_type(4)));
typedef __bf16 bf16x8 __attribute__((ext_vector_type(8)));

typedef const void __attribute__((address_space(1))) as1_void;
typedef void __attribute__((address_space(3))) as3_void;

__device__ __forceinline__ void gload_lds16(const void* g, void* l) {
    __builtin_amdgcn_global_load_lds((as1_void*)g, (as3_void*)l, 16, 0, 0);
}

__device__ __forceinline__ ushort_t f2bf(float f) {
    uint32_t u = __float_as_uint(f);
    uint32_t r = (u + 0x7fffu + ((u >> 16) & 1u)) >> 16;
    return (ushort_t)r;
}
__device__ __forceinline__ float bf_lo(uint32_t u) { return __uint_as_float(u << 16); }
__device__ __forceinline__ float bf_hi(uint32_t u) { return __uint_as_float(u & 0xffff0000u); }

__device__ inline unsigned f2enc(float f) {
    unsigned b = __float_as_uint(f);
    return (b & 0x80000000u) ? ~b : (b | 0x80000000u);
}
__device__ inline float enc2f(unsigned e) {
    unsigned b = (e & 0x80000000u) ? (e ^ 0x80000000u) : ~e;
    return __uint_as_float(b);
}

#define ENC_NEG_INF (~0xFF800000u)

// ---------------- fused init: deg=0, m1=-inf, s1=0, m2=-inf, s2=0 ----------------
__global__ __launch_bounds__(256) void k_init(int* __restrict__ deg, unsigned* __restrict__ m1,
                                              float* __restrict__ s1, unsigned* __restrict__ m2,
                                              float* __restrict__ s2) {
    int i = blockIdx.x * 256 + threadIdx.x;
    if (i < NN) { deg[i] = 0; m2[i] = ENC_NEG_INF; s2[i] = 0.f; }
    if (i < NN * NHEAD) { m1[i] = ENC_NEG_INF; s1[i] = 0.f; }
}

// ---------------- f32 -> bf16 convert (vectorized) ----------------
__global__ __launch_bounds__(256) void k_cvt(const float* __restrict__ in,
                                             ushort_t* __restrict__ out, long n4) {
    long i = (long)blockIdx.x * blockDim.x + threadIdx.x;
    if (i >= n4) return;
    float4 v = *(const float4*)(in + i * 4);
    ushort4 o;
    o.x = f2bf(v.x); o.y = f2bf(v.y); o.z = f2bf(v.z); o.w = f2bf(v.w);
    *(ushort4*)(out + i * 4) = o;
}

// ---------------- transpose + convert: in[K][N] f32 -> out[N][K] bf16 --------
__global__ __launch_bounds__(256) void k_tcvt(const float* __restrict__ in,
                                              ushort_t* __restrict__ out, int K, int N) {
    int idx = blockIdx.x * blockDim.x + threadIdx.x;
    if (idx >= N * K) return;
    int n = idx / K, k = idx % K;
    out[idx] = f2bf(in[(size_t)k * N + n]);
}

// ---------------- bf16 MFMA GEMM: C[M,N] = A[M,K] @ BT[N,K]^T (+G[gidx[m],:]) ----
// 1-D grid, XCD-chunked bijective swizzle (m204), n-fast ordering so the nBN
// column-blocks sharing an A row-panel land on the same XCD L2.
// Optional fused per-row attention dots: aS/aD[m*attStride + by].
template <bool ADD_GATHER, bool OUT_BF16, bool FUSE_ATT>
__global__ __launch_bounds__(256) void k_mgemm(
    const ushort_t* __restrict__ A, const ushort_t* __restrict__ BT, void* __restrict__ Cv,
    int M, int N, int K, int nBN,
    const float* __restrict__ G, const int* __restrict__ gidx,
    const float* __restrict__ attS, const float* __restrict__ attD,
    float* __restrict__ aS, float* __restrict__ aD, int attStride)
{
    __shared__ __align__(16) char smem[16384];  // sA[128][32]bf16 + sB[128][32]bf16
    char* sA = smem;
    char* sB = smem + 8192;

    // XCD-chunked bijective swizzle
    const int nwg = gridDim.x;
    const int orig = blockIdx.x;
    const int q = nwg >> 3, r = nwg & 7;
    const int xcd = orig & 7, sid = orig >> 3;
    const int wg = (xcd < r ? xcd * (q + 1) : r * (q + 1) + (xcd - r) * q) + sid;
    const int bx = wg / nBN, by = wg % nBN;

    const int tid = threadIdx.x;
    const int lane = tid & 63;
    const int wave = tid >> 6;
    const int wr = wave >> 1, wc = wave & 1;
    const int m0 = bx * 128, n0 = by * 128;

    const int sr = tid >> 2;
    const int sc = (tid & 3) * 8;
    const ushort_t* gA = A + (size_t)(m0 + sr) * K + sc;
    const ushort_t* gB = BT + (size_t)(n0 + sr) * K + sc;
    const int ldsw = wave * 1024;

    const int a_off = (wr * 64 + (lane & 15)) * 64 + (lane >> 4) * 16;
    const int b_off = (wc * 64 + (lane & 15)) * 64 + (lane >> 4) * 16;

    f32x4 acc[4][4];
#pragma unroll
    for (int i = 0; i < 4; i++)
#pragma unroll
        for (int j = 0; j < 4; j++) acc[i][j] = 0.f;

    for (int kt = 0; kt < K; kt += 32) {
        gload_lds16(gA + kt,                  sA + ldsw);
        gload_lds16(gA + (size_t)64 * K + kt, sA + 4096 + ldsw);
        gload_lds16(gB + kt,                  sB + ldsw);
        gload_lds16(gB + (size_t)64 * K + kt, sB + 4096 + ldsw);
        __syncthreads();
        bf16x8 af[4], bfr[4];
#pragma unroll
        for (int i = 0; i < 4; i++) af[i]  = *(const bf16x8*)(sA + a_off + i * 1024);
#pragma unroll
        for (int j = 0; j < 4; j++) bfr[j] = *(const bf16x8*)(sB + b_off + j * 1024);
#pragma unroll
        for (int i = 0; i < 4; i++)
#pragma unroll
            for (int j = 0; j < 4; j++)
                acc[i][j] = __builtin_amdgcn_mfma_f32_16x16x32_bf16(af[i], bfr[j], acc[i][j], 0, 0, 0);
        __syncthreads();
    }

    float asv[4], adv[4];
    if (FUSE_ATT) {
#pragma unroll
        for (int j = 0; j < 4; j++) {
            int col = wc * 64 + j * 16 + (lane & 15);
            asv[j] = attS[by * 128 + col];
            adv[j] = attD[by * 128 + col];
        }
    }
    float* redS = (float*)smem;          // [2(wc)][128]
    float* redD = (float*)smem + 256;

#pragma unroll
    for (int i = 0; i < 4; i++) {
        int mbase = m0 + wr * 64 + i * 16 + (lane >> 4) * 4;
#pragma unroll
        for (int rr = 0; rr < 4; rr++) {
            int m = mbase + rr;
            if (m >= M) continue;
            const float* grow = nullptr;
            if (ADD_GATHER) grow = G + (size_t)gidx[m] * N;
            float vs = 0.f, vd = 0.f;
#pragma unroll
            for (int j = 0; j < 4; j++) {
                int n = n0 + wc * 64 + j * 16 + (lane & 15);
                float v = acc[i][j][rr];
                if (ADD_GATHER) v += grow[n];
                if (OUT_BF16) ((ushort_t*)Cv)[(size_t)m * N + n] = f2bf(v);
                else          ((float*)Cv)[(size_t)m * N + n] = v;
                if (FUSE_ATT) { vs = fmaf(v, asv[j], vs); vd = fmaf(v, adv[j], vd); }
            }
            if (FUSE_ATT) {
#pragma unroll
                for (int o = 1; o < 16; o <<= 1) { vs += __shfl_xor(vs, o); vd += __shfl_xor(vd, o); }
                if ((lane & 15) == 0) {
                    int mloc = wr * 64 + i * 16 + (lane >> 4) * 4 + rr;
                    redS[wc * 128 + mloc] = vs;
                    redD[wc * 128 + mloc] = vd;
                }
            }
        }
    }
    if (FUSE_ATT) {
        __syncthreads();
        int sd = tid >> 7, mloc = tid & 127;
        int m = m0 + mloc;
        if (m < M) {
            const float* rb = sd ? redD : redS;
            float v = rb[mloc] + rb[128 + mloc];
            (sd ? aD : aS)[(size_t)m * attStride + by] = v;
        }
    }
}

// ---------------- edge pass 1 (H=4): logit + segment max + degree -----
__global__ void k_edge_max4(
    const int* __restrict__ ei, const float* __restrict__ a_src, const float* __restrict__ a_dst,
    float* __restrict__ w, unsigned* __restrict__ menc, int* __restrict__ deg)
{
    int e = blockIdx.x * blockDim.x + threadIdx.x;
    if (e >= ET) return;
    int src = e < NE ? ei[e] : e - NE;
    int dst = e < NE ? ei[NE + e] : e - NE;
    float4 as = *(const float4*)(a_src + (size_t)src * 4);
    float4 ad = *(const float4*)(a_dst + (size_t)dst * 4);
    float4 v;
    v.x = as.x + ad.x; v.x = v.x >= 0.f ? v.x : 0.2f * v.x;
    v.y = as.y + ad.y; v.y = v.y >= 0.f ? v.y : 0.2f * v.y;
    v.z = as.z + ad.z; v.z = v.z >= 0.f ? v.z : 0.2f * v.z;
    v.w = as.w + ad.w; v.w = v.w >= 0.f ? v.w : 0.2f * v.w;
    *(float4*)(w + (size_t)e * 4) = v;
    atomicMax(&menc[dst * 4 + 0], f2enc(v.x));
    atomicMax(&menc[dst * 4 + 1], f2enc(v.y));
    atomicMax(&menc[dst * 4 + 2], f2enc(v.z));
    atomicMax(&menc[dst * 4 + 3], f2enc(v.w));
    atomicAdd(&deg[dst], 1);
}

// ---------------- edge pass 2 (H=4): exp + segment sum, CSR-ordered out -------
__global__ void k_edge_expsum4(
    const int* __restrict__ ei, const float* __restrict__ w, const int* __restrict__ pos_of_e,
    const unsigned* __restrict__ menc, float* __restrict__ s, float* __restrict__ wcsr)
{
    int e = blockIdx.x * blockDim.x + threadIdx.x;
    if (e >= ET) return;
    int dst = e < NE ? ei[NE + e] : e - NE;
    int pos = pos_of_e[e];
    uint4 me = *(const uint4*)(menc + (size_t)dst * 4);
    float4 wv = *(const float4*)(w + (size_t)e * 4);
    wv.x = expf(wv.x - enc2f(me.x));
    wv.y = expf(wv.y - enc2f(me.y));
    wv.z = expf(wv.z - enc2f(me.z));
    wv.w = expf(wv.w - enc2f(me.w));
    *(float4*)(wcsr + (size_t)pos * 4) = wv;
    atomicAdd(&s[dst * 4 + 0], wv.x);
    atomicAdd(&s[dst * 4 + 1], wv.y);
    atomicAdd(&s[dst * 4 + 2], wv.z);
    atomicAdd(&s[dst * 4 + 3], wv.w);
}

// ---------------- edge passes layer2 (H=1) ----------------
__global__ void k_edge_max1(
    const int* __restrict__ ei, const float* __restrict__ a_src, const float* __restrict__ a_dst,
    float* __restrict__ w, unsigned* __restrict__ menc)
{
    int e = blockIdx.x * blockDim.x + threadIdx.x;
    if (e >= ET) return;
    int src = e < NE ? ei[e] : e - NE;
    int dst = e < NE ? ei[NE + e] : e - NE;
    float v = a_src[src] + a_dst[dst];
    v = v >= 0.f ? v : 0.2f * v;
    w[e] = v;
    atomicMax(&menc[dst], f2enc(v));
}
__global__ void k_edge_expsum1(
    const int* __restrict__ ei, const float* __restrict__ w, const int* __restrict__ pos_of_e,
    const unsigned* __restrict__ menc, float* __restrict__ s, float* __restrict__ wcsr)
{
    int e = blockIdx.x * blockDim.x + threadIdx.x;
    if (e >= ET) return;
    int dst = e < NE ? ei[NE + e] : e - NE;
    float wv = expf(w[e] - enc2f(menc[dst]));
    wcsr[pos_of_e[e]] = wv;
    atomicAdd(&s[dst], wv);
}

// ---------------- 3-kernel block scan over degrees ----------------
#define SCB 196   // 196*256 = 50176 >= NN
__global__ __launch_bounds__(256) void k_deg_bsum(const int* __restrict__ deg, int* __restrict__ bsum) {
    int i = blockIdx.x * 256 + threadIdx.x;
    int v = (i < NN) ? deg[i] : 0;
    for (int o = 32; o; o >>= 1) v += __shfl_xor(v, o);
    __shared__ int wsum[4];
    if ((threadIdx.x & 63) == 0) wsum[threadIdx.x >> 6] = v;
    __syncthreads();
    if (threadIdx.x == 0) bsum[blockIdx.x] = wsum[0] + wsum[1] + wsum[2] + wsum[3];
}
__global__ __launch_bounds__(256) void k_bsum_scan(int* __restrict__ bsum, int* __restrict__ bbase,
                                                  int* __restrict__ row_ptr) {
    int t = threadIdx.x;
    int v = (t < SCB) ? bsum[t] : 0;
    int x = v;
    for (int o = 1; o < 64; o <<= 1) { int y = __shfl_up(x, o); if ((t & 63) >= o) x += y; }
    __shared__ int wsum[4];
    if ((t & 63) == 63) wsum[t >> 6] = x;
    __syncthreads();
    int base = 0;
    for (int w = 0; w < (t >> 6); w++) base += wsum[w];
    if (t < SCB) bbase[t] = base + x - v;    // exclusive
    if (t == 0) row_ptr[NN] = wsum[0] + wsum[1] + wsum[2] + wsum[3];
}
__global__ __launch_bounds__(256) void k_scan_final(const int* __restrict__ deg, const int* __restrict__ bbase,
                                                    int* __restrict__ row_ptr, int* __restrict__ cursor) {
    int b = blockIdx.x;
    int t = threadIdx.x;
    int i = b * 256 + t;
    int v = (i < NN) ? deg[i] : 0;
    int x = v;
    for (int o = 1; o < 64; o <<= 1) { int y = __shfl_up(x, o); if ((t & 63) >= o) x += y; }
    __shared__ int wsum[4];
    if ((t & 63) == 63) wsum[t >> 6] = x;
    __syncthreads();
    int base = bbase[b];
    for (int w = 0; w < (t >> 6); w++) base += wsum[w];
    int excl = base + x - v;
    if (i < NN) { row_ptr[i] = excl; cursor[i] = excl; }
}

// ---------------- scatter: csr_src + pos_of_e ----------------
__global__ void k_scatter(const int* __restrict__ ei, int* __restrict__ cursor,
                          int* __restrict__ csr_src, int* __restrict__ pos_of_e)
{
    int e = blockIdx.x * blockDim.x + threadIdx.x;
    if (e >= ET) return;
    int src = e < NE ? ei[e] : e - NE;
    int dst = e < NE ? ei[NE + e] : e - NE;
    int pos = atomicAdd(&cursor[dst], 1);
    csr_src[pos] = src;
    pos_of_e[e] = pos;
}

// ---------------- aggregation layer1: one wave per node, CSR-ordered -------
// lane covers 8 channels (16B row load). w already CSR-ordered. 2-edge unroll.
__global__ __launch_bounds__(256) void k_agg1(
    const ushort_t* __restrict__ h1, const float* __restrict__ wc, const float* __restrict__ s,
    const int* __restrict__ row_ptr, const int* __restrict__ csr_src,
    const float* __restrict__ b1, ushort_t* __restrict__ g1)
{
    const int n = blockIdx.x * 4 + (threadIdx.x >> 6);
    const int lane = threadIdx.x & 63;
    const int head = lane >> 4;
    const float inv = 1.0f / (s[n * NHEAD + head] + 1e-16f);
    int p = row_ptr[n];
    const int end = row_ptr[n + 1];

    float a[8] = {0.f, 0.f, 0.f, 0.f, 0.f, 0.f, 0.f, 0.f};
    for (; p + 1 < end; p += 2) {
        int s0 = csr_src[p], s1v = csr_src[p + 1];
        float c0 = wc[p * 4 + head] * inv;
        float c1 = wc[(p + 1) * 4 + head] * inv;
        uint4 u0 = *(const uint4*)(h1 + (size_t)s0 * F1 + lane * 8);
        uint4 u1 = *(const uint4*)(h1 + (size_t)s1v * F1 + lane * 8);
        a[0] = fmaf(c0, bf_lo(u0.x), a[0]); a[1] = fmaf(c0, bf_hi(u0.x), a[1]);
        a[2] = fmaf(c0, bf_lo(u0.y), a[2]); a[3] = fmaf(c0, bf_hi(u0.y), a[3]);
        a[4] = fmaf(c0, bf_lo(u0.z), a[4]); a[5] = fmaf(c0, bf_hi(u0.z), a[5]);
        a[6] = fmaf(c0, bf_lo(u0.w), a[6]); a[7] = fmaf(c0, bf_hi(u0.w), a[7]);
        a[0] = fmaf(c1, bf_lo(u1.x), a[0]); a[1] = fmaf(c1, bf_hi(u1.x), a[1]);
        a[2] = fmaf(c1, bf_lo(u1.y), a[2]); a[3] = fmaf(c1, bf_hi(u1.y), a[3]);
        a[4] = fmaf(c1, bf_lo(u1.z), a[4]); a[5] = fmaf(c1, bf_hi(u1.z), a[5]);
        a[6] = fmaf(c1, bf_lo(u1.w), a[6]); a[7] = fmaf(c1, bf_hi(u1.w), a[7]);
    }
    if (p < end) {
        int s0 = csr_src[p];
        float c0 = wc[p * 4 + head] * inv;
        uint4 u0 = *(const uint4*)(h1 + (size_t)s0 * F1 + lane * 8);
        a[0] = fmaf(c0, bf_lo(u0.x), a[0]); a[1] = fmaf(c0, bf_hi(u0.x), a[1]);
        a[2] = fmaf(c0, bf_lo(u0.y), a[2]); a[3] = fmaf(c0, bf_hi(u0.y), a[3]);
        a[4] = fmaf(c0, bf_lo(u0.z), a[4]); a[5] = fmaf(c0, bf_hi(u0.z), a[5]);
        a[6] = fmaf(c0, bf_lo(u0.w), a[6]); a[7] = fmaf(c0, bf_hi(u0.w), a[7]);
    }
    const int ch = lane * 8;
    float4 bA = *(const float4*)(b1 + ch);
    float4 bB = *(const float4*)(b1 + ch + 4);
    uint4 ov;
    ov.x = (uint32_t)f2bf(fmaxf(a[0] + bA.x, 0.f)) | ((uint32_t)f2bf(fmaxf(a[1] + bA.y, 0.f)) << 16);
    ov.y = (uint32_t)f2bf(fmaxf(a[2] + bA.z, 0.f)) | ((uint32_t)f2bf(fmaxf(a[3] + bA.w, 0.f)) << 16);
    ov.z = (uint32_t)f2bf(fmaxf(a[4] + bB.x, 0.f)) | ((uint32_t)f2bf(fmaxf(a[5] + bB.y, 0.f)) << 16);
    ov.w = (uint32_t)f2bf(fmaxf(a[6] + bB.z, 0.f)) | ((uint32_t)f2bf(fmaxf(a[7] + bB.w, 0.f)) << 16);
    *(uint4*)(g1 + (size_t)n * F1 + ch) = ov;
}

// ---------------- aggregation layer2 + final linear: one wave per node ------
__global__ __launch_bounds__(256) void k_agg2(
    const ushort_t* __restrict__ h2, const float* __restrict__ wc, const float* __restrict__ s,
    const int* __restrict__ row_ptr, const int* __restrict__ csr_src,
    const float* __restrict__ b2, const float* __restrict__ outW, const float* __restrict__ outb,
    float* __restrict__ out)
{
    const int n = blockIdx.x * 4 + (threadIdx.x >> 6);
    const int lane = threadIdx.x & 63;
    const float inv = 1.0f / (s[n] + 1e-16f);
    int p = row_ptr[n];
    const int end = row_ptr[n + 1];

    float a0 = 0.f, a1 = 0.f;
    for (; p + 1 < end; p += 2) {
        int s0 = csr_src[p], s1v = csr_src[p + 1];
        float c0 = wc[p] * inv, c1 = wc[p + 1] * inv;
        uint32_t u0 = *(const uint32_t*)(h2 + (size_t)s0 * F2 + lane * 2);
        uint32_t u1 = *(const uint32_t*)(h2 + (size_t)s1v * F2 + lane * 2);
        a0 = fmaf(c0, bf_lo(u0), a0); a1 = fmaf(c0, bf_hi(u0), a1);
        a0 = fmaf(c1, bf_lo(u1), a0); a1 = fmaf(c1, bf_hi(u1), a1);
    }
    if (p < end) {
        int s0 = csr_src[p];
        float c0 = wc[p] * inv;
        uint32_t u0 = *(const uint32_t*)(h2 + (size_t)s0 * F2 + lane * 2);
        a0 = fmaf(c0, bf_lo(u0), a0); a1 = fmaf(c0, bf_hi(u0), a1);
    }
    float v0 = a0 + b2[lane * 2];     v0 = v0 > 0.f ? v0 : 0.f;
    float v1 = a1 + b2[lane * 2 + 1]; v1 = v1 > 0.f ? v1 : 0.f;
    float pr = v0 * outW[lane * 2] + v1 * outW[lane * 2 + 1];
    for (int o = 32; o; o >>= 1) pr += __shfl_xor(pr, o);
    if (lane == 0) out[n] = pr + outb[0];
}

// =======================================================================
extern "C" void kernel_launch(void* const* d_in, const int* in_sizes, int n_in,
                              void* d_out, int out_size, void* d_ws, size_t ws_size,
                              hipStream_t stream)
{
    const float* x        = (const float*)d_in[0];   // [NN, INCH]
    const float* cond     = (const float*)d_in[1];   // [NG, CONDCH]
    const float* W1       = (const float*)d_in[2];   // [INCH+CONDCH, F1]
    const float* att_src1 = (const float*)d_in[3];
    const float* att_dst1 = (const float*)d_in[4];
    const float* b1       = (const float*)d_in[5];
    const float* W2       = (const float*)d_in[6];   // [F1, F2]
    const float* att_src2 = (const float*)d_in[7];
    const float* att_dst2 = (const float*)d_in[8];
    const float* b2       = (const float*)d_in[9];
    const float* outW     = (const float*)d_in[10];
    const float* outb     = (const float*)d_in[11];
    const int*   ei       = (const int*)d_in[12];    // [2, NE]
    const int*   batch    = (const int*)d_in[13];    // [NN]
    float* out = (float*)d_out;

    // ---- workspace layout ----
    char* ws = (char*)d_ws;
    size_t off = 0;
    auto alloc = [&](size_t bytes) { void* p = ws + off; off += (bytes + 255) & ~size_t(255); return p; };
    ushort_t* xb      = (ushort_t*)alloc((size_t)MPAD * INCH * 2);    // 76.9 MB (aliased by g1b)
    ushort_t* condb   = (ushort_t*)alloc((size_t)NG * CONDCH * 2);
    ushort_t* W1aT    = (ushort_t*)alloc((size_t)F1 * INCH * 2);      // [512][768]
    ushort_t* W1cT    = (ushort_t*)alloc((size_t)F1 * CONDCH * 2);    // [512][768]
    ushort_t* W2T     = (ushort_t*)alloc((size_t)F2 * F1 * 2);        // [128][512]
    float*    C2      = (float*)alloc((size_t)NG * F1 * 4);           // [128][512]
    ushort_t* h1b     = (ushort_t*)alloc((size_t)NN * F1 * 2);        // 51.2 MB
    float*    a_src1  = (float*)alloc((size_t)NN * NHEAD * 4);
    float*    a_dst1  = (float*)alloc((size_t)NN * NHEAD * 4);
    unsigned* m1enc   = (unsigned*)alloc((size_t)NN * NHEAD * 4);
    float*    s1      = (float*)alloc((size_t)NN * NHEAD * 4);
    float*    w1      = (float*)alloc((size_t)ET * NHEAD * 4);        // 7.2 MB (raw logits)
    float*    w1c     = (float*)alloc((size_t)ET * NHEAD * 4);        // 7.2 MB (CSR-ordered exp)
    int*      deg     = (int*)alloc((size_t)NN * 4);
    int*      cursor  = (int*)alloc((size_t)NN * 4);
    int*      row_ptr = (int*)alloc((size_t)(NN + 1) * 4);
    int*      csr_src = (int*)alloc((size_t)ET * 4);
    int*      pos_of_e= (int*)alloc((size_t)ET * 4);
    int*      bsum    = (int*)alloc((size_t)SCB * 4);
    int*      bbase   = (int*)alloc((size_t)SCB * 4);
    ushort_t* h2b     = (ushort_t*)alloc((size_t)NN * F2 * 2);        // 12.8 MB
    float*    a_src2  = (float*)alloc((size_t)NN * 4);
    float*    a_dst2  = (float*)alloc((size_t)NN * 4);
    unsigned* m2enc   = (unsigned*)alloc((size_t)NN * 4);
    float*    s2      = (float*)alloc((size_t)NN * 4);
    float*    w2      = (float*)alloc((size_t)ET * 4);
    float*    w2c     = (float*)alloc((size_t)ET * 4);
    ushort_t* g1b     = xb;   // alias: xb dead after GEMM1, g1b written after
    (void)ws_size;

    // ---- fused init ----
    k_init<<<(NN * NHEAD + 255) / 256, 256, 0, stream>>>(deg, m1enc, s1, m2enc, s2);

    // ---- dtype conversions ----
    {
        long n4 = (long)NN * INCH / 4;
        k_cvt<<<(int)((n4 + 255) / 256), 256, 0, stream>>>(x, xb, n4);
        n4 = (long)NG * CONDCH / 4;
        k_cvt<<<(int)((n4 + 255) / 256), 256, 0, stream>>>(cond, condb, n4);
        int ne;
        ne = F1 * INCH;   k_tcvt<<<(ne + 255) / 256, 256, 0, stream>>>(W1, W1aT, INCH, F1);
        ne = F1 * CONDCH; k_tcvt<<<(ne + 255) / 256, 256, 0, stream>>>(W1 + (size_t)INCH * F1, W1cT, CONDCH, F1);
        ne = F2 * F1;     k_tcvt<<<(ne + 255) / 256, 256, 0, stream>>>(W2, W2T, F1, F2);
    }

    // ---- C2 = cond @ W1c  -> f32 [128][512] ----
    k_mgemm<false, false, false><<<4, 256, 0, stream>>>(
        condb, W1cT, C2, NG, F1, CONDCH, 4, nullptr, nullptr, nullptr, nullptr, nullptr, nullptr, 0);
    // ---- h1 = bf16( x @ W1a + C2[batch] ), fused att1 logits ----
    k_mgemm<true, true, true><<<(MPAD / 128) * 4, 256, 0, stream>>>(
        xb, W1aT, h1b, NN, F1, INCH, 4, C2, batch, att_src1, att_dst1, a_src1, a_dst1, NHEAD);
    // ---- edge pass 1 (max + degree) ----
    k_edge_max4<<<(ET + 255) / 256, 256, 0, stream>>>(ei, a_src1, a_dst1, w1, m1enc, deg);
    // ---- CSR build ----
    k_deg_bsum<<<SCB, 256, 0, stream>>>(deg, bsum);
    k_bsum_scan<<<1, 256, 0, stream>>>(bsum, bbase, row_ptr);
    k_scan_final<<<SCB, 256, 0, stream>>>(deg, bbase, row_ptr, cursor);
    k_scatter<<<(ET + 255) / 256, 256, 0, stream>>>(ei, cursor, csr_src, pos_of_e);
    // ---- edge pass 2 (exp + sum, CSR-ordered weights) ----
    k_edge_expsum4<<<(ET + 255) / 256, 256, 0, stream>>>(ei, w1, pos_of_e, m1enc, s1, w1c);
    // ---- aggregate layer1 (+b1, relu) -> g1 bf16 ----
    k_agg1<<<NN / 4, 256, 0, stream>>>(h1b, w1c, s1, row_ptr, csr_src, b1, g1b);
    // ---- h2 = bf16( g1 @ W2 ), fused att2 logits ----
    k_mgemm<false, true, true><<<MPAD / 128, 256, 0, stream>>>(
        g1b, W2T, h2b, NN, F2, F1, 1, nullptr, nullptr, att_src2, att_dst2, a_src2, a_dst2, 1);
    // ---- edge passes layer2 (reuse CSR) ----
    k_edge_max1<<<(ET + 255) / 256, 256, 0, stream>>>(ei, a_src2, a_dst2, w2, m2enc);
    k_edge_expsum1<<<(ET + 255) / 256, 256, 0, stream>>>(ei, w2, pos_of_e, m2enc, s2, w2c);
    // ---- aggregate layer2 + final linear -> out ----
    k_agg2<<<NN / 4, 256, 0, stream>>>(h2b, w2c, s2, row_ptr, csr_src, b2, outW, outb, out);
}

// Round 5
// 450.005 us; speedup vs baseline: 3.5573x; 1.2180x over previous
//
#include <hip/hip_runtime.h>
#include <hip/hip_bf16.h>
#include <cstdint>
#include <cstddef>

#define NN 50000        // nodes
#define NE 400000       // edges (without self loops)
#define ET (NE + NN)    // edges incl self loops
#define NG 128          // graphs
#define INCH 768
#define CONDCH 768
#define HIDD 128
#define NHEAD 4
#define F1 (NHEAD * HIDD)   // 512
#define F2 HIDD             // 128
#define MPAD 50048          // 391 * 128

typedef unsigned short ushort_t;
typedef float f32x4 __attribute__((ext_vector_type(4)));
typedef __bf16 bf16x8 __attribute__((ext_vector_type(8)));

typedef const void __attribute__((address_space(1))) as1_void;
typedef void __attribute__((address_space(3))) as3_void;

__device__ __forceinline__ void gload_lds16(const void* g, void* l) {
    __builtin_amdgcn_global_load_lds((as1_void*)g, (as3_void*)l, 16, 0, 0);
}

__device__ __forceinline__ ushort_t f2bf(float f) {
    uint32_t u = __float_as_uint(f);
    uint32_t r = (u + 0x7fffu + ((u >> 16) & 1u)) >> 16;
    return (ushort_t)r;
}
__device__ __forceinline__ ushort_t cvt_bf(float f) {   // compiler RNE cast
    __bf16 b = (__bf16)f;
    return __builtin_bit_cast(ushort_t, b);
}
__device__ __forceinline__ float bf_lo(uint32_t u) { return __uint_as_float(u << 16); }
__device__ __forceinline__ float bf_hi(uint32_t u) { return __uint_as_float(u & 0xffff0000u); }

__device__ inline unsigned f2enc(float f) {
    unsigned b = __float_as_uint(f);
    return (b & 0x80000000u) ? ~b : (b | 0x80000000u);
}
__device__ inline float enc2f(unsigned e) {
    unsigned b = (e & 0x80000000u) ? (e ^ 0x80000000u) : ~e;
    return __uint_as_float(b);
}

#define ENC_NEG_INF (~0xFF800000u)

// ---------------- fused init: deg=1 (self loop), m1=-inf, m2=-inf ----------------
__global__ __launch_bounds__(256) void k_init(int* __restrict__ deg, unsigned* __restrict__ m1,
                                              unsigned* __restrict__ m2) {
    int i = blockIdx.x * 256 + threadIdx.x;
    if (i < NN) { deg[i] = 1; m2[i] = ENC_NEG_INF; }
    if (i < NN * NHEAD) { m1[i] = ENC_NEG_INF; }
}

// ---------------- f32 -> bf16 convert (vectorized, cond only) ----------------
__global__ __launch_bounds__(256) void k_cvt(const float* __restrict__ in,
                                             ushort_t* __restrict__ out, long n4) {
    long i = (long)blockIdx.x * blockDim.x + threadIdx.x;
    if (i >= n4) return;
    float4 v = *(const float4*)(in + i * 4);
    ushort4 o;
    o.x = f2bf(v.x); o.y = f2bf(v.y); o.z = f2bf(v.z); o.w = f2bf(v.w);
    *(ushort4*)(out + i * 4) = o;
}

// ---------------- all weight transposes in one kernel --------------------------
// ranges: [0, R1): W1a  [R1, R2): W1c  [R2, R3): W2
#define R1 (F1 * INCH)
#define R2 (R1 + F1 * CONDCH)
#define R3 (R2 + F2 * F1)
__global__ __launch_bounds__(256) void k_tcvt_all(
    const float* __restrict__ W1, const float* __restrict__ W2,
    ushort_t* __restrict__ W1aT, ushort_t* __restrict__ W1cT, ushort_t* __restrict__ W2T)
{
    int idx = blockIdx.x * blockDim.x + threadIdx.x;
    if (idx >= R3) return;
    if (idx < R1) {
        int n = idx / INCH, k = idx % INCH;
        W1aT[idx] = f2bf(W1[(size_t)k * F1 + n]);
    } else if (idx < R2) {
        int j = idx - R1;
        int n = j / CONDCH, k = j % CONDCH;
        W1cT[j] = f2bf(W1[(size_t)(INCH + k) * F1 + n]);
    } else {
        int j = idx - R2;
        int n = j / F1, k = j % F1;
        W2T[j] = f2bf(W2[(size_t)k * F2 + n]);
    }
}

// ---------------- bf16 MFMA GEMM: C[M,N] = A @ BT^T (+G[gidx[m],:]) ----
// A_F32: stage A from f32 source with in-register bf16 conversion (row clamp).
// 1-D grid, XCD-chunked bijective swizzle, n-fast ordering.
// FUSE_ATT: per-row dots with attS/attD -> aS/aD[m*attStride + by].
template <bool A_F32, bool ADD_GATHER, bool OUT_BF16, bool FUSE_ATT>
__global__ __launch_bounds__(256) void k_mgemm(
    const ushort_t* __restrict__ A, const float* __restrict__ Af, int Aclamp,
    const ushort_t* __restrict__ BT, void* __restrict__ Cv,
    int M, int N, int K, int nBN,
    const float* __restrict__ G, const int* __restrict__ gidx,
    const float* __restrict__ attS, const float* __restrict__ attD,
    float* __restrict__ aS, float* __restrict__ aD, int attStride)
{
    __shared__ __align__(16) char smem[16384];  // sA[128][32]bf16 + sB[128][32]bf16
    char* sA = smem;
    char* sB = smem + 8192;

    const int nwg = gridDim.x;
    const int orig = blockIdx.x;
    const int q = nwg >> 3, r = nwg & 7;
    const int xcd = orig & 7, sid = orig >> 3;
    const int wg = (xcd < r ? xcd * (q + 1) : r * (q + 1) + (xcd - r) * q) + sid;
    const int bx = wg / nBN, by = wg % nBN;

    const int tid = threadIdx.x;
    const int lane = tid & 63;
    const int wave = tid >> 6;
    const int wr = wave >> 1, wc = wave & 1;
    const int m0 = bx * 128, n0 = by * 128;

    // B staging (always gload_lds): thread covers row tid>>2 (+64), 16B chunk (tid&3)*8
    const int sr = tid >> 2;
    const int sc = (tid & 3) * 8;
    const ushort_t* gB = BT + (size_t)(n0 + sr) * K + sc;
    const int ldsw = wave * 1024;

    // A staging
    const ushort_t* gA = nullptr;
    const float* gAf = nullptr;
    int a_lds_byte = 0;
    if (A_F32) {
        int arow = m0 + (tid >> 1);
        if (arow > Aclamp) arow = Aclamp;
        gAf = Af + (size_t)arow * K + (tid & 1) * 16;
        a_lds_byte = (tid >> 1) * 64 + (tid & 1) * 32;
    } else {
        gA = A + (size_t)(m0 + sr) * K + sc;
    }

    const int a_off = (wr * 64 + (lane & 15)) * 64 + (lane >> 4) * 16;
    const int b_off = (wc * 64 + (lane & 15)) * 64 + (lane >> 4) * 16;

    f32x4 acc[4][4];
#pragma unroll
    for (int i = 0; i < 4; i++)
#pragma unroll
        for (int j = 0; j < 4; j++) acc[i][j] = 0.f;

    for (int kt = 0; kt < K; kt += 32) {
        if (A_F32) {
            float4 v0 = *(const float4*)(gAf + kt);
            float4 v1 = *(const float4*)(gAf + kt + 4);
            float4 v2 = *(const float4*)(gAf + kt + 8);
            float4 v3 = *(const float4*)(gAf + kt + 12);
            uint4 o0, o1;
            o0.x = (uint32_t)cvt_bf(v0.x) | ((uint32_t)cvt_bf(v0.y) << 16);
            o0.y = (uint32_t)cvt_bf(v0.z) | ((uint32_t)cvt_bf(v0.w) << 16);
            o0.z = (uint32_t)cvt_bf(v1.x) | ((uint32_t)cvt_bf(v1.y) << 16);
            o0.w = (uint32_t)cvt_bf(v1.z) | ((uint32_t)cvt_bf(v1.w) << 16);
            o1.x = (uint32_t)cvt_bf(v2.x) | ((uint32_t)cvt_bf(v2.y) << 16);
            o1.y = (uint32_t)cvt_bf(v2.z) | ((uint32_t)cvt_bf(v2.w) << 16);
            o1.z = (uint32_t)cvt_bf(v3.x) | ((uint32_t)cvt_bf(v3.y) << 16);
            o1.w = (uint32_t)cvt_bf(v3.z) | ((uint32_t)cvt_bf(v3.w) << 16);
            *(uint4*)(sA + a_lds_byte) = o0;
            *(uint4*)(sA + a_lds_byte + 16) = o1;
        } else {
            gload_lds16(gA + kt,                  sA + ldsw);
            gload_lds16(gA + (size_t)64 * K + kt, sA + 4096 + ldsw);
        }
        gload_lds16(gB + kt,                  sB + ldsw);
        gload_lds16(gB + (size_t)64 * K + kt, sB + 4096 + ldsw);
        __syncthreads();
        bf16x8 af[4], bfr[4];
#pragma unroll
        for (int i = 0; i < 4; i++) af[i]  = *(const bf16x8*)(sA + a_off + i * 1024);
#pragma unroll
        for (int j = 0; j < 4; j++) bfr[j] = *(const bf16x8*)(sB + b_off + j * 1024);
#pragma unroll
        for (int i = 0; i < 4; i++)
#pragma unroll
            for (int j = 0; j < 4; j++)
                acc[i][j] = __builtin_amdgcn_mfma_f32_16x16x32_bf16(af[i], bfr[j], acc[i][j], 0, 0, 0);
        __syncthreads();
    }

    float asv[4], adv[4];
    if (FUSE_ATT) {
#pragma unroll
        for (int j = 0; j < 4; j++) {
            int col = wc * 64 + j * 16 + (lane & 15);
            asv[j] = attS[by * 128 + col];
            adv[j] = attD[by * 128 + col];
        }
    }
    float* redS = (float*)smem;          // [2(wc)][128]
    float* redD = (float*)smem + 256;

#pragma unroll
    for (int i = 0; i < 4; i++) {
        int mbase = m0 + wr * 64 + i * 16 + (lane >> 4) * 4;
#pragma unroll
        for (int rr = 0; rr < 4; rr++) {
            int m = mbase + rr;
            if (m >= M) continue;
            const float* grow = nullptr;
            if (ADD_GATHER) grow = G + (size_t)gidx[m] * N;
            float vs = 0.f, vd = 0.f;
#pragma unroll
            for (int j = 0; j < 4; j++) {
                int n = n0 + wc * 64 + j * 16 + (lane & 15);
                float v = acc[i][j][rr];
                if (ADD_GATHER) v += grow[n];
                if (OUT_BF16) ((ushort_t*)Cv)[(size_t)m * N + n] = f2bf(v);
                else          ((float*)Cv)[(size_t)m * N + n] = v;
                if (FUSE_ATT) { vs = fmaf(v, asv[j], vs); vd = fmaf(v, adv[j], vd); }
            }
            if (FUSE_ATT) {
#pragma unroll
                for (int o = 1; o < 16; o <<= 1) { vs += __shfl_xor(vs, o); vd += __shfl_xor(vd, o); }
                if ((lane & 15) == 0) {
                    int mloc = wr * 64 + i * 16 + (lane >> 4) * 4 + rr;
                    redS[wc * 128 + mloc] = vs;
                    redD[wc * 128 + mloc] = vd;
                }
            }
        }
    }
    if (FUSE_ATT) {
        __syncthreads();
        int sd = tid >> 7, mloc = tid & 127;
        int m = m0 + mloc;
        if (m < M) {
            const float* rb = sd ? redD : redS;
            float v = rb[mloc] + rb[128 + mloc];
            (sd ? aD : aS)[(size_t)m * attStride + by] = v;
        }
    }
}

// ---------------- degree count (real edges only; self-loops pre-counted) -------
__global__ void k_deg(const int* __restrict__ ei, int* __restrict__ deg)
{
    int e = blockIdx.x * blockDim.x + threadIdx.x;
    if (e >= NE) return;
    atomicAdd(&deg[ei[NE + e]], 1);
}

// ---------------- 3-kernel block scan over degrees ----------------
#define SCB 196   // 196*256 = 50176 >= NN
__global__ __launch_bounds__(256) void k_deg_bsum(const int* __restrict__ deg, int* __restrict__ bsum) {
    int i = blockIdx.x * 256 + threadIdx.x;
    int v = (i < NN) ? deg[i] : 0;
    for (int o = 32; o; o >>= 1) v += __shfl_xor(v, o);
    __shared__ int wsum[4];
    if ((threadIdx.x & 63) == 0) wsum[threadIdx.x >> 6] = v;
    __syncthreads();
    if (threadIdx.x == 0) bsum[blockIdx.x] = wsum[0] + wsum[1] + wsum[2] + wsum[3];
}
__global__ __launch_bounds__(256) void k_bsum_scan(int* __restrict__ bsum, int* __restrict__ bbase,
                                                  int* __restrict__ row_ptr) {
    int t = threadIdx.x;
    int v = (t < SCB) ? bsum[t] : 0;
    int x = v;
    for (int o = 1; o < 64; o <<= 1) { int y = __shfl_up(x, o); if ((t & 63) >= o) x += y; }
    __shared__ int wsum[4];
    if ((t & 63) == 63) wsum[t >> 6] = x;
    __syncthreads();
    int base = 0;
    for (int w = 0; w < (t >> 6); w++) base += wsum[w];
    if (t < SCB) bbase[t] = base + x - v;    // exclusive
    if (t == 0) row_ptr[NN] = wsum[0] + wsum[1] + wsum[2] + wsum[3];
}
__global__ __launch_bounds__(256) void k_scan_final(const int* __restrict__ deg, const int* __restrict__ bbase,
                                                    int* __restrict__ row_ptr, int* __restrict__ cursor) {
    int b = blockIdx.x;
    int t = threadIdx.x;
    int i = b * 256 + t;
    int v = (i < NN) ? deg[i] : 0;
    int x = v;
    for (int o = 1; o < 64; o <<= 1) { int y = __shfl_up(x, o); if ((t & 63) >= o) x += y; }
    __shared__ int wsum[4];
    if ((t & 63) == 63) wsum[t >> 6] = x;
    __syncthreads();
    int base = bbase[b];
    for (int w = 0; w < (t >> 6); w++) base += wsum[w];
    int excl = base + x - v;
    if (i < NN) { row_ptr[i] = excl; cursor[i] = excl; }
}

// ---------------- edge layer1: logit + segment max + CSR scatter ----------------
__global__ void k_maxscat4(
    const int* __restrict__ ei, const float* __restrict__ a_src, const float* __restrict__ a_dst,
    unsigned* __restrict__ menc, int* __restrict__ cursor,
    int* __restrict__ csr_src, int* __restrict__ pos_of_e, float* __restrict__ wcsr)
{
    int e = blockIdx.x * blockDim.x + threadIdx.x;
    if (e >= ET) return;
    int src = e < NE ? ei[e] : e - NE;
    int dst = e < NE ? ei[NE + e] : e - NE;
    float4 as = *(const float4*)(a_src + (size_t)src * 4);
    float4 ad = *(const float4*)(a_dst + (size_t)dst * 4);
    float4 v;
    v.x = as.x + ad.x; v.x = v.x >= 0.f ? v.x : 0.2f * v.x;
    v.y = as.y + ad.y; v.y = v.y >= 0.f ? v.y : 0.2f * v.y;
    v.z = as.z + ad.z; v.z = v.z >= 0.f ? v.z : 0.2f * v.z;
    v.w = as.w + ad.w; v.w = v.w >= 0.f ? v.w : 0.2f * v.w;
    atomicMax(&menc[dst * 4 + 0], f2enc(v.x));
    atomicMax(&menc[dst * 4 + 1], f2enc(v.y));
    atomicMax(&menc[dst * 4 + 2], f2enc(v.z));
    atomicMax(&menc[dst * 4 + 3], f2enc(v.w));
    int pos = atomicAdd(&cursor[dst], 1);
    csr_src[pos] = src;
    pos_of_e[e] = pos;
    *(float4*)(wcsr + (size_t)pos * 4) = v;
}

// ---------------- edge layer2: logit + segment max, CSR-ordered write ----------
__global__ void k_max1w(
    const int* __restrict__ ei, const float* __restrict__ a_src, const float* __restrict__ a_dst,
    const int* __restrict__ pos_of_e, unsigned* __restrict__ menc, float* __restrict__ wcsr)
{
    int e = blockIdx.x * blockDim.x + threadIdx.x;
    if (e >= ET) return;
    int src = e < NE ? ei[e] : e - NE;
    int dst = e < NE ? ei[NE + e] : e - NE;
    float v = a_src[src] + a_dst[dst];
    v = v >= 0.f ? v : 0.2f * v;
    atomicMax(&menc[dst], f2enc(v));
    wcsr[pos_of_e[e]] = v;
}

// ---------------- aggregation layer1: one wave per node, inline exp + ssum ------
__global__ __launch_bounds__(256) void k_agg1(
    const ushort_t* __restrict__ h1, const float* __restrict__ wc, const unsigned* __restrict__ menc,
    const int* __restrict__ row_ptr, const int* __restrict__ csr_src,
    const float* __restrict__ b1, ushort_t* __restrict__ g1)
{
    const int n = blockIdx.x * 4 + (threadIdx.x >> 6);
    const int lane = threadIdx.x & 63;
    const int head = lane >> 4;
    const float m = enc2f(menc[n * NHEAD + head]);
    int p = row_ptr[n];
    const int end = row_ptr[n + 1];

    float ssum = 0.f;
    float a[8] = {0.f, 0.f, 0.f, 0.f, 0.f, 0.f, 0.f, 0.f};
    for (; p + 1 < end; p += 2) {
        int s0 = csr_src[p], s1v = csr_src[p + 1];
        float c0 = expf(wc[p * 4 + head] - m);
        float c1 = expf(wc[(p + 1) * 4 + head] - m);
        uint4 u0 = *(const uint4*)(h1 + (size_t)s0 * F1 + lane * 8);
        uint4 u1 = *(const uint4*)(h1 + (size_t)s1v * F1 + lane * 8);
        ssum += c0 + c1;
        a[0] = fmaf(c0, bf_lo(u0.x), a[0]); a[1] = fmaf(c0, bf_hi(u0.x), a[1]);
        a[2] = fmaf(c0, bf_lo(u0.y), a[2]); a[3] = fmaf(c0, bf_hi(u0.y), a[3]);
        a[4] = fmaf(c0, bf_lo(u0.z), a[4]); a[5] = fmaf(c0, bf_hi(u0.z), a[5]);
        a[6] = fmaf(c0, bf_lo(u0.w), a[6]); a[7] = fmaf(c0, bf_hi(u0.w), a[7]);
        a[0] = fmaf(c1, bf_lo(u1.x), a[0]); a[1] = fmaf(c1, bf_hi(u1.x), a[1]);
        a[2] = fmaf(c1, bf_lo(u1.y), a[2]); a[3] = fmaf(c1, bf_hi(u1.y), a[3]);
        a[4] = fmaf(c1, bf_lo(u1.z), a[4]); a[5] = fmaf(c1, bf_hi(u1.z), a[5]);
        a[6] = fmaf(c1, bf_lo(u1.w), a[6]); a[7] = fmaf(c1, bf_hi(u1.w), a[7]);
    }
    if (p < end) {
        int s0 = csr_src[p];
        float c0 = expf(wc[p * 4 + head] - m);
        uint4 u0 = *(const uint4*)(h1 + (size_t)s0 * F1 + lane * 8);
        ssum += c0;
        a[0] = fmaf(c0, bf_lo(u0.x), a[0]); a[1] = fmaf(c0, bf_hi(u0.x), a[1]);
        a[2] = fmaf(c0, bf_lo(u0.y), a[2]); a[3] = fmaf(c0, bf_hi(u0.y), a[3]);
        a[4] = fmaf(c0, bf_lo(u0.z), a[4]); a[5] = fmaf(c0, bf_hi(u0.z), a[5]);
        a[6] = fmaf(c0, bf_lo(u0.w), a[6]); a[7] = fmaf(c0, bf_hi(u0.w), a[7]);
    }
    const float inv = 1.0f / (ssum + 1e-16f);
    const int ch = lane * 8;
    float4 bA = *(const float4*)(b1 + ch);
    float4 bB = *(const float4*)(b1 + ch + 4);
    uint4 ov;
    ov.x = (uint32_t)f2bf(fmaxf(fmaf(a[0], inv, bA.x), 0.f)) | ((uint32_t)f2bf(fmaxf(fmaf(a[1], inv, bA.y), 0.f)) << 16);
    ov.y = (uint32_t)f2bf(fmaxf(fmaf(a[2], inv, bA.z), 0.f)) | ((uint32_t)f2bf(fmaxf(fmaf(a[3], inv, bA.w), 0.f)) << 16);
    ov.z = (uint32_t)f2bf(fmaxf(fmaf(a[4], inv, bB.x), 0.f)) | ((uint32_t)f2bf(fmaxf(fmaf(a[5], inv, bB.y), 0.f)) << 16);
    ov.w = (uint32_t)f2bf(fmaxf(fmaf(a[6], inv, bB.z), 0.f)) | ((uint32_t)f2bf(fmaxf(fmaf(a[7], inv, bB.w), 0.f)) << 16);
    *(uint4*)(g1 + (size_t)n * F1 + ch) = ov;
}

// ---------------- aggregation layer2 + final linear: one wave per node ------
__global__ __launch_bounds__(256) void k_agg2(
    const ushort_t* __restrict__ h2, const float* __restrict__ wc, const unsigned* __restrict__ menc,
    const int* __restrict__ row_ptr, const int* __restrict__ csr_src,
    const float* __restrict__ b2, const float* __restrict__ outW, const float* __restrict__ outb,
    float* __restrict__ out)
{
    const int n = blockIdx.x * 4 + (threadIdx.x >> 6);
    const int lane = threadIdx.x & 63;
    const float m = enc2f(menc[n]);
    int p = row_ptr[n];
    const int end = row_ptr[n + 1];

    float ssum = 0.f;
    float a0 = 0.f, a1 = 0.f;
    for (; p + 1 < end; p += 2) {
        int s0 = csr_src[p], s1v = csr_src[p + 1];
        float c0 = expf(wc[p] - m), c1 = expf(wc[p + 1] - m);
        uint32_t u0 = *(const uint32_t*)(h2 + (size_t)s0 * F2 + lane * 2);
        uint32_t u1 = *(const uint32_t*)(h2 + (size_t)s1v * F2 + lane * 2);
        ssum += c0 + c1;
        a0 = fmaf(c0, bf_lo(u0), a0); a1 = fmaf(c0, bf_hi(u0), a1);
        a0 = fmaf(c1, bf_lo(u1), a0); a1 = fmaf(c1, bf_hi(u1), a1);
    }
    if (p < end) {
        int s0 = csr_src[p];
        float c0 = expf(wc[p] - m);
        uint32_t u0 = *(const uint32_t*)(h2 + (size_t)s0 * F2 + lane * 2);
        ssum += c0;
        a0 = fmaf(c0, bf_lo(u0), a0); a1 = fmaf(c0, bf_hi(u0), a1);
    }
    const float inv = 1.0f / (ssum + 1e-16f);
    float v0 = fmaf(a0, inv, b2[lane * 2]);     v0 = v0 > 0.f ? v0 : 0.f;
    float v1 = fmaf(a1, inv, b2[lane * 2 + 1]); v1 = v1 > 0.f ? v1 : 0.f;
    float pr = v0 * outW[lane * 2] + v1 * outW[lane * 2 + 1];
    for (int o = 32; o; o >>= 1) pr += __shfl_xor(pr, o);
    if (lane == 0) out[n] = pr + outb[0];
}

// =======================================================================
extern "C" void kernel_launch(void* const* d_in, const int* in_sizes, int n_in,
                              void* d_out, int out_size, void* d_ws, size_t ws_size,
                              hipStream_t stream)
{
    const float* x        = (const float*)d_in[0];   // [NN, INCH]
    const float* cond     = (const float*)d_in[1];   // [NG, CONDCH]
    const float* W1       = (const float*)d_in[2];   // [INCH+CONDCH, F1]
    const float* att_src1 = (const float*)d_in[3];
    const float* att_dst1 = (const float*)d_in[4];
    const float* b1       = (const float*)d_in[5];
    const float* W2       = (const float*)d_in[6];   // [F1, F2]
    const float* att_src2 = (const float*)d_in[7];
    const float* att_dst2 = (const float*)d_in[8];
    const float* b2       = (const float*)d_in[9];
    const float* outW     = (const float*)d_in[10];
    const float* outb     = (const float*)d_in[11];
    const int*   ei       = (const int*)d_in[12];    // [2, NE]
    const int*   batch    = (const int*)d_in[13];    // [NN]
    float* out = (float*)d_out;

    // ---- workspace layout ----
    char* ws = (char*)d_ws;
    size_t off = 0;
    auto alloc = [&](size_t bytes) { void* p = ws + off; off += (bytes + 255) & ~size_t(255); return p; };
    ushort_t* condb   = (ushort_t*)alloc((size_t)NG * CONDCH * 2);
    ushort_t* W1aT    = (ushort_t*)alloc((size_t)F1 * INCH * 2);      // [512][768]
    ushort_t* W1cT    = (ushort_t*)alloc((size_t)F1 * CONDCH * 2);    // [512][768]
    ushort_t* W2T     = (ushort_t*)alloc((size_t)F2 * F1 * 2);        // [128][512]
    float*    C2      = (float*)alloc((size_t)NG * F1 * 4);           // [128][512]
    ushort_t* h1b     = (ushort_t*)alloc((size_t)NN * F1 * 2);        // 51.2 MB
    float*    a_src1  = (float*)alloc((size_t)NN * NHEAD * 4);
    float*    a_dst1  = (float*)alloc((size_t)NN * NHEAD * 4);
    unsigned* m1enc   = (unsigned*)alloc((size_t)NN * NHEAD * 4);
    float*    w1c     = (float*)alloc((size_t)ET * NHEAD * 4);        // 7.2 MB (CSR-ordered logits)
    int*      deg     = (int*)alloc((size_t)NN * 4);
    int*      cursor  = (int*)alloc((size_t)NN * 4);
    int*      row_ptr = (int*)alloc((size_t)(NN + 1) * 4);
    int*      csr_src = (int*)alloc((size_t)ET * 4);
    int*      pos_of_e= (int*)alloc((size_t)ET * 4);
    int*      bsum    = (int*)alloc((size_t)SCB * 4);
    int*      bbase   = (int*)alloc((size_t)SCB * 4);
    ushort_t* g1b     = (ushort_t*)alloc((size_t)MPAD * F1 * 2);      // 51.2 MB
    ushort_t* h2b     = (ushort_t*)alloc((size_t)NN * F2 * 2);        // 12.8 MB
    float*    a_src2  = (float*)alloc((size_t)NN * 4);
    float*    a_dst2  = (float*)alloc((size_t)NN * 4);
    unsigned* m2enc   = (unsigned*)alloc((size_t)NN * 4);
    float*    w2c     = (float*)alloc((size_t)ET * 4);
    (void)ws_size;

    // ---- fused init (deg=1 pre-counts self loops) ----
    k_init<<<(NN * NHEAD + 255) / 256, 256, 0, stream>>>(deg, m1enc, m2enc);

    // ---- conversions ----
    {
        long n4 = (long)NG * CONDCH / 4;
        k_cvt<<<(int)((n4 + 255) / 256), 256, 0, stream>>>(cond, condb, n4);
        k_tcvt_all<<<(R3 + 255) / 256, 256, 0, stream>>>(W1, W2, W1aT, W1cT, W2T);
    }

    // ---- degree + CSR skeleton (independent of GEMM) ----
    k_deg<<<(NE + 255) / 256, 256, 0, stream>>>(ei, deg);
    k_deg_bsum<<<SCB, 256, 0, stream>>>(deg, bsum);
    k_bsum_scan<<<1, 256, 0, stream>>>(bsum, bbase, row_ptr);
    k_scan_final<<<SCB, 256, 0, stream>>>(deg, bbase, row_ptr, cursor);

    // ---- C2 = cond @ W1c  -> f32 [128][512] ----
    k_mgemm<false, false, false, false><<<4, 256, 0, stream>>>(
        condb, nullptr, 0, W1cT, C2, NG, F1, CONDCH, 4,
        nullptr, nullptr, nullptr, nullptr, nullptr, nullptr, 0);
    // ---- h1 = bf16( x @ W1a + C2[batch] ), fused att1 logits; A staged from f32 x ----
    k_mgemm<true, true, true, true><<<(MPAD / 128) * 4, 256, 0, stream>>>(
        nullptr, x, NN - 1, W1aT, h1b, NN, F1, INCH, 4,
        C2, batch, att_src1, att_dst1, a_src1, a_dst1, NHEAD);
    // ---- edge layer1: logit + max + scatter (CSR-ordered logits) ----
    k_maxscat4<<<(ET + 255) / 256, 256, 0, stream>>>(ei, a_src1, a_dst1, m1enc, cursor,
                                                     csr_src, pos_of_e, w1c);
    // ---- aggregate layer1 (inline softmax, +b1, relu) -> g1 bf16 ----
    k_agg1<<<NN / 4, 256, 0, stream>>>(h1b, w1c, m1enc, row_ptr, csr_src, b1, g1b);
    // ---- h2 = bf16( g1 @ W2 ), fused att2 logits ----
    k_mgemm<false, false, true, true><<<MPAD / 128, 256, 0, stream>>>(
        g1b, nullptr, 0, W2T, h2b, NN, F2, F1, 1,
        nullptr, nullptr, att_src2, att_dst2, a_src2, a_dst2, 1);
    // ---- edge layer2: logit + max, CSR-ordered write ----
    k_max1w<<<(ET + 255) / 256, 256, 0, stream>>>(ei, a_src2, a_dst2, pos_of_e, m2enc, w2c);
    // ---- aggregate layer2 (inline softmax) + final linear -> out ----
    k_agg2<<<NN / 4, 256, 0, stream>>>(h2b, w2c, m2enc, row_ptr, csr_src, b2, outW, outb, out);
}

// Round 6
// 346.787 us; speedup vs baseline: 4.6161x; 1.2976x over previous
//
#include <hip/hip_runtime.h>
#include <hip/hip_bf16.h>
#include <cstdint>
#include <cstddef>

#define NN 50000        // nodes
#define NE 400000       // edges (without self loops)
#define ET (NE + NN)    // edges incl self loops
#define NG 128          // graphs
#define INCH 768
#define CONDCH 768
#define HIDD 128
#define NHEAD 4
#define F1 (NHEAD * HIDD)   // 512
#define F2 HIDD             // 128
#define MPAD 50048          // 391 * 128

typedef unsigned short ushort_t;
typedef float f32x4 __attribute__((ext_vector_type(4)));
typedef __bf16 bf16x8 __attribute__((ext_vector_type(8)));

typedef const void __attribute__((address_space(1))) as1_void;
typedef void __attribute__((address_space(3))) as3_void;

__device__ __forceinline__ void gload_lds16(const void* g, void* l) {
    __builtin_amdgcn_global_load_lds((as1_void*)g, (as3_void*)l, 16, 0, 0);
}

__device__ __forceinline__ ushort_t f2bf(float f) {
    uint32_t u = __float_as_uint(f);
    uint32_t r = (u + 0x7fffu + ((u >> 16) & 1u)) >> 16;
    return (ushort_t)r;
}
__device__ __forceinline__ float bf_lo(uint32_t u) { return __uint_as_float(u << 16); }
__device__ __forceinline__ float bf_hi(uint32_t u) { return __uint_as_float(u & 0xffff0000u); }

// ---------------- init: deg=1 (self loop pre-counted) ----------------
__global__ __launch_bounds__(256) void k_init(int* __restrict__ deg) {
    int i = blockIdx.x * 256 + threadIdx.x;
    if (i < NN) deg[i] = 1;
}

// ---------------- f32 -> bf16 convert (vectorized) ----------------
__global__ __launch_bounds__(256) void k_cvt(const float* __restrict__ in,
                                             ushort_t* __restrict__ out, long n4) {
    long i = (long)blockIdx.x * blockDim.x + threadIdx.x;
    if (i >= n4) return;
    float4 v = *(const float4*)(in + i * 4);
    ushort4 o;
    o.x = f2bf(v.x); o.y = f2bf(v.y); o.z = f2bf(v.z); o.w = f2bf(v.w);
    *(ushort4*)(out + i * 4) = o;
}

// ---------------- all weight transposes in one kernel --------------------------
#define R1 (F1 * INCH)
#define R2 (R1 + F1 * CONDCH)
#define R3 (R2 + F2 * F1)
__global__ __launch_bounds__(256) void k_tcvt_all(
    const float* __restrict__ W1, const float* __restrict__ W2,
    ushort_t* __restrict__ W1aT, ushort_t* __restrict__ W1cT, ushort_t* __restrict__ W2T)
{
    int idx = blockIdx.x * blockDim.x + threadIdx.x;
    if (idx >= R3) return;
    if (idx < R1) {
        int n = idx / INCH, k = idx % INCH;
        W1aT[idx] = f2bf(W1[(size_t)k * F1 + n]);
    } else if (idx < R2) {
        int j = idx - R1;
        int n = j / CONDCH, k = j % CONDCH;
        W1cT[j] = f2bf(W1[(size_t)(INCH + k) * F1 + n]);
    } else {
        int j = idx - R2;
        int n = j / F1, k = j % F1;
        W2T[j] = f2bf(W2[(size_t)k * F2 + n]);
    }
}

// ---------------- bf16 MFMA GEMM: C[M,N] = A[M,K] @ BT[N,K]^T (+G[gidx[m],:]) ----
// 1-D grid, XCD-chunked bijective swizzle, n-fast ordering.
// FUSE_ATT: per-row dots with attS/attD -> aS/aD[m*attStride + by].
template <bool ADD_GATHER, bool OUT_BF16, bool FUSE_ATT>
__global__ __launch_bounds__(256) void k_mgemm(
    const ushort_t* __restrict__ A, const ushort_t* __restrict__ BT, void* __restrict__ Cv,
    int M, int N, int K, int nBN,
    const float* __restrict__ G, const int* __restrict__ gidx,
    const float* __restrict__ attS, const float* __restrict__ attD,
    float* __restrict__ aS, float* __restrict__ aD, int attStride)
{
    __shared__ __align__(16) char smem[16384];  // sA[128][32]bf16 + sB[128][32]bf16
    char* sA = smem;
    char* sB = smem + 8192;

    const int nwg = gridDim.x;
    const int orig = blockIdx.x;
    const int q = nwg >> 3, r = nwg & 7;
    const int xcd = orig & 7, sid = orig >> 3;
    const int wg = (xcd < r ? xcd * (q + 1) : r * (q + 1) + (xcd - r) * q) + sid;
    const int bx = wg / nBN, by = wg % nBN;

    const int tid = threadIdx.x;
    const int lane = tid & 63;
    const int wave = tid >> 6;
    const int wr = wave >> 1, wc = wave & 1;
    const int m0 = bx * 128, n0 = by * 128;

    const int sr = tid >> 2;
    const int sc = (tid & 3) * 8;
    const ushort_t* gA = A + (size_t)(m0 + sr) * K + sc;
    const ushort_t* gB = BT + (size_t)(n0 + sr) * K + sc;
    const int ldsw = wave * 1024;

    const int a_off = (wr * 64 + (lane & 15)) * 64 + (lane >> 4) * 16;
    const int b_off = (wc * 64 + (lane & 15)) * 64 + (lane >> 4) * 16;

    f32x4 acc[4][4];
#pragma unroll
    for (int i = 0; i < 4; i++)
#pragma unroll
        for (int j = 0; j < 4; j++) acc[i][j] = 0.f;

    for (int kt = 0; kt < K; kt += 32) {
        gload_lds16(gA + kt,                  sA + ldsw);
        gload_lds16(gA + (size_t)64 * K + kt, sA + 4096 + ldsw);
        gload_lds16(gB + kt,                  sB + ldsw);
        gload_lds16(gB + (size_t)64 * K + kt, sB + 4096 + ldsw);
        __syncthreads();
        bf16x8 af[4], bfr[4];
#pragma unroll
        for (int i = 0; i < 4; i++) af[i]  = *(const bf16x8*)(sA + a_off + i * 1024);
#pragma unroll
        for (int j = 0; j < 4; j++) bfr[j] = *(const bf16x8*)(sB + b_off + j * 1024);
#pragma unroll
        for (int i = 0; i < 4; i++)
#pragma unroll
            for (int j = 0; j < 4; j++)
                acc[i][j] = __builtin_amdgcn_mfma_f32_16x16x32_bf16(af[i], bfr[j], acc[i][j], 0, 0, 0);
        __syncthreads();
    }

    float asv[4], adv[4];
    if (FUSE_ATT) {
#pragma unroll
        for (int j = 0; j < 4; j++) {
            int col = wc * 64 + j * 16 + (lane & 15);
            asv[j] = attS[by * 128 + col];
            adv[j] = attD[by * 128 + col];
        }
    }
    float* redS = (float*)smem;          // [2(wc)][128]
    float* redD = (float*)smem + 256;

#pragma unroll
    for (int i = 0; i < 4; i++) {
        int mbase = m0 + wr * 64 + i * 16 + (lane >> 4) * 4;
#pragma unroll
        for (int rr = 0; rr < 4; rr++) {
            int m = mbase + rr;
            if (m >= M) continue;
            const float* grow = nullptr;
            if (ADD_GATHER) grow = G + (size_t)gidx[m] * N;
            float vs = 0.f, vd = 0.f;
#pragma unroll
            for (int j = 0; j < 4; j++) {
                int n = n0 + wc * 64 + j * 16 + (lane & 15);
                float v = acc[i][j][rr];
                if (ADD_GATHER) v += grow[n];
                if (OUT_BF16) ((ushort_t*)Cv)[(size_t)m * N + n] = f2bf(v);
                else          ((float*)Cv)[(size_t)m * N + n] = v;
                if (FUSE_ATT) { vs = fmaf(v, asv[j], vs); vd = fmaf(v, adv[j], vd); }
            }
            if (FUSE_ATT) {
#pragma unroll
                for (int o = 1; o < 16; o <<= 1) { vs += __shfl_xor(vs, o); vd += __shfl_xor(vd, o); }
                if ((lane & 15) == 0) {
                    int mloc = wr * 64 + i * 16 + (lane >> 4) * 4 + rr;
                    redS[wc * 128 + mloc] = vs;
                    redD[wc * 128 + mloc] = vd;
                }
            }
        }
    }
    if (FUSE_ATT) {
        __syncthreads();
        int sd = tid >> 7, mloc = tid & 127;
        int m = m0 + mloc;
        if (m < M) {
            const float* rb = sd ? redD : redS;
            float v = rb[mloc] + rb[128 + mloc];
            (sd ? aD : aS)[(size_t)m * attStride + by] = v;
        }
    }
}

// ---------------- degree count (real edges only; self-loops pre-counted) -------
__global__ void k_deg(const int* __restrict__ ei, int* __restrict__ deg)
{
    int e = blockIdx.x * blockDim.x + threadIdx.x;
    if (e >= NE) return;
    atomicAdd(&deg[ei[NE + e]], 1);
}

// ---------------- 3-kernel block scan over degrees ----------------
#define SCB 196   // 196*256 = 50176 >= NN
__global__ __launch_bounds__(256) void k_deg_bsum(const int* __restrict__ deg, int* __restrict__ bsum) {
    int i = blockIdx.x * 256 + threadIdx.x;
    int v = (i < NN) ? deg[i] : 0;
    for (int o = 32; o; o >>= 1) v += __shfl_xor(v, o);
    __shared__ int wsum[4];
    if ((threadIdx.x & 63) == 0) wsum[threadIdx.x >> 6] = v;
    __syncthreads();
    if (threadIdx.x == 0) bsum[blockIdx.x] = wsum[0] + wsum[1] + wsum[2] + wsum[3];
}
__global__ __launch_bounds__(256) void k_bsum_scan(int* __restrict__ bsum, int* __restrict__ bbase,
                                                  int* __restrict__ row_ptr) {
    int t = threadIdx.x;
    int v = (t < SCB) ? bsum[t] : 0;
    int x = v;
    for (int o = 1; o < 64; o <<= 1) { int y = __shfl_up(x, o); if ((t & 63) >= o) x += y; }
    __shared__ int wsum[4];
    if ((t & 63) == 63) wsum[t >> 6] = x;
    __syncthreads();
    int base = 0;
    for (int w = 0; w < (t >> 6); w++) base += wsum[w];
    if (t < SCB) bbase[t] = base + x - v;    // exclusive
    if (t == 0) row_ptr[NN] = wsum[0] + wsum[1] + wsum[2] + wsum[3];
}
__global__ __launch_bounds__(256) void k_scan_final(const int* __restrict__ deg, const int* __restrict__ bbase,
                                                    int* __restrict__ row_ptr, int* __restrict__ cursor) {
    int b = blockIdx.x;
    int t = threadIdx.x;
    int i = b * 256 + t;
    int v = (i < NN) ? deg[i] : 0;
    int x = v;
    for (int o = 1; o < 64; o <<= 1) { int y = __shfl_up(x, o); if ((t & 63) >= o) x += y; }
    __shared__ int wsum[4];
    if ((t & 63) == 63) wsum[t >> 6] = x;
    __syncthreads();
    int base = bbase[b];
    for (int w = 0; w < (t >> 6); w++) base += wsum[w];
    int excl = base + x - v;
    if (i < NN) { row_ptr[i] = excl; cursor[i] = excl; }
}

// ---------------- scatter: csr_src only ----------------
__global__ void k_scatter(const int* __restrict__ ei, int* __restrict__ cursor,
                          int* __restrict__ csr_src)
{
    int e = blockIdx.x * blockDim.x + threadIdx.x;
    if (e >= ET) return;
    int src = e < NE ? ei[e] : e - NE;
    int dst = e < NE ? ei[NE + e] : e - NE;
    int pos = atomicAdd(&cursor[dst], 1);
    csr_src[pos] = src;
}

// ---------------- aggregation layer1: one wave per node, in-kernel softmax ------
// pass1: lanes parallel over edges -> per-head max (wave reduce).
// pass2: sequential 2-edge unroll, inline exp + ssum + row gather.
__global__ __launch_bounds__(256) void k_agg1(
    const ushort_t* __restrict__ h1, const float* __restrict__ a_src, const float* __restrict__ a_dst,
    const int* __restrict__ row_ptr, const int* __restrict__ csr_src,
    const float* __restrict__ b1, ushort_t* __restrict__ g1)
{
    const int n = blockIdx.x * 4 + (threadIdx.x >> 6);
    const int lane = threadIdx.x & 63;
    const int head = lane >> 4;
    const int beg = row_ptr[n], end = row_ptr[n + 1];
    const float4 ad = *(const float4*)(a_dst + (size_t)n * 4);

    // pass 1: per-head max
    float mx[4] = {-1e30f, -1e30f, -1e30f, -1e30f};
    for (int p = beg + lane; p < end; p += 64) {
        int src = csr_src[p];
        float4 as = *(const float4*)(a_src + (size_t)src * 4);
        float v;
        v = as.x + ad.x; v = v >= 0.f ? v : 0.2f * v; mx[0] = fmaxf(mx[0], v);
        v = as.y + ad.y; v = v >= 0.f ? v : 0.2f * v; mx[1] = fmaxf(mx[1], v);
        v = as.z + ad.z; v = v >= 0.f ? v : 0.2f * v; mx[2] = fmaxf(mx[2], v);
        v = as.w + ad.w; v = v >= 0.f ? v : 0.2f * v; mx[3] = fmaxf(mx[3], v);
    }
#pragma unroll
    for (int o = 32; o; o >>= 1) {
        mx[0] = fmaxf(mx[0], __shfl_xor(mx[0], o));
        mx[1] = fmaxf(mx[1], __shfl_xor(mx[1], o));
        mx[2] = fmaxf(mx[2], __shfl_xor(mx[2], o));
        mx[3] = fmaxf(mx[3], __shfl_xor(mx[3], o));
    }
    const float m   = (head & 1) ? ((head & 2) ? mx[3] : mx[1]) : ((head & 2) ? mx[2] : mx[0]);
    const float adh = (head & 1) ? ((head & 2) ? ad.w : ad.y)   : ((head & 2) ? ad.z : ad.x);

    // pass 2: gather + exp + accumulate
    float ssum = 0.f;
    float a[8] = {0.f, 0.f, 0.f, 0.f, 0.f, 0.f, 0.f, 0.f};
    int p = beg;
    for (; p + 1 < end; p += 2) {
        int s0 = csr_src[p], s1v = csr_src[p + 1];
        float l0 = a_src[s0 * 4 + head] + adh;  l0 = l0 >= 0.f ? l0 : 0.2f * l0;
        float l1 = a_src[s1v * 4 + head] + adh; l1 = l1 >= 0.f ? l1 : 0.2f * l1;
        float c0 = expf(l0 - m), c1 = expf(l1 - m);
        uint4 u0 = *(const uint4*)(h1 + (size_t)s0 * F1 + lane * 8);
        uint4 u1 = *(const uint4*)(h1 + (size_t)s1v * F1 + lane * 8);
        ssum += c0 + c1;
        a[0] = fmaf(c0, bf_lo(u0.x), a[0]); a[1] = fmaf(c0, bf_hi(u0.x), a[1]);
        a[2] = fmaf(c0, bf_lo(u0.y), a[2]); a[3] = fmaf(c0, bf_hi(u0.y), a[3]);
        a[4] = fmaf(c0, bf_lo(u0.z), a[4]); a[5] = fmaf(c0, bf_hi(u0.z), a[5]);
        a[6] = fmaf(c0, bf_lo(u0.w), a[6]); a[7] = fmaf(c0, bf_hi(u0.w), a[7]);
        a[0] = fmaf(c1, bf_lo(u1.x), a[0]); a[1] = fmaf(c1, bf_hi(u1.x), a[1]);
        a[2] = fmaf(c1, bf_lo(u1.y), a[2]); a[3] = fmaf(c1, bf_hi(u1.y), a[3]);
        a[4] = fmaf(c1, bf_lo(u1.z), a[4]); a[5] = fmaf(c1, bf_hi(u1.z), a[5]);
        a[6] = fmaf(c1, bf_lo(u1.w), a[6]); a[7] = fmaf(c1, bf_hi(u1.w), a[7]);
    }
    if (p < end) {
        int s0 = csr_src[p];
        float l0 = a_src[s0 * 4 + head] + adh; l0 = l0 >= 0.f ? l0 : 0.2f * l0;
        float c0 = expf(l0 - m);
        uint4 u0 = *(const uint4*)(h1 + (size_t)s0 * F1 + lane * 8);
        ssum += c0;
        a[0] = fmaf(c0, bf_lo(u0.x), a[0]); a[1] = fmaf(c0, bf_hi(u0.x), a[1]);
        a[2] = fmaf(c0, bf_lo(u0.y), a[2]); a[3] = fmaf(c0, bf_hi(u0.y), a[3]);
        a[4] = fmaf(c0, bf_lo(u0.z), a[4]); a[5] = fmaf(c0, bf_hi(u0.z), a[5]);
        a[6] = fmaf(c0, bf_lo(u0.w), a[6]); a[7] = fmaf(c0, bf_hi(u0.w), a[7]);
    }
    const float inv = 1.0f / (ssum + 1e-16f);
    const int ch = lane * 8;
    float4 bA = *(const float4*)(b1 + ch);
    float4 bB = *(const float4*)(b1 + ch + 4);
    uint4 ov;
    ov.x = (uint32_t)f2bf(fmaxf(fmaf(a[0], inv, bA.x), 0.f)) | ((uint32_t)f2bf(fmaxf(fmaf(a[1], inv, bA.y), 0.f)) << 16);
    ov.y = (uint32_t)f2bf(fmaxf(fmaf(a[2], inv, bA.z), 0.f)) | ((uint32_t)f2bf(fmaxf(fmaf(a[3], inv, bA.w), 0.f)) << 16);
    ov.z = (uint32_t)f2bf(fmaxf(fmaf(a[4], inv, bB.x), 0.f)) | ((uint32_t)f2bf(fmaxf(fmaf(a[5], inv, bB.y), 0.f)) << 16);
    ov.w = (uint32_t)f2bf(fmaxf(fmaf(a[6], inv, bB.z), 0.f)) | ((uint32_t)f2bf(fmaxf(fmaf(a[7], inv, bB.w), 0.f)) << 16);
    *(uint4*)(g1 + (size_t)n * F1 + ch) = ov;
}

// ---------------- aggregation layer2 + final linear: one wave per node ------
__global__ __launch_bounds__(256) void k_agg2(
    const ushort_t* __restrict__ h2, const float* __restrict__ a_src, const float* __restrict__ a_dst,
    const int* __restrict__ row_ptr, const int* __restrict__ csr_src,
    const float* __restrict__ b2, const float* __restrict__ outW, const float* __restrict__ outb,
    float* __restrict__ out)
{
    const int n = blockIdx.x * 4 + (threadIdx.x >> 6);
    const int lane = threadIdx.x & 63;
    const int beg = row_ptr[n], end = row_ptr[n + 1];
    const float ad = a_dst[n];

    // pass 1: max
    float mx = -1e30f;
    for (int p = beg + lane; p < end; p += 64) {
        float v = a_src[csr_src[p]] + ad;
        v = v >= 0.f ? v : 0.2f * v;
        mx = fmaxf(mx, v);
    }
#pragma unroll
    for (int o = 32; o; o >>= 1) mx = fmaxf(mx, __shfl_xor(mx, o));

    // pass 2
    float ssum = 0.f;
    float a0 = 0.f, a1 = 0.f;
    int p = beg;
    for (; p + 1 < end; p += 2) {
        int s0 = csr_src[p], s1v = csr_src[p + 1];
        float l0 = a_src[s0] + ad;  l0 = l0 >= 0.f ? l0 : 0.2f * l0;
        float l1 = a_src[s1v] + ad; l1 = l1 >= 0.f ? l1 : 0.2f * l1;
        float c0 = expf(l0 - mx), c1 = expf(l1 - mx);
        uint32_t u0 = *(const uint32_t*)(h2 + (size_t)s0 * F2 + lane * 2);
        uint32_t u1 = *(const uint32_t*)(h2 + (size_t)s1v * F2 + lane * 2);
        ssum += c0 + c1;
        a0 = fmaf(c0, bf_lo(u0), a0); a1 = fmaf(c0, bf_hi(u0), a1);
        a0 = fmaf(c1, bf_lo(u1), a0); a1 = fmaf(c1, bf_hi(u1), a1);
    }
    if (p < end) {
        int s0 = csr_src[p];
        float l0 = a_src[s0] + ad; l0 = l0 >= 0.f ? l0 : 0.2f * l0;
        float c0 = expf(l0 - mx);
        uint32_t u0 = *(const uint32_t*)(h2 + (size_t)s0 * F2 + lane * 2);
        ssum += c0;
        a0 = fmaf(c0, bf_lo(u0), a0); a1 = fmaf(c0, bf_hi(u0), a1);
    }
    const float inv = 1.0f / (ssum + 1e-16f);
    float v0 = fmaf(a0, inv, b2[lane * 2]);     v0 = v0 > 0.f ? v0 : 0.f;
    float v1 = fmaf(a1, inv, b2[lane * 2 + 1]); v1 = v1 > 0.f ? v1 : 0.f;
    float pr = v0 * outW[lane * 2] + v1 * outW[lane * 2 + 1];
    for (int o = 32; o; o >>= 1) pr += __shfl_xor(pr, o);
    if (lane == 0) out[n] = pr + outb[0];
}

// =======================================================================
extern "C" void kernel_launch(void* const* d_in, const int* in_sizes, int n_in,
                              void* d_out, int out_size, void* d_ws, size_t ws_size,
                              hipStream_t stream)
{
    const float* x        = (const float*)d_in[0];   // [NN, INCH]
    const float* cond     = (const float*)d_in[1];   // [NG, CONDCH]
    const float* W1       = (const float*)d_in[2];   // [INCH+CONDCH, F1]
    const float* att_src1 = (const float*)d_in[3];
    const float* att_dst1 = (const float*)d_in[4];
    const float* b1       = (const float*)d_in[5];
    const float* W2       = (const float*)d_in[6];   // [F1, F2]
    const float* att_src2 = (const float*)d_in[7];
    const float* att_dst2 = (const float*)d_in[8];
    const float* b2       = (const float*)d_in[9];
    const float* outW     = (const float*)d_in[10];
    const float* outb     = (const float*)d_in[11];
    const int*   ei       = (const int*)d_in[12];    // [2, NE]
    const int*   batch    = (const int*)d_in[13];    // [NN]
    float* out = (float*)d_out;

    // ---- workspace layout ----
    char* ws = (char*)d_ws;
    size_t off = 0;
    auto alloc = [&](size_t bytes) { void* p = ws + off; off += (bytes + 255) & ~size_t(255); return p; };
    ushort_t* xb      = (ushort_t*)alloc((size_t)MPAD * INCH * 2);    // 76.9 MB (aliased by g1b)
    ushort_t* condb   = (ushort_t*)alloc((size_t)NG * CONDCH * 2);
    ushort_t* W1aT    = (ushort_t*)alloc((size_t)F1 * INCH * 2);      // [512][768]
    ushort_t* W1cT    = (ushort_t*)alloc((size_t)F1 * CONDCH * 2);    // [512][768]
    ushort_t* W2T     = (ushort_t*)alloc((size_t)F2 * F1 * 2);        // [128][512]
    float*    C2      = (float*)alloc((size_t)NG * F1 * 4);           // [128][512]
    ushort_t* h1b     = (ushort_t*)alloc((size_t)NN * F1 * 2);        // 51.2 MB
    float*    a_src1  = (float*)alloc((size_t)NN * NHEAD * 4);
    float*    a_dst1  = (float*)alloc((size_t)NN * NHEAD * 4);
    int*      deg     = (int*)alloc((size_t)NN * 4);
    int*      cursor  = (int*)alloc((size_t)NN * 4);
    int*      row_ptr = (int*)alloc((size_t)(NN + 1) * 4);
    int*      csr_src = (int*)alloc((size_t)ET * 4);
    int*      bsum    = (int*)alloc((size_t)SCB * 4);
    int*      bbase   = (int*)alloc((size_t)SCB * 4);
    ushort_t* h2b     = (ushort_t*)alloc((size_t)NN * F2 * 2);        // 12.8 MB
    float*    a_src2  = (float*)alloc((size_t)NN * 4);
    float*    a_dst2  = (float*)alloc((size_t)NN * 4);
    ushort_t* g1b     = xb;   // alias: xb dead after GEMM1; g1b written in agg1
    (void)ws_size;

    // ---- init (deg=1 pre-counts self loops) ----
    k_init<<<(NN + 255) / 256, 256, 0, stream>>>(deg);

    // ---- conversions ----
    {
        long n4 = (long)NN * INCH / 4;
        k_cvt<<<(int)((n4 + 255) / 256), 256, 0, stream>>>(x, xb, n4);
        n4 = (long)NG * CONDCH / 4;
        k_cvt<<<(int)((n4 + 255) / 256), 256, 0, stream>>>(cond, condb, n4);
        k_tcvt_all<<<(R3 + 255) / 256, 256, 0, stream>>>(W1, W2, W1aT, W1cT, W2T);
    }

    // ---- degree + CSR skeleton ----
    k_deg<<<(NE + 255) / 256, 256, 0, stream>>>(ei, deg);
    k_deg_bsum<<<SCB, 256, 0, stream>>>(deg, bsum);
    k_bsum_scan<<<1, 256, 0, stream>>>(bsum, bbase, row_ptr);
    k_scan_final<<<SCB, 256, 0, stream>>>(deg, bbase, row_ptr, cursor);
    k_scatter<<<(ET + 255) / 256, 256, 0, stream>>>(ei, cursor, csr_src);

    // ---- C2 = cond @ W1c  -> f32 [128][512] ----
    k_mgemm<false, false, false><<<4, 256, 0, stream>>>(
        condb, W1cT, C2, NG, F1, CONDCH, 4,
        nullptr, nullptr, nullptr, nullptr, nullptr, nullptr, 0);
    // ---- h1 = bf16( x @ W1a + C2[batch] ), fused att1 logits ----
    k_mgemm<true, true, true><<<(MPAD / 128) * 4, 256, 0, stream>>>(
        xb, W1aT, h1b, NN, F1, INCH, 4,
        C2, batch, att_src1, att_dst1, a_src1, a_dst1, NHEAD);
    // ---- aggregate layer1 (in-kernel softmax, +b1, relu) -> g1 bf16 ----
    k_agg1<<<NN / 4, 256, 0, stream>>>(h1b, a_src1, a_dst1, row_ptr, csr_src, b1, g1b);
    // ---- h2 = bf16( g1 @ W2 ), fused att2 logits ----
    k_mgemm<false, true, true><<<MPAD / 128, 256, 0, stream>>>(
        g1b, W2T, h2b, NN, F2, F1, 1,
        nullptr, nullptr, att_src2, att_dst2, a_src2, a_dst2, 1);
    // ---- aggregate layer2 (in-kernel softmax) + final linear -> out ----
    k_agg2<<<NN / 4, 256, 0, stream>>>(h2b, a_src2, a_dst2, row_ptr, csr_src, b2, outW, outb, out);
}

// Round 7
// 326.691 us; speedup vs baseline: 4.9001x; 1.0615x over previous
//
#include <hip/hip_runtime.h>
#include <hip/hip_bf16.h>
#include <cstdint>
#include <cstddef>

#define NN 50000        // nodes
#define NE 400000       // edges (without self loops)
#define ET (NE + NN)    // edges incl self loops
#define NG 128          // graphs
#define INCH 768
#define CONDCH 768
#define HIDD 128
#define NHEAD 4
#define F1 (NHEAD * HIDD)   // 512
#define F2 HIDD             // 128
#define MPAD 50176          // 196 * 256

typedef unsigned short ushort_t;
typedef float f32x4 __attribute__((ext_vector_type(4)));
typedef __bf16 bf16x8 __attribute__((ext_vector_type(8)));

typedef const void __attribute__((address_space(1))) as1_void;
typedef void __attribute__((address_space(3))) as3_void;

__device__ __forceinline__ void gload_lds16(const void* g, void* l) {
    __builtin_amdgcn_global_load_lds((as1_void*)g, (as3_void*)l, 16, 0, 0);
}

__device__ __forceinline__ ushort_t f2bf(float f) {
    uint32_t u = __float_as_uint(f);
    uint32_t r = (u + 0x7fffu + ((u >> 16) & 1u)) >> 16;
    return (ushort_t)r;
}
__device__ __forceinline__ float bf_lo(uint32_t u) { return __uint_as_float(u << 16); }
__device__ __forceinline__ float bf_hi(uint32_t u) { return __uint_as_float(u & 0xffff0000u); }

// ---------------- f32 -> bf16 convert (vectorized) + optional deg init ---------
__global__ __launch_bounds__(256) void k_cvt(const float* __restrict__ in,
                                             ushort_t* __restrict__ out, long n4,
                                             int* __restrict__ deg) {
    long i = (long)blockIdx.x * blockDim.x + threadIdx.x;
    if (deg && i < NN) deg[i] = 1;   // self-loop pre-count
    if (i >= n4) return;
    float4 v = *(const float4*)(in + i * 4);
    ushort4 o;
    o.x = f2bf(v.x); o.y = f2bf(v.y); o.z = f2bf(v.z); o.w = f2bf(v.w);
    *(ushort4*)(out + i * 4) = o;
}

// ---------------- all weight transposes in one kernel --------------------------
#define R1 (F1 * INCH)
#define R2 (R1 + F1 * CONDCH)
#define R3 (R2 + F2 * F1)
__global__ __launch_bounds__(256) void k_tcvt_all(
    const float* __restrict__ W1, const float* __restrict__ W2,
    ushort_t* __restrict__ W1aT, ushort_t* __restrict__ W1cT, ushort_t* __restrict__ W2T)
{
    int idx = blockIdx.x * blockDim.x + threadIdx.x;
    if (idx >= R3) return;
    if (idx < R1) {
        int n = idx / INCH, k = idx % INCH;
        W1aT[idx] = f2bf(W1[(size_t)k * F1 + n]);
    } else if (idx < R2) {
        int j = idx - R1;
        int n = j / CONDCH, k = j % CONDCH;
        W1cT[j] = f2bf(W1[(size_t)(INCH + k) * F1 + n]);
    } else {
        int j = idx - R2;
        int n = j / F1, k = j % F1;
        W2T[j] = f2bf(W2[(size_t)k * F2 + n]);
    }
}

// ---------------- bf16 MFMA GEMM: C[M,N] = A[M,K] @ BT[N,K]^T (+G[gidx[m],:]) ----
// TM x 128 tile, TM in {128, 256}; TM*2 threads; wave grid (TM/64) x 2, each wave
// a 64x64 sub-tile. 1-D grid, XCD-chunked bijective swizzle, n-fast ordering.
// FUSE_ATT: per-row dots with attS/attD -> aS/aD[m*attStride + by].
template <int TM, bool ADD_GATHER, bool OUT_BF16, bool FUSE_ATT>
__global__ __launch_bounds__(TM * 2) void k_mgemm(
    const ushort_t* __restrict__ A, const ushort_t* __restrict__ BT, void* __restrict__ Cv,
    int M, int N, int K, int nBN,
    const float* __restrict__ G, const int* __restrict__ gidx,
    const float* __restrict__ attS, const float* __restrict__ attD,
    float* __restrict__ aS, float* __restrict__ aD, int attStride)
{
    __shared__ __align__(16) char smem[TM * 64 + 8192];  // sA[TM][32]bf16 + sB[128][32]bf16
    char* sA = smem;
    char* sB = smem + TM * 64;

    const int nwg = gridDim.x;
    const int orig = blockIdx.x;
    const int q = nwg >> 3, r = nwg & 7;
    const int xcd = orig & 7, sid = orig >> 3;
    const int wg = (xcd < r ? xcd * (q + 1) : r * (q + 1) + (xcd - r) * q) + sid;
    const int bx = wg / nBN, by = wg % nBN;

    const int tid = threadIdx.x;
    const int lane = tid & 63;
    const int wave = tid >> 6;
    const int wr = wave >> 1, wc = wave & 1;
    const int m0 = bx * TM, n0 = by * 128;

    // staging: thread t covers row t>>2 (rows/issue = TM/2), 16B chunk (t&3)*8
    const int sr = tid >> 2;
    const int sc = (tid & 3) * 8;
    const ushort_t* gA = A + (size_t)(m0 + sr) * K + sc;
    const ushort_t* gB = BT + (size_t)(n0 + sr) * K + sc;
    const int ldsw = wave * 1024;   // 16 rows x 64B per wave per issue

    const int a_off = (wr * 64 + (lane & 15)) * 64 + (lane >> 4) * 16;
    const int b_off = (wc * 64 + (lane & 15)) * 64 + (lane >> 4) * 16;

    f32x4 acc[4][4];
#pragma unroll
    for (int i = 0; i < 4; i++)
#pragma unroll
        for (int j = 0; j < 4; j++) acc[i][j] = 0.f;

    for (int kt = 0; kt < K; kt += 32) {
        gload_lds16(gA + kt,                         sA + ldsw);
        gload_lds16(gA + (size_t)(TM / 2) * K + kt,  sA + TM * 32 + ldsw);
        gload_lds16(gB + kt,                         sB + ldsw);
        if (TM == 128)
            gload_lds16(gB + (size_t)64 * K + kt,    sB + 4096 + ldsw);
        __syncthreads();
        bf16x8 af[4], bfr[4];
#pragma unroll
        for (int i = 0; i < 4; i++) af[i]  = *(const bf16x8*)(sA + a_off + i * 1024);
#pragma unroll
        for (int j = 0; j < 4; j++) bfr[j] = *(const bf16x8*)(sB + b_off + j * 1024);
#pragma unroll
        for (int i = 0; i < 4; i++)
#pragma unroll
            for (int j = 0; j < 4; j++)
                acc[i][j] = __builtin_amdgcn_mfma_f32_16x16x32_bf16(af[i], bfr[j], acc[i][j], 0, 0, 0);
        __syncthreads();
    }

    float asv[4], adv[4];
    if (FUSE_ATT) {
#pragma unroll
        for (int j = 0; j < 4; j++) {
            int col = wc * 64 + j * 16 + (lane & 15);
            asv[j] = attS[by * 128 + col];
            adv[j] = attD[by * 128 + col];
        }
    }
    float* redS = (float*)smem;              // [2(wc)][TM]
    float* redD = (float*)smem + 2 * TM;

#pragma unroll
    for (int i = 0; i < 4; i++) {
        int mbase = m0 + wr * 64 + i * 16 + (lane >> 4) * 4;
#pragma unroll
        for (int rr = 0; rr < 4; rr++) {
            int m = mbase + rr;
            if (m >= M) continue;
            const float* grow = nullptr;
            if (ADD_GATHER) grow = G + (size_t)gidx[m] * N;
            float vs = 0.f, vd = 0.f;
#pragma unroll
            for (int j = 0; j < 4; j++) {
                int n = n0 + wc * 64 + j * 16 + (lane & 15);
                float v = acc[i][j][rr];
                if (ADD_GATHER) v += grow[n];
                if (OUT_BF16) ((ushort_t*)Cv)[(size_t)m * N + n] = f2bf(v);
                else          ((float*)Cv)[(size_t)m * N + n] = v;
                if (FUSE_ATT) { vs = fmaf(v, asv[j], vs); vd = fmaf(v, adv[j], vd); }
            }
            if (FUSE_ATT) {
#pragma unroll
                for (int o = 1; o < 16; o <<= 1) { vs += __shfl_xor(vs, o); vd += __shfl_xor(vd, o); }
                if ((lane & 15) == 0) {
                    int mloc = wr * 64 + i * 16 + (lane >> 4) * 4 + rr;
                    redS[wc * TM + mloc] = vs;
                    redD[wc * TM + mloc] = vd;
                }
            }
        }
    }
    if (FUSE_ATT) {
        __syncthreads();
        int sd = tid >= TM ? 1 : 0, mloc = tid & (TM - 1);
        int m = m0 + mloc;
        if (m < M) {
            const float* rb = sd ? redD : redS;
            float v = rb[mloc] + rb[TM + mloc];
            (sd ? aD : aS)[(size_t)m * attStride + by] = v;
        }
    }
}

// ---------------- degree count (real edges only; self-loops pre-counted) -------
__global__ void k_deg(const int* __restrict__ ei, int* __restrict__ deg)
{
    int e = blockIdx.x * blockDim.x + threadIdx.x;
    if (e >= NE) return;
    atomicAdd(&deg[ei[NE + e]], 1);
}

// ---------------- 3-kernel block scan over degrees ----------------
#define SCB 196   // 196*256 = 50176 >= NN
__global__ __launch_bounds__(256) void k_deg_bsum(const int* __restrict__ deg, int* __restrict__ bsum) {
    int i = blockIdx.x * 256 + threadIdx.x;
    int v = (i < NN) ? deg[i] : 0;
    for (int o = 32; o; o >>= 1) v += __shfl_xor(v, o);
    __shared__ int wsum[4];
    if ((threadIdx.x & 63) == 0) wsum[threadIdx.x >> 6] = v;
    __syncthreads();
    if (threadIdx.x == 0) bsum[blockIdx.x] = wsum[0] + wsum[1] + wsum[2] + wsum[3];
}
__global__ __launch_bounds__(256) void k_bsum_scan(int* __restrict__ bsum, int* __restrict__ bbase,
                                                  int* __restrict__ row_ptr) {
    int t = threadIdx.x;
    int v = (t < SCB) ? bsum[t] : 0;
    int x = v;
    for (int o = 1; o < 64; o <<= 1) { int y = __shfl_up(x, o); if ((t & 63) >= o) x += y; }
    __shared__ int wsum[4];
    if ((t & 63) == 63) wsum[t >> 6] = x;
    __syncthreads();
    int base = 0;
    for (int w = 0; w < (t >> 6); w++) base += wsum[w];
    if (t < SCB) bbase[t] = base + x - v;    // exclusive
    if (t == 0) row_ptr[NN] = wsum[0] + wsum[1] + wsum[2] + wsum[3];
}
__global__ __launch_bounds__(256) void k_scan_final(const int* __restrict__ deg, const int* __restrict__ bbase,
                                                    int* __restrict__ row_ptr, int* __restrict__ cursor) {
    int b = blockIdx.x;
    int t = threadIdx.x;
    int i = b * 256 + t;
    int v = (i < NN) ? deg[i] : 0;
    int x = v;
    for (int o = 1; o < 64; o <<= 1) { int y = __shfl_up(x, o); if ((t & 63) >= o) x += y; }
    __shared__ int wsum[4];
    if ((t & 63) == 63) wsum[t >> 6] = x;
    __syncthreads();
    int base = bbase[b];
    for (int w = 0; w < (t >> 6); w++) base += wsum[w];
    int excl = base + x - v;
    if (i < NN) { row_ptr[i] = excl; cursor[i] = excl; }
}

// ---------------- scatter: csr_src only ----------------
__global__ void k_scatter(const int* __restrict__ ei, int* __restrict__ cursor,
                          int* __restrict__ csr_src)
{
    int e = blockIdx.x * blockDim.x + threadIdx.x;
    if (e >= ET) return;
    int src = e < NE ? ei[e] : e - NE;
    int dst = e < NE ? ei[NE + e] : e - NE;
    int pos = atomicAdd(&cursor[dst], 1);
    csr_src[pos] = src;
}

// ---------------- aggregation layer1: one wave per node, in-kernel softmax ------
__global__ __launch_bounds__(256) void k_agg1(
    const ushort_t* __restrict__ h1, const float* __restrict__ a_src, const float* __restrict__ a_dst,
    const int* __restrict__ row_ptr, const int* __restrict__ csr_src,
    const float* __restrict__ b1, ushort_t* __restrict__ g1)
{
    const int n = blockIdx.x * 4 + (threadIdx.x >> 6);
    const int lane = threadIdx.x & 63;
    const int head = lane >> 4;
    const int beg = row_ptr[n], end = row_ptr[n + 1];
    const float4 ad = *(const float4*)(a_dst + (size_t)n * 4);

    // pass 1: per-head max (lanes parallel)
    float mx[4] = {-1e30f, -1e30f, -1e30f, -1e30f};
    for (int p = beg + lane; p < end; p += 64) {
        int src = csr_src[p];
        float4 as = *(const float4*)(a_src + (size_t)src * 4);
        float v;
        v = as.x + ad.x; v = v >= 0.f ? v : 0.2f * v; mx[0] = fmaxf(mx[0], v);
        v = as.y + ad.y; v = v >= 0.f ? v : 0.2f * v; mx[1] = fmaxf(mx[1], v);
        v = as.z + ad.z; v = v >= 0.f ? v : 0.2f * v; mx[2] = fmaxf(mx[2], v);
        v = as.w + ad.w; v = v >= 0.f ? v : 0.2f * v; mx[3] = fmaxf(mx[3], v);
    }
#pragma unroll
    for (int o = 32; o; o >>= 1) {
        mx[0] = fmaxf(mx[0], __shfl_xor(mx[0], o));
        mx[1] = fmaxf(mx[1], __shfl_xor(mx[1], o));
        mx[2] = fmaxf(mx[2], __shfl_xor(mx[2], o));
        mx[3] = fmaxf(mx[3], __shfl_xor(mx[3], o));
    }
    const float m   = (head & 1) ? ((head & 2) ? mx[3] : mx[1]) : ((head & 2) ? mx[2] : mx[0]);
    const float adh = (head & 1) ? ((head & 2) ? ad.w : ad.y)   : ((head & 2) ? ad.z : ad.x);

    // pass 2: gather + exp + accumulate, 4-edge unroll (MLP)
    float ssum = 0.f;
    float a[8] = {0.f, 0.f, 0.f, 0.f, 0.f, 0.f, 0.f, 0.f};
    int p = beg;
#define LREL(l) ((l) >= 0.f ? (l) : 0.2f * (l))
#define ACC8(c, u) \
        a[0] = fmaf(c, bf_lo(u.x), a[0]); a[1] = fmaf(c, bf_hi(u.x), a[1]); \
        a[2] = fmaf(c, bf_lo(u.y), a[2]); a[3] = fmaf(c, bf_hi(u.y), a[3]); \
        a[4] = fmaf(c, bf_lo(u.z), a[4]); a[5] = fmaf(c, bf_hi(u.z), a[5]); \
        a[6] = fmaf(c, bf_lo(u.w), a[6]); a[7] = fmaf(c, bf_hi(u.w), a[7]);
    for (; p + 3 < end; p += 4) {
        int s0 = csr_src[p], s1 = csr_src[p + 1], s2 = csr_src[p + 2], s3 = csr_src[p + 3];
        uint4 u0 = *(const uint4*)(h1 + (size_t)s0 * F1 + lane * 8);
        uint4 u1 = *(const uint4*)(h1 + (size_t)s1 * F1 + lane * 8);
        uint4 u2 = *(const uint4*)(h1 + (size_t)s2 * F1 + lane * 8);
        uint4 u3 = *(const uint4*)(h1 + (size_t)s3 * F1 + lane * 8);
        float c0 = expf(LREL(a_src[s0 * 4 + head] + adh) - m);
        float c1 = expf(LREL(a_src[s1 * 4 + head] + adh) - m);
        float c2 = expf(LREL(a_src[s2 * 4 + head] + adh) - m);
        float c3 = expf(LREL(a_src[s3 * 4 + head] + adh) - m);
        ssum += c0 + c1 + c2 + c3;
        ACC8(c0, u0) ACC8(c1, u1) ACC8(c2, u2) ACC8(c3, u3)
    }
    for (; p < end; p++) {
        int s0 = csr_src[p];
        uint4 u0 = *(const uint4*)(h1 + (size_t)s0 * F1 + lane * 8);
        float c0 = expf(LREL(a_src[s0 * 4 + head] + adh) - m);
        ssum += c0;
        ACC8(c0, u0)
    }
#undef ACC8
    const float inv = 1.0f / (ssum + 1e-16f);
    const int ch = lane * 8;
    float4 bA = *(const float4*)(b1 + ch);
    float4 bB = *(const float4*)(b1 + ch + 4);
    uint4 ov;
    ov.x = (uint32_t)f2bf(fmaxf(fmaf(a[0], inv, bA.x), 0.f)) | ((uint32_t)f2bf(fmaxf(fmaf(a[1], inv, bA.y), 0.f)) << 16);
    ov.y = (uint32_t)f2bf(fmaxf(fmaf(a[2], inv, bA.z), 0.f)) | ((uint32_t)f2bf(fmaxf(fmaf(a[3], inv, bA.w), 0.f)) << 16);
    ov.z = (uint32_t)f2bf(fmaxf(fmaf(a[4], inv, bB.x), 0.f)) | ((uint32_t)f2bf(fmaxf(fmaf(a[5], inv, bB.y), 0.f)) << 16);
    ov.w = (uint32_t)f2bf(fmaxf(fmaf(a[6], inv, bB.z), 0.f)) | ((uint32_t)f2bf(fmaxf(fmaf(a[7], inv, bB.w), 0.f)) << 16);
    *(uint4*)(g1 + (size_t)n * F1 + ch) = ov;
}

// ---------------- aggregation layer2 + final linear: one wave per node ------
__global__ __launch_bounds__(256) void k_agg2(
    const ushort_t* __restrict__ h2, const float* __restrict__ a_src, const float* __restrict__ a_dst,
    const int* __restrict__ row_ptr, const int* __restrict__ csr_src,
    const float* __restrict__ b2, const float* __restrict__ outW, const float* __restrict__ outb,
    float* __restrict__ out)
{
    const int n = blockIdx.x * 4 + (threadIdx.x >> 6);
    const int lane = threadIdx.x & 63;
    const int beg = row_ptr[n], end = row_ptr[n + 1];
    const float ad = a_dst[n];

    // pass 1: max
    float mx = -1e30f;
    for (int p = beg + lane; p < end; p += 64) {
        float v = a_src[csr_src[p]] + ad;
        v = v >= 0.f ? v : 0.2f * v;
        mx = fmaxf(mx, v);
    }
#pragma unroll
    for (int o = 32; o; o >>= 1) mx = fmaxf(mx, __shfl_xor(mx, o));

    // pass 2: 4-edge unroll
    float ssum = 0.f;
    float a0 = 0.f, a1 = 0.f;
    int p = beg;
    for (; p + 3 < end; p += 4) {
        int s0 = csr_src[p], s1 = csr_src[p + 1], s2 = csr_src[p + 2], s3 = csr_src[p + 3];
        uint32_t u0 = *(const uint32_t*)(h2 + (size_t)s0 * F2 + lane * 2);
        uint32_t u1 = *(const uint32_t*)(h2 + (size_t)s1 * F2 + lane * 2);
        uint32_t u2 = *(const uint32_t*)(h2 + (size_t)s2 * F2 + lane * 2);
        uint32_t u3 = *(const uint32_t*)(h2 + (size_t)s3 * F2 + lane * 2);
        float c0 = expf(LREL(a_src[s0] + ad) - mx);
        float c1 = expf(LREL(a_src[s1] + ad) - mx);
        float c2 = expf(LREL(a_src[s2] + ad) - mx);
        float c3 = expf(LREL(a_src[s3] + ad) - mx);
        ssum += c0 + c1 + c2 + c3;
        a0 = fmaf(c0, bf_lo(u0), a0); a1 = fmaf(c0, bf_hi(u0), a1);
        a0 = fmaf(c1, bf_lo(u1), a0); a1 = fmaf(c1, bf_hi(u1), a1);
        a0 = fmaf(c2, bf_lo(u2), a0); a1 = fmaf(c2, bf_hi(u2), a1);
        a0 = fmaf(c3, bf_lo(u3), a0); a1 = fmaf(c3, bf_hi(u3), a1);
    }
    for (; p < end; p++) {
        int s0 = csr_src[p];
        uint32_t u0 = *(const uint32_t*)(h2 + (size_t)s0 * F2 + lane * 2);
        float c0 = expf(LREL(a_src[s0] + ad) - mx);
        ssum += c0;
        a0 = fmaf(c0, bf_lo(u0), a0); a1 = fmaf(c0, bf_hi(u0), a1);
    }
    const float inv = 1.0f / (ssum + 1e-16f);
    float v0 = fmaf(a0, inv, b2[lane * 2]);     v0 = v0 > 0.f ? v0 : 0.f;
    float v1 = fmaf(a1, inv, b2[lane * 2 + 1]); v1 = v1 > 0.f ? v1 : 0.f;
    float pr = v0 * outW[lane * 2] + v1 * outW[lane * 2 + 1];
    for (int o = 32; o; o >>= 1) pr += __shfl_xor(pr, o);
    if (lane == 0) out[n] = pr + outb[0];
}

// =======================================================================
extern "C" void kernel_launch(void* const* d_in, const int* in_sizes, int n_in,
                              void* d_out, int out_size, void* d_ws, size_t ws_size,
                              hipStream_t stream)
{
    const float* x        = (const float*)d_in[0];   // [NN, INCH]
    const float* cond     = (const float*)d_in[1];   // [NG, CONDCH]
    const float* W1       = (const float*)d_in[2];   // [INCH+CONDCH, F1]
    const float* att_src1 = (const float*)d_in[3];
    const float* att_dst1 = (const float*)d_in[4];
    const float* b1       = (const float*)d_in[5];
    const float* W2       = (const float*)d_in[6];   // [F1, F2]
    const float* att_src2 = (const float*)d_in[7];
    const float* att_dst2 = (const float*)d_in[8];
    const float* b2       = (const float*)d_in[9];
    const float* outW     = (const float*)d_in[10];
    const float* outb     = (const float*)d_in[11];
    const int*   ei       = (const int*)d_in[12];    // [2, NE]
    const int*   batch    = (const int*)d_in[13];    // [NN]
    float* out = (float*)d_out;

    // ---- workspace layout ----
    char* ws = (char*)d_ws;
    size_t off = 0;
    auto alloc = [&](size_t bytes) { void* p = ws + off; off += (bytes + 255) & ~size_t(255); return p; };
    ushort_t* xb      = (ushort_t*)alloc((size_t)MPAD * INCH * 2);    // 77.1 MB (aliased by g1b)
    ushort_t* condb   = (ushort_t*)alloc((size_t)NG * CONDCH * 2);
    ushort_t* W1aT    = (ushort_t*)alloc((size_t)F1 * INCH * 2);      // [512][768]
    ushort_t* W1cT    = (ushort_t*)alloc((size_t)F1 * CONDCH * 2);    // [512][768]
    ushort_t* W2T     = (ushort_t*)alloc((size_t)F2 * F1 * 2);        // [128][512]
    float*    C2      = (float*)alloc((size_t)NG * F1 * 4);           // [128][512]
    ushort_t* h1b     = (ushort_t*)alloc((size_t)NN * F1 * 2);        // 51.2 MB
    float*    a_src1  = (float*)alloc((size_t)NN * NHEAD * 4);
    float*    a_dst1  = (float*)alloc((size_t)NN * NHEAD * 4);
    int*      deg     = (int*)alloc((size_t)NN * 4);
    int*      cursor  = (int*)alloc((size_t)NN * 4);
    int*      row_ptr = (int*)alloc((size_t)(NN + 1) * 4);
    int*      csr_src = (int*)alloc((size_t)ET * 4);
    int*      bsum    = (int*)alloc((size_t)SCB * 4);
    int*      bbase   = (int*)alloc((size_t)SCB * 4);
    ushort_t* h2b     = (ushort_t*)alloc((size_t)NN * F2 * 2);        // 12.8 MB
    float*    a_src2  = (float*)alloc((size_t)NN * 4);
    float*    a_dst2  = (float*)alloc((size_t)NN * 4);
    ushort_t* g1b     = xb;   // alias: xb dead after GEMM1; g1b written in agg1
    (void)ws_size;

    // ---- conversions (k_cvt(x) also inits deg=1) ----
    {
        long n4 = (long)NN * INCH / 4;
        k_cvt<<<(int)((n4 + 255) / 256), 256, 0, stream>>>(x, xb, n4, deg);
        n4 = (long)NG * CONDCH / 4;
        k_cvt<<<(int)((n4 + 255) / 256), 256, 0, stream>>>(cond, condb, n4, nullptr);
        k_tcvt_all<<<(R3 + 255) / 256, 256, 0, stream>>>(W1, W2, W1aT, W1cT, W2T);
    }

    // ---- degree + CSR skeleton ----
    k_deg<<<(NE + 255) / 256, 256, 0, stream>>>(ei, deg);
    k_deg_bsum<<<SCB, 256, 0, stream>>>(deg, bsum);
    k_bsum_scan<<<1, 256, 0, stream>>>(bsum, bbase, row_ptr);
    k_scan_final<<<SCB, 256, 0, stream>>>(deg, bbase, row_ptr, cursor);
    k_scatter<<<(ET + 255) / 256, 256, 0, stream>>>(ei, cursor, csr_src);

    // ---- C2 = cond @ W1c  -> f32 [128][512] ----
    k_mgemm<128, false, false, false><<<4, 256, 0, stream>>>(
        condb, W1cT, C2, NG, F1, CONDCH, 4,
        nullptr, nullptr, nullptr, nullptr, nullptr, nullptr, 0);
    // ---- h1 = bf16( x @ W1a + C2[batch] ), fused att1 logits ----
    k_mgemm<256, true, true, true><<<(MPAD / 256) * 4, 512, 0, stream>>>(
        xb, W1aT, h1b, NN, F1, INCH, 4,
        C2, batch, att_src1, att_dst1, a_src1, a_dst1, NHEAD);
    // ---- aggregate layer1 (in-kernel softmax, +b1, relu) -> g1 bf16 ----
    k_agg1<<<NN / 4, 256, 0, stream>>>(h1b, a_src1, a_dst1, row_ptr, csr_src, b1, g1b);
    // ---- h2 = bf16( g1 @ W2 ), fused att2 logits ----
    k_mgemm<256, false, true, true><<<MPAD / 256, 512, 0, stream>>>(
        g1b, W2T, h2b, NN, F2, F1, 1,
        nullptr, nullptr, att_src2, att_dst2, a_src2, a_dst2, 1);
    // ---- aggregate layer2 (in-kernel softmax) + final linear -> out ----
    k_agg2<<<NN / 4, 256, 0, stream>>>(h2b, a_src2, a_dst2, row_ptr, csr_src, b2, outW, outb, out);
}

// Round 8
// 312.286 us; speedup vs baseline: 5.1261x; 1.0461x over previous
//
#include <hip/hip_runtime.h>
#include <hip/hip_bf16.h>
#include <cstdint>
#include <cstddef>

#define NN 50000        // nodes
#define NE 400000       // edges (without self loops)
#define ET (NE + NN)    // edges incl self loops
#define NG 128          // graphs
#define INCH 768
#define CONDCH 768
#define HIDD 128
#define NHEAD 4
#define F1 (NHEAD * HIDD)   // 512
#define F2 HIDD             // 128
#define MPAD 50176          // 196 * 256

typedef unsigned short ushort_t;
typedef float f32x4 __attribute__((ext_vector_type(4)));
typedef __bf16 bf16x8 __attribute__((ext_vector_type(8)));

typedef const void __attribute__((address_space(1))) as1_void;
typedef void __attribute__((address_space(3))) as3_void;

__device__ __forceinline__ void gload_lds16(const void* g, void* l) {
    __builtin_amdgcn_global_load_lds((as1_void*)g, (as3_void*)l, 16, 0, 0);
}

__device__ __forceinline__ ushort_t f2bf(float f) {
    uint32_t u = __float_as_uint(f);
    uint32_t r = (u + 0x7fffu + ((u >> 16) & 1u)) >> 16;
    return (ushort_t)r;
}
__device__ __forceinline__ float bf_lo(uint32_t u) { return __uint_as_float(u << 16); }
__device__ __forceinline__ float bf_hi(uint32_t u) { return __uint_as_float(u & 0xffff0000u); }

// ---------------- f32 -> bf16 convert (vectorized) + optional deg init ---------
__global__ __launch_bounds__(256) void k_cvt(const float* __restrict__ in,
                                             ushort_t* __restrict__ out, long n4,
                                             int* __restrict__ deg) {
    long i = (long)blockIdx.x * blockDim.x + threadIdx.x;
    if (deg && i < NN) deg[i] = 1;   // self-loop pre-count
    if (i >= n4) return;
    float4 v = *(const float4*)(in + i * 4);
    ushort4 o;
    o.x = f2bf(v.x); o.y = f2bf(v.y); o.z = f2bf(v.z); o.w = f2bf(v.w);
    *(ushort4*)(out + i * 4) = o;
}

// ---------------- all weight transposes in one kernel --------------------------
#define R1 (F1 * INCH)
#define R2 (R1 + F1 * CONDCH)
#define R3 (R2 + F2 * F1)
__global__ __launch_bounds__(256) void k_tcvt_all(
    const float* __restrict__ W1, const float* __restrict__ W2,
    ushort_t* __restrict__ W1aT, ushort_t* __restrict__ W1cT, ushort_t* __restrict__ W2T)
{
    int idx = blockIdx.x * blockDim.x + threadIdx.x;
    if (idx >= R3) return;
    if (idx < R1) {
        int n = idx / INCH, k = idx % INCH;
        W1aT[idx] = f2bf(W1[(size_t)k * F1 + n]);
    } else if (idx < R2) {
        int j = idx - R1;
        int n = j / CONDCH, k = j % CONDCH;
        W1cT[j] = f2bf(W1[(size_t)(INCH + k) * F1 + n]);
    } else {
        int j = idx - R2;
        int n = j / F1, k = j % F1;
        W2T[j] = f2bf(W2[(size_t)k * F2 + n]);
    }
}

// ---------------- bf16 MFMA GEMM: C[M,N] = A[M,K] @ BT[N,K]^T (+G[gidx[m],:]) ----
// TM x 128 tile, double-buffered LDS, 2-phase prefetch with counted vmcnt
// (stage t+1 issued BEFORE compute of t; s_barrier + vmcnt(NISSUE) keeps the
// prefetch in flight across the barrier — no full drain in the main loop).
// 1-D grid, XCD-chunked bijective swizzle, n-fast ordering.
// FUSE_ATT: per-row dots with attS/attD -> aS/aD[m*attStride + by].
template <int TM, bool ADD_GATHER, bool OUT_BF16, bool FUSE_ATT>
__global__ __launch_bounds__(TM * 2) void k_mgemm(
    const ushort_t* __restrict__ A, const ushort_t* __restrict__ BT, void* __restrict__ Cv,
    int M, int N, int K, int nBN,
    const float* __restrict__ G, const int* __restrict__ gidx,
    const float* __restrict__ attS, const float* __restrict__ attD,
    float* __restrict__ aS, float* __restrict__ aD, int attStride)
{
    constexpr int SA = TM * 64;     // bytes per A buffer (TM rows x 64B)
    constexpr int SB = 8192;        // bytes per B buffer (128 rows x 64B)
    __shared__ __align__(16) char smem[2 * SA + 2 * SB];
    char* sA = smem;
    char* sB = smem + 2 * SA;

    const int nwg = gridDim.x;
    const int orig = blockIdx.x;
    const int q = nwg >> 3, r = nwg & 7;
    const int xcd = orig & 7, sid = orig >> 3;
    const int wg = (xcd < r ? xcd * (q + 1) : r * (q + 1) + (xcd - r) * q) + sid;
    const int bx = wg / nBN, by = wg % nBN;

    const int tid = threadIdx.x;
    const int lane = tid & 63;
    const int wave = tid >> 6;
    const int wr = wave >> 1, wc = wave & 1;
    const int m0 = bx * TM, n0 = by * 128;

    // staging: thread t covers row t>>2 (rows/issue = TM/2), 16B chunk (t&3)*8
    const int sr = tid >> 2;
    const int sc = (tid & 3) * 8;
    const ushort_t* gA = A + (size_t)(m0 + sr) * K + sc;
    const ushort_t* gB = BT + (size_t)(n0 + sr) * K + sc;
    const int ldsw = wave * 1024;   // 16 rows x 64B per wave per issue

    const int a_off = (wr * 64 + (lane & 15)) * 64 + (lane >> 4) * 16;
    const int b_off = (wc * 64 + (lane & 15)) * 64 + (lane >> 4) * 16;

    auto STAGE = [&](int kt, int b) {
        char* dA = sA + b * SA + ldsw;
        gload_lds16(gA + kt, dA);
        gload_lds16(gA + (size_t)(TM / 2) * K + kt, dA + SA / 2);
        char* dB = sB + b * SB + ldsw;
        gload_lds16(gB + kt, dB);
        if (TM == 128)
            gload_lds16(gB + (size_t)64 * K + kt, dB + 4096);
    };

    f32x4 acc[4][4];
#pragma unroll
    for (int i = 0; i < 4; i++)
#pragma unroll
        for (int j = 0; j < 4; j++) acc[i][j] = 0.f;

    STAGE(0, 0);
    const int nt = K / 32;
    for (int t = 0; t < nt; t++) {
        const int cur = t & 1;
        if (t + 1 < nt) {
            STAGE((t + 1) * 32, cur ^ 1);   // prefetch stays in flight across barrier
            if constexpr (TM == 256) { asm volatile("s_waitcnt vmcnt(3)" ::: "memory"); }
            else                     { asm volatile("s_waitcnt vmcnt(4)" ::: "memory"); }
        } else {
            asm volatile("s_waitcnt vmcnt(0)" ::: "memory");
        }
        __builtin_amdgcn_s_barrier();
        __builtin_amdgcn_sched_barrier(0);  // don't hoist LDS reads above barrier
        bf16x8 af[4], bfr[4];
#pragma unroll
        for (int i = 0; i < 4; i++) af[i]  = *(const bf16x8*)(sA + cur * SA + a_off + i * 1024);
#pragma unroll
        for (int j = 0; j < 4; j++) bfr[j] = *(const bf16x8*)(sB + cur * SB + b_off + j * 1024);
#pragma unroll
        for (int i = 0; i < 4; i++)
#pragma unroll
            for (int j = 0; j < 4; j++)
                acc[i][j] = __builtin_amdgcn_mfma_f32_16x16x32_bf16(af[i], bfr[j], acc[i][j], 0, 0, 0);
        __builtin_amdgcn_sched_barrier(0);  // keep reads/MFMA before end barrier
        __builtin_amdgcn_s_barrier();       // all waves done reading buf[cur]
    }

    float asv[4], adv[4];
    if (FUSE_ATT) {
#pragma unroll
        for (int j = 0; j < 4; j++) {
            int col = wc * 64 + j * 16 + (lane & 15);
            asv[j] = attS[by * 128 + col];
            adv[j] = attD[by * 128 + col];
        }
    }
    float* redS = (float*)smem;              // [2(wc)][TM]
    float* redD = (float*)smem + 2 * TM;

#pragma unroll
    for (int i = 0; i < 4; i++) {
        int mbase = m0 + wr * 64 + i * 16 + (lane >> 4) * 4;
#pragma unroll
        for (int rr = 0; rr < 4; rr++) {
            int m = mbase + rr;
            if (m >= M) continue;
            const float* grow = nullptr;
            if (ADD_GATHER) grow = G + (size_t)gidx[m] * N;
            float vs = 0.f, vd = 0.f;
#pragma unroll
            for (int j = 0; j < 4; j++) {
                int n = n0 + wc * 64 + j * 16 + (lane & 15);
                float v = acc[i][j][rr];
                if (ADD_GATHER) v += grow[n];
                if (OUT_BF16) ((ushort_t*)Cv)[(size_t)m * N + n] = f2bf(v);
                else          ((float*)Cv)[(size_t)m * N + n] = v;
                if (FUSE_ATT) { vs = fmaf(v, asv[j], vs); vd = fmaf(v, adv[j], vd); }
            }
            if (FUSE_ATT) {
#pragma unroll
                for (int o = 1; o < 16; o <<= 1) { vs += __shfl_xor(vs, o); vd += __shfl_xor(vd, o); }
                if ((lane & 15) == 0) {
                    int mloc = wr * 64 + i * 16 + (lane >> 4) * 4 + rr;
                    redS[wc * TM + mloc] = vs;
                    redD[wc * TM + mloc] = vd;
                }
            }
        }
    }
    if (FUSE_ATT) {
        __syncthreads();
        int sd = tid >= TM ? 1 : 0, mloc = tid & (TM - 1);
        int m = m0 + mloc;
        if (m < M) {
            const float* rb = sd ? redD : redS;
            float v = rb[mloc] + rb[TM + mloc];
            (sd ? aD : aS)[(size_t)m * attStride + by] = v;
        }
    }
}

// ---------------- degree count (real edges only; self-loops pre-counted) -------
__global__ void k_deg(const int* __restrict__ ei, int* __restrict__ deg)
{
    int e = blockIdx.x * blockDim.x + threadIdx.x;
    if (e >= NE) return;
    atomicAdd(&deg[ei[NE + e]], 1);
}

// ---------------- 3-kernel block scan over degrees ----------------
#define SCB 196   // 196*256 = 50176 >= NN
__global__ __launch_bounds__(256) void k_deg_bsum(const int* __restrict__ deg, int* __restrict__ bsum) {
    int i = blockIdx.x * 256 + threadIdx.x;
    int v = (i < NN) ? deg[i] : 0;
    for (int o = 32; o; o >>= 1) v += __shfl_xor(v, o);
    __shared__ int wsum[4];
    if ((threadIdx.x & 63) == 0) wsum[threadIdx.x >> 6] = v;
    __syncthreads();
    if (threadIdx.x == 0) bsum[blockIdx.x] = wsum[0] + wsum[1] + wsum[2] + wsum[3];
}
__global__ __launch_bounds__(256) void k_bsum_scan(int* __restrict__ bsum, int* __restrict__ bbase,
                                                  int* __restrict__ row_ptr) {
    int t = threadIdx.x;
    int v = (t < SCB) ? bsum[t] : 0;
    int x = v;
    for (int o = 1; o < 64; o <<= 1) { int y = __shfl_up(x, o); if ((t & 63) >= o) x += y; }
    __shared__ int wsum[4];
    if ((t & 63) == 63) wsum[t >> 6] = x;
    __syncthreads();
    int base = 0;
    for (int w = 0; w < (t >> 6); w++) base += wsum[w];
    if (t < SCB) bbase[t] = base + x - v;    // exclusive
    if (t == 0) row_ptr[NN] = wsum[0] + wsum[1] + wsum[2] + wsum[3];
}
__global__ __launch_bounds__(256) void k_scan_final(const int* __restrict__ deg, const int* __restrict__ bbase,
                                                    int* __restrict__ row_ptr, int* __restrict__ cursor) {
    int b = blockIdx.x;
    int t = threadIdx.x;
    int i = b * 256 + t;
    int v = (i < NN) ? deg[i] : 0;
    int x = v;
    for (int o = 1; o < 64; o <<= 1) { int y = __shfl_up(x, o); if ((t & 63) >= o) x += y; }
    __shared__ int wsum[4];
    if ((t & 63) == 63) wsum[t >> 6] = x;
    __syncthreads();
    int base = bbase[b];
    for (int w = 0; w < (t >> 6); w++) base += wsum[w];
    int excl = base + x - v;
    if (i < NN) { row_ptr[i] = excl; cursor[i] = excl; }
}

// ---------------- scatter: csr_src only ----------------
__global__ void k_scatter(const int* __restrict__ ei, int* __restrict__ cursor,
                          int* __restrict__ csr_src)
{
    int e = blockIdx.x * blockDim.x + threadIdx.x;
    if (e >= ET) return;
    int src = e < NE ? ei[e] : e - NE;
    int dst = e < NE ? ei[NE + e] : e - NE;
    int pos = atomicAdd(&cursor[dst], 1);
    csr_src[pos] = src;
}

// ---------------- aggregation layer1: one wave per node, in-kernel softmax ------
__global__ __launch_bounds__(256) void k_agg1(
    const ushort_t* __restrict__ h1, const float* __restrict__ a_src, const float* __restrict__ a_dst,
    const int* __restrict__ row_ptr, const int* __restrict__ csr_src,
    const float* __restrict__ b1, ushort_t* __restrict__ g1)
{
    const int n = blockIdx.x * 4 + (threadIdx.x >> 6);
    const int lane = threadIdx.x & 63;
    const int head = lane >> 4;
    const int beg = row_ptr[n], end = row_ptr[n + 1];
    const float4 ad = *(const float4*)(a_dst + (size_t)n * 4);

    // pass 1: per-head max (lanes parallel)
    float mx[4] = {-1e30f, -1e30f, -1e30f, -1e30f};
    for (int p = beg + lane; p < end; p += 64) {
        int src = csr_src[p];
        float4 as = *(const float4*)(a_src + (size_t)src * 4);
        float v;
        v = as.x + ad.x; v = v >= 0.f ? v : 0.2f * v; mx[0] = fmaxf(mx[0], v);
        v = as.y + ad.y; v = v >= 0.f ? v : 0.2f * v; mx[1] = fmaxf(mx[1], v);
        v = as.z + ad.z; v = v >= 0.f ? v : 0.2f * v; mx[2] = fmaxf(mx[2], v);
        v = as.w + ad.w; v = v >= 0.f ? v : 0.2f * v; mx[3] = fmaxf(mx[3], v);
    }
#pragma unroll
    for (int o = 32; o; o >>= 1) {
        mx[0] = fmaxf(mx[0], __shfl_xor(mx[0], o));
        mx[1] = fmaxf(mx[1], __shfl_xor(mx[1], o));
        mx[2] = fmaxf(mx[2], __shfl_xor(mx[2], o));
        mx[3] = fmaxf(mx[3], __shfl_xor(mx[3], o));
    }
    const float m   = (head & 1) ? ((head & 2) ? mx[3] : mx[1]) : ((head & 2) ? mx[2] : mx[0]);
    const float adh = (head & 1) ? ((head & 2) ? ad.w : ad.y)   : ((head & 2) ? ad.z : ad.x);

    // pass 2: gather + exp + accumulate, 4-edge unroll (MLP)
    float ssum = 0.f;
    float a[8] = {0.f, 0.f, 0.f, 0.f, 0.f, 0.f, 0.f, 0.f};
    int p = beg;
#define LREL(l) ((l) >= 0.f ? (l) : 0.2f * (l))
#define ACC8(c, u) \
        a[0] = fmaf(c, bf_lo(u.x), a[0]); a[1] = fmaf(c, bf_hi(u.x), a[1]); \
        a[2] = fmaf(c, bf_lo(u.y), a[2]); a[3] = fmaf(c, bf_hi(u.y), a[3]); \
        a[4] = fmaf(c, bf_lo(u.z), a[4]); a[5] = fmaf(c, bf_hi(u.z), a[5]); \
        a[6] = fmaf(c, bf_lo(u.w), a[6]); a[7] = fmaf(c, bf_hi(u.w), a[7]);
    for (; p + 3 < end; p += 4) {
        int s0 = csr_src[p], s1 = csr_src[p + 1], s2 = csr_src[p + 2], s3 = csr_src[p + 3];
        uint4 u0 = *(const uint4*)(h1 + (size_t)s0 * F1 + lane * 8);
        uint4 u1 = *(const uint4*)(h1 + (size_t)s1 * F1 + lane * 8);
        uint4 u2 = *(const uint4*)(h1 + (size_t)s2 * F1 + lane * 8);
        uint4 u3 = *(const uint4*)(h1 + (size_t)s3 * F1 + lane * 8);
        float c0 = expf(LREL(a_src[s0 * 4 + head] + adh) - m);
        float c1 = expf(LREL(a_src[s1 * 4 + head] + adh) - m);
        float c2 = expf(LREL(a_src[s2 * 4 + head] + adh) - m);
        float c3 = expf(LREL(a_src[s3 * 4 + head] + adh) - m);
        ssum += c0 + c1 + c2 + c3;
        ACC8(c0, u0) ACC8(c1, u1) ACC8(c2, u2) ACC8(c3, u3)
    }
    for (; p < end; p++) {
        int s0 = csr_src[p];
        uint4 u0 = *(const uint4*)(h1 + (size_t)s0 * F1 + lane * 8);
        float c0 = expf(LREL(a_src[s0 * 4 + head] + adh) - m);
        ssum += c0;
        ACC8(c0, u0)
    }
#undef ACC8
    const float inv = 1.0f / (ssum + 1e-16f);
    const int ch = lane * 8;
    float4 bA = *(const float4*)(b1 + ch);
    float4 bB = *(const float4*)(b1 + ch + 4);
    uint4 ov;
    ov.x = (uint32_t)f2bf(fmaxf(fmaf(a[0], inv, bA.x), 0.f)) | ((uint32_t)f2bf(fmaxf(fmaf(a[1], inv, bA.y), 0.f)) << 16);
    ov.y = (uint32_t)f2bf(fmaxf(fmaf(a[2], inv, bA.z), 0.f)) | ((uint32_t)f2bf(fmaxf(fmaf(a[3], inv, bA.w), 0.f)) << 16);
    ov.z = (uint32_t)f2bf(fmaxf(fmaf(a[4], inv, bB.x), 0.f)) | ((uint32_t)f2bf(fmaxf(fmaf(a[5], inv, bB.y), 0.f)) << 16);
    ov.w = (uint32_t)f2bf(fmaxf(fmaf(a[6], inv, bB.z), 0.f)) | ((uint32_t)f2bf(fmaxf(fmaf(a[7], inv, bB.w), 0.f)) << 16);
    *(uint4*)(g1 + (size_t)n * F1 + ch) = ov;
}

// ---------------- aggregation layer2 + final linear: one wave per node ------
__global__ __launch_bounds__(256) void k_agg2(
    const ushort_t* __restrict__ h2, const float* __restrict__ a_src, const float* __restrict__ a_dst,
    const int* __restrict__ row_ptr, const int* __restrict__ csr_src,
    const float* __restrict__ b2, const float* __restrict__ outW, const float* __restrict__ outb,
    float* __restrict__ out)
{
    const int n = blockIdx.x * 4 + (threadIdx.x >> 6);
    const int lane = threadIdx.x & 63;
    const int beg = row_ptr[n], end = row_ptr[n + 1];
    const float ad = a_dst[n];

    // pass 1: max
    float mx = -1e30f;
    for (int p = beg + lane; p < end; p += 64) {
        float v = a_src[csr_src[p]] + ad;
        v = v >= 0.f ? v : 0.2f * v;
        mx = fmaxf(mx, v);
    }
#pragma unroll
    for (int o = 32; o; o >>= 1) mx = fmaxf(mx, __shfl_xor(mx, o));

    // pass 2: 4-edge unroll
    float ssum = 0.f;
    float a0 = 0.f, a1 = 0.f;
    int p = beg;
    for (; p + 3 < end; p += 4) {
        int s0 = csr_src[p], s1 = csr_src[p + 1], s2 = csr_src[p + 2], s3 = csr_src[p + 3];
        uint32_t u0 = *(const uint32_t*)(h2 + (size_t)s0 * F2 + lane * 2);
        uint32_t u1 = *(const uint32_t*)(h2 + (size_t)s1 * F2 + lane * 2);
        uint32_t u2 = *(const uint32_t*)(h2 + (size_t)s2 * F2 + lane * 2);
        uint32_t u3 = *(const uint32_t*)(h2 + (size_t)s3 * F2 + lane * 2);
        float c0 = expf(LREL(a_src[s0] + ad) - mx);
        float c1 = expf(LREL(a_src[s1] + ad) - mx);
        float c2 = expf(LREL(a_src[s2] + ad) - mx);
        float c3 = expf(LREL(a_src[s3] + ad) - mx);
        ssum += c0 + c1 + c2 + c3;
        a0 = fmaf(c0, bf_lo(u0), a0); a1 = fmaf(c0, bf_hi(u0), a1);
        a0 = fmaf(c1, bf_lo(u1), a0); a1 = fmaf(c1, bf_hi(u1), a1);
        a0 = fmaf(c2, bf_lo(u2), a0); a1 = fmaf(c2, bf_hi(u2), a1);
        a0 = fmaf(c3, bf_lo(u3), a0); a1 = fmaf(c3, bf_hi(u3), a1);
    }
    for (; p < end; p++) {
        int s0 = csr_src[p];
        uint32_t u0 = *(const uint32_t*)(h2 + (size_t)s0 * F2 + lane * 2);
        float c0 = expf(LREL(a_src[s0] + ad) - mx);
        ssum += c0;
        a0 = fmaf(c0, bf_lo(u0), a0); a1 = fmaf(c0, bf_hi(u0), a1);
    }
    const float inv = 1.0f / (ssum + 1e-16f);
    float v0 = fmaf(a0, inv, b2[lane * 2]);     v0 = v0 > 0.f ? v0 : 0.f;
    float v1 = fmaf(a1, inv, b2[lane * 2 + 1]); v1 = v1 > 0.f ? v1 : 0.f;
    float pr = v0 * outW[lane * 2] + v1 * outW[lane * 2 + 1];
    for (int o = 32; o; o >>= 1) pr += __shfl_xor(pr, o);
    if (lane == 0) out[n] = pr + outb[0];
}

// =======================================================================
extern "C" void kernel_launch(void* const* d_in, const int* in_sizes, int n_in,
                              void* d_out, int out_size, void* d_ws, size_t ws_size,
                              hipStream_t stream)
{
    const float* x        = (const float*)d_in[0];   // [NN, INCH]
    const float* cond     = (const float*)d_in[1];   // [NG, CONDCH]
    const float* W1       = (const float*)d_in[2];   // [INCH+CONDCH, F1]
    const float* att_src1 = (const float*)d_in[3];
    const float* att_dst1 = (const float*)d_in[4];
    const float* b1       = (const float*)d_in[5];
    const float* W2       = (const float*)d_in[6];   // [F1, F2]
    const float* att_src2 = (const float*)d_in[7];
    const float* att_dst2 = (const float*)d_in[8];
    const float* b2       = (const float*)d_in[9];
    const float* outW     = (const float*)d_in[10];
    const float* outb     = (const float*)d_in[11];
    const int*   ei       = (const int*)d_in[12];    // [2, NE]
    const int*   batch    = (const int*)d_in[13];    // [NN]
    float* out = (float*)d_out;

    // ---- workspace layout ----
    char* ws = (char*)d_ws;
    size_t off = 0;
    auto alloc = [&](size_t bytes) { void* p = ws + off; off += (bytes + 255) & ~size_t(255); return p; };
    ushort_t* xb      = (ushort_t*)alloc((size_t)MPAD * INCH * 2);    // 77.1 MB (aliased by g1b)
    ushort_t* condb   = (ushort_t*)alloc((size_t)NG * CONDCH * 2);
    ushort_t* W1aT    = (ushort_t*)alloc((size_t)F1 * INCH * 2);      // [512][768]
    ushort_t* W1cT    = (ushort_t*)alloc((size_t)F1 * CONDCH * 2);    // [512][768]
    ushort_t* W2T     = (ushort_t*)alloc((size_t)F2 * F1 * 2);        // [128][512]
    float*    C2      = (float*)alloc((size_t)NG * F1 * 4);           // [128][512]
    ushort_t* h1b     = (ushort_t*)alloc((size_t)NN * F1 * 2);        // 51.2 MB
    float*    a_src1  = (float*)alloc((size_t)NN * NHEAD * 4);
    float*    a_dst1  = (float*)alloc((size_t)NN * NHEAD * 4);
    int*      deg     = (int*)alloc((size_t)NN * 4);
    int*      cursor  = (int*)alloc((size_t)NN * 4);
    int*      row_ptr = (int*)alloc((size_t)(NN + 1) * 4);
    int*      csr_src = (int*)alloc((size_t)ET * 4);
    int*      bsum    = (int*)alloc((size_t)SCB * 4);
    int*      bbase   = (int*)alloc((size_t)SCB * 4);
    ushort_t* h2b     = (ushort_t*)alloc((size_t)NN * F2 * 2);        // 12.8 MB
    float*    a_src2  = (float*)alloc((size_t)NN * 4);
    float*    a_dst2  = (float*)alloc((size_t)NN * 4);
    ushort_t* g1b     = xb;   // alias: xb dead after GEMM1; g1b written in agg1
    (void)ws_size;

    // ---- conversions (k_cvt(x) also inits deg=1) ----
    {
        long n4 = (long)NN * INCH / 4;
        k_cvt<<<(int)((n4 + 255) / 256), 256, 0, stream>>>(x, xb, n4, deg);
        n4 = (long)NG * CONDCH / 4;
        k_cvt<<<(int)((n4 + 255) / 256), 256, 0, stream>>>(cond, condb, n4, nullptr);
        k_tcvt_all<<<(R3 + 255) / 256, 256, 0, stream>>>(W1, W2, W1aT, W1cT, W2T);
    }

    // ---- degree + CSR skeleton ----
    k_deg<<<(NE + 255) / 256, 256, 0, stream>>>(ei, deg);
    k_deg_bsum<<<SCB, 256, 0, stream>>>(deg, bsum);
    k_bsum_scan<<<1, 256, 0, stream>>>(bsum, bbase, row_ptr);
    k_scan_final<<<SCB, 256, 0, stream>>>(deg, bbase, row_ptr, cursor);
    k_scatter<<<(ET + 255) / 256, 256, 0, stream>>>(ei, cursor, csr_src);

    // ---- C2 = cond @ W1c  -> f32 [128][512] ----
    k_mgemm<128, false, false, false><<<4, 256, 0, stream>>>(
        condb, W1cT, C2, NG, F1, CONDCH, 4,
        nullptr, nullptr, nullptr, nullptr, nullptr, nullptr, 0);
    // ---- h1 = bf16( x @ W1a + C2[batch] ), fused att1 logits ----
    k_mgemm<256, true, true, true><<<(MPAD / 256) * 4, 512, 0, stream>>>(
        xb, W1aT, h1b, NN, F1, INCH, 4,
        C2, batch, att_src1, att_dst1, a_src1, a_dst1, NHEAD);
    // ---- aggregate layer1 (in-kernel softmax, +b1, relu) -> g1 bf16 ----
    k_agg1<<<NN / 4, 256, 0, stream>>>(h1b, a_src1, a_dst1, row_ptr, csr_src, b1, g1b);
    // ---- h2 = bf16( g1 @ W2 ), fused att2 logits ----
    k_mgemm<256, false, true, true><<<MPAD / 256, 512, 0, stream>>>(
        g1b, W2T, h2b, NN, F2, F1, 1,
        nullptr, nullptr, att_src2, att_dst2, a_src2, a_dst2, 1);
    // ---- aggregate layer2 (in-kernel softmax) + final linear -> out ----
    k_agg2<<<NN / 4, 256, 0, stream>>>(h2b, a_src2, a_dst2, row_ptr, csr_src, b2, outW, outb, out);
}

// Round 9
// 306.424 us; speedup vs baseline: 5.2242x; 1.0191x over previous
//
#include <hip/hip_runtime.h>
#include <hip/hip_bf16.h>
#include <cstdint>
#include <cstddef>

#define NN 50000        // nodes
#define NE 400000       // edges (without self loops)
#define ET (NE + NN)    // edges incl self loops
#define NG 128          // graphs
#define INCH 768
#define CONDCH 768
#define HIDD 128
#define NHEAD 4
#define F1 (NHEAD * HIDD)   // 512
#define F2 HIDD             // 128
#define MPAD 50176          // 196 * 256

typedef unsigned short ushort_t;
typedef float f32x4 __attribute__((ext_vector_type(4)));
typedef __bf16 bf16x8 __attribute__((ext_vector_type(8)));

typedef const void __attribute__((address_space(1))) as1_void;
typedef void __attribute__((address_space(3))) as3_void;

__device__ __forceinline__ void gload_lds16(const void* g, void* l) {
    __builtin_amdgcn_global_load_lds((as1_void*)g, (as3_void*)l, 16, 0, 0);
}

__device__ __forceinline__ ushort_t f2bf(float f) {
    uint32_t u = __float_as_uint(f);
    uint32_t r = (u + 0x7fffu + ((u >> 16) & 1u)) >> 16;
    return (ushort_t)r;
}
__device__ __forceinline__ float bf_lo(uint32_t u) { return __uint_as_float(u << 16); }
__device__ __forceinline__ float bf_hi(uint32_t u) { return __uint_as_float(u & 0xffff0000u); }

// ---------------- k_prep: cond->bf16, weight transposes, deg=1 init ------------
// ranges: weights idx in [0,R3); cond idx in [0, NG*CONDCH/4) (float4); deg [0,NN)
#define R1 (F1 * INCH)
#define R2 (R1 + F1 * CONDCH)
#define R3 (R2 + F2 * F1)
#define CND4 (NG * CONDCH / 4)
__global__ __launch_bounds__(256) void k_prep(
    const float* __restrict__ W1, const float* __restrict__ W2, const float* __restrict__ cond,
    ushort_t* __restrict__ W1aT, ushort_t* __restrict__ W1cT, ushort_t* __restrict__ W2T,
    ushort_t* __restrict__ condb, int* __restrict__ deg)
{
    int idx = blockIdx.x * blockDim.x + threadIdx.x;
    if (idx < NN) deg[idx] = 1;              // self-loop pre-count
    if (idx < CND4) {
        float4 v = *(const float4*)(cond + (size_t)idx * 4);
        ushort4 o;
        o.x = f2bf(v.x); o.y = f2bf(v.y); o.z = f2bf(v.z); o.w = f2bf(v.w);
        *(ushort4*)(condb + (size_t)idx * 4) = o;
    }
    if (idx >= R3) return;
    if (idx < R1) {
        int n = idx / INCH, k = idx % INCH;
        W1aT[idx] = f2bf(W1[(size_t)k * F1 + n]);
    } else if (idx < R2) {
        int j = idx - R1;
        int n = j / CONDCH, k = j % CONDCH;
        W1cT[j] = f2bf(W1[(size_t)(INCH + k) * F1 + n]);
    } else {
        int j = idx - R2;
        int n = j / F1, k = j % F1;
        W2T[j] = f2bf(W2[(size_t)k * F2 + n]);
    }
}

// ---------------- x -> bf16 convert (vectorized) + fused edge-degree count -----
__global__ __launch_bounds__(256) void k_cvt_x(const float* __restrict__ in,
                                               ushort_t* __restrict__ out, long n4,
                                               const int* __restrict__ ei,
                                               int* __restrict__ deg) {
    long i = (long)blockIdx.x * blockDim.x + threadIdx.x;
    if (i < NE) atomicAdd(&deg[ei[NE + i]], 1);
    if (i >= n4) return;
    float4 v = *(const float4*)(in + i * 4);
    ushort4 o;
    o.x = f2bf(v.x); o.y = f2bf(v.y); o.z = f2bf(v.z); o.w = f2bf(v.w);
    *(ushort4*)(out + i * 4) = o;
}

// ---------------- bf16 MFMA GEMM: C[M,N] = A[M,K] @ BT[N,K]^T (+G[gidx[m],:]) ----
// TM x 128 tile, double-buffered LDS, 1 barrier per K-step:
//   { vmcnt(0); s_barrier; STAGE(t+1 -> buf^1); compute buf }
// The stage issued at iter t has the whole compute(t) to land, so the vmcnt(0)
// at iter t+1 is nearly free. The barrier at iter t is after compute(t-1) in
// program order, so staging buf^1 (last read at t-1) cannot race.
// 1-D grid, XCD-chunked bijective swizzle, n-fast ordering.
// FUSE_ATT: per-row dots with attS/attD -> aS/aD[m*attStride + by].
template <int TM, bool ADD_GATHER, bool OUT_BF16, bool FUSE_ATT>
__global__ __launch_bounds__(TM * 2) void k_mgemm(
    const ushort_t* __restrict__ A, const ushort_t* __restrict__ BT, void* __restrict__ Cv,
    int M, int N, int K, int nBN,
    const float* __restrict__ G, const int* __restrict__ gidx,
    const float* __restrict__ attS, const float* __restrict__ attD,
    float* __restrict__ aS, float* __restrict__ aD, int attStride)
{
    constexpr int SA = TM * 64;     // bytes per A buffer (TM rows x 64B)
    constexpr int SB = 8192;        // bytes per B buffer (128 rows x 64B)
    __shared__ __align__(16) char smem[2 * SA + 2 * SB];
    char* sA = smem;
    char* sB = smem + 2 * SA;

    const int nwg = gridDim.x;
    const int orig = blockIdx.x;
    const int q = nwg >> 3, r = nwg & 7;
    const int xcd = orig & 7, sid = orig >> 3;
    const int wg = (xcd < r ? xcd * (q + 1) : r * (q + 1) + (xcd - r) * q) + sid;
    const int bx = wg / nBN, by = wg % nBN;

    const int tid = threadIdx.x;
    const int lane = tid & 63;
    const int wave = tid >> 6;
    const int wr = wave >> 1, wc = wave & 1;
    const int m0 = bx * TM, n0 = by * 128;

    // staging: thread t covers row t>>2 (rows/issue = TM/2), 16B chunk (t&3)*8
    const int sr = tid >> 2;
    const int sc = (tid & 3) * 8;
    const ushort_t* gA = A + (size_t)(m0 + sr) * K + sc;
    const ushort_t* gB = BT + (size_t)(n0 + sr) * K + sc;
    const int ldsw = wave * 1024;   // 16 rows x 64B per wave per issue

    const int a_off = (wr * 64 + (lane & 15)) * 64 + (lane >> 4) * 16;
    const int b_off = (wc * 64 + (lane & 15)) * 64 + (lane >> 4) * 16;

    auto STAGE = [&](int kt, int b) {
        char* dA = sA + b * SA + ldsw;
        gload_lds16(gA + kt, dA);
        gload_lds16(gA + (size_t)(TM / 2) * K + kt, dA + SA / 2);
        char* dB = sB + b * SB + ldsw;
        gload_lds16(gB + kt, dB);
        if (TM == 128)
            gload_lds16(gB + (size_t)64 * K + kt, dB + 4096);
    };

    f32x4 acc[4][4];
#pragma unroll
    for (int i = 0; i < 4; i++)
#pragma unroll
        for (int j = 0; j < 4; j++) acc[i][j] = 0.f;

    STAGE(0, 0);
    const int nt = K / 32;   // always even for our K (768, 512)
    for (int t = 0; t < nt; t++) {
        const int cur = t & 1;
        asm volatile("s_waitcnt vmcnt(0)" ::: "memory");   // stage(t) landed
        __builtin_amdgcn_s_barrier();
        __builtin_amdgcn_sched_barrier(0);  // don't hoist LDS reads above barrier
        if (t + 1 < nt) STAGE((t + 1) * 32, cur ^ 1);      // in flight across compute
        bf16x8 af[4], bfr[4];
#pragma unroll
        for (int i = 0; i < 4; i++) af[i]  = *(const bf16x8*)(sA + cur * SA + a_off + i * 1024);
#pragma unroll
        for (int j = 0; j < 4; j++) bfr[j] = *(const bf16x8*)(sB + cur * SB + b_off + j * 1024);
#pragma unroll
        for (int i = 0; i < 4; i++)
#pragma unroll
            for (int j = 0; j < 4; j++)
                acc[i][j] = __builtin_amdgcn_mfma_f32_16x16x32_bf16(af[i], bfr[j], acc[i][j], 0, 0, 0);
    }
    // NOTE: no trailing barrier needed: nt even => last compute read buffers at
    // index 1; the FUSE_ATT epilogue reuses only smem[0..4*TM*4) in buffer 0.

    float asv[4], adv[4];
    if (FUSE_ATT) {
#pragma unroll
        for (int j = 0; j < 4; j++) {
            int col = wc * 64 + j * 16 + (lane & 15);
            asv[j] = attS[by * 128 + col];
            adv[j] = attD[by * 128 + col];
        }
    }
    float* redS = (float*)smem;              // [2(wc)][TM]  (buffer-0 region)
    float* redD = (float*)smem + 2 * TM;

#pragma unroll
    for (int i = 0; i < 4; i++) {
        int mbase = m0 + wr * 64 + i * 16 + (lane >> 4) * 4;
#pragma unroll
        for (int rr = 0; rr < 4; rr++) {
            int m = mbase + rr;
            if (m >= M) continue;
            const float* grow = nullptr;
            if (ADD_GATHER) grow = G + (size_t)gidx[m] * N;
            float vs = 0.f, vd = 0.f;
#pragma unroll
            for (int j = 0; j < 4; j++) {
                int n = n0 + wc * 64 + j * 16 + (lane & 15);
                float v = acc[i][j][rr];
                if (ADD_GATHER) v += grow[n];
                if (OUT_BF16) ((ushort_t*)Cv)[(size_t)m * N + n] = f2bf(v);
                else          ((float*)Cv)[(size_t)m * N + n] = v;
                if (FUSE_ATT) { vs = fmaf(v, asv[j], vs); vd = fmaf(v, adv[j], vd); }
            }
            if (FUSE_ATT) {
#pragma unroll
                for (int o = 1; o < 16; o <<= 1) { vs += __shfl_xor(vs, o); vd += __shfl_xor(vd, o); }
                if ((lane & 15) == 0) {
                    int mloc = wr * 64 + i * 16 + (lane >> 4) * 4 + rr;
                    redS[wc * TM + mloc] = vs;
                    redD[wc * TM + mloc] = vd;
                }
            }
        }
    }
    if (FUSE_ATT) {
        __syncthreads();
        int sd = tid >= TM ? 1 : 0, mloc = tid & (TM - 1);
        int m = m0 + mloc;
        if (m < M) {
            const float* rb = sd ? redD : redS;
            float v = rb[mloc] + rb[TM + mloc];
            (sd ? aD : aS)[(size_t)m * attStride + by] = v;
        }
    }
}

// ---------------- 3-kernel block scan over degrees ----------------
#define SCB 196   // 196*256 = 50176 >= NN
__global__ __launch_bounds__(256) void k_deg_bsum(const int* __restrict__ deg, int* __restrict__ bsum) {
    int i = blockIdx.x * 256 + threadIdx.x;
    int v = (i < NN) ? deg[i] : 0;
    for (int o = 32; o; o >>= 1) v += __shfl_xor(v, o);
    __shared__ int wsum[4];
    if ((threadIdx.x & 63) == 0) wsum[threadIdx.x >> 6] = v;
    __syncthreads();
    if (threadIdx.x == 0) bsum[blockIdx.x] = wsum[0] + wsum[1] + wsum[2] + wsum[3];
}
__global__ __launch_bounds__(256) void k_bsum_scan(int* __restrict__ bsum, int* __restrict__ bbase,
                                                  int* __restrict__ row_ptr) {
    int t = threadIdx.x;
    int v = (t < SCB) ? bsum[t] : 0;
    int x = v;
    for (int o = 1; o < 64; o <<= 1) { int y = __shfl_up(x, o); if ((t & 63) >= o) x += y; }
    __shared__ int wsum[4];
    if ((t & 63) == 63) wsum[t >> 6] = x;
    __syncthreads();
    int base = 0;
    for (int w = 0; w < (t >> 6); w++) base += wsum[w];
    if (t < SCB) bbase[t] = base + x - v;    // exclusive
    if (t == 0) row_ptr[NN] = wsum[0] + wsum[1] + wsum[2] + wsum[3];
}
__global__ __launch_bounds__(256) void k_scan_final(const int* __restrict__ deg, const int* __restrict__ bbase,
                                                    int* __restrict__ row_ptr, int* __restrict__ cursor) {
    int b = blockIdx.x;
    int t = threadIdx.x;
    int i = b * 256 + t;
    int v = (i < NN) ? deg[i] : 0;
    int x = v;
    for (int o = 1; o < 64; o <<= 1) { int y = __shfl_up(x, o); if ((t & 63) >= o) x += y; }
    __shared__ int wsum[4];
    if ((t & 63) == 63) wsum[t >> 6] = x;
    __syncthreads();
    int base = bbase[b];
    for (int w = 0; w < (t >> 6); w++) base += wsum[w];
    int excl = base + x - v;
    if (i < NN) { row_ptr[i] = excl; cursor[i] = excl; }
}

// ---------------- scatter: csr_src only ----------------
__global__ void k_scatter(const int* __restrict__ ei, int* __restrict__ cursor,
                          int* __restrict__ csr_src)
{
    int e = blockIdx.x * blockDim.x + threadIdx.x;
    if (e >= ET) return;
    int src = e < NE ? ei[e] : e - NE;
    int dst = e < NE ? ei[NE + e] : e - NE;
    int pos = atomicAdd(&cursor[dst], 1);
    csr_src[pos] = src;
}

// ---------------- aggregation layer1: one wave per node, in-kernel softmax ------
__global__ __launch_bounds__(256) void k_agg1(
    const ushort_t* __restrict__ h1, const float* __restrict__ a_src, const float* __restrict__ a_dst,
    const int* __restrict__ row_ptr, const int* __restrict__ csr_src,
    const float* __restrict__ b1, ushort_t* __restrict__ g1)
{
    const int n = blockIdx.x * 4 + (threadIdx.x >> 6);
    const int lane = threadIdx.x & 63;
    const int head = lane >> 4;
    const int beg = row_ptr[n], end = row_ptr[n + 1];
    const float4 ad = *(const float4*)(a_dst + (size_t)n * 4);

    // pass 1: per-head max (lanes parallel)
    float mx[4] = {-1e30f, -1e30f, -1e30f, -1e30f};
    for (int p = beg + lane; p < end; p += 64) {
        int src = csr_src[p];
        float4 as = *(const float4*)(a_src + (size_t)src * 4);
        float v;
        v = as.x + ad.x; v = v >= 0.f ? v : 0.2f * v; mx[0] = fmaxf(mx[0], v);
        v = as.y + ad.y; v = v >= 0.f ? v : 0.2f * v; mx[1] = fmaxf(mx[1], v);
        v = as.z + ad.z; v = v >= 0.f ? v : 0.2f * v; mx[2] = fmaxf(mx[2], v);
        v = as.w + ad.w; v = v >= 0.f ? v : 0.2f * v; mx[3] = fmaxf(mx[3], v);
    }
#pragma unroll
    for (int o = 32; o; o >>= 1) {
        mx[0] = fmaxf(mx[0], __shfl_xor(mx[0], o));
        mx[1] = fmaxf(mx[1], __shfl_xor(mx[1], o));
        mx[2] = fmaxf(mx[2], __shfl_xor(mx[2], o));
        mx[3] = fmaxf(mx[3], __shfl_xor(mx[3], o));
    }
    const float m   = (head & 1) ? ((head & 2) ? mx[3] : mx[1]) : ((head & 2) ? mx[2] : mx[0]);
    const float adh = (head & 1) ? ((head & 2) ? ad.w : ad.y)   : ((head & 2) ? ad.z : ad.x);

    // pass 2: gather + exp + accumulate, 4-edge unroll (MLP)
    float ssum = 0.f;
    float a[8] = {0.f, 0.f, 0.f, 0.f, 0.f, 0.f, 0.f, 0.f};
    int p = beg;
#define LREL(l) ((l) >= 0.f ? (l) : 0.2f * (l))
#define ACC8(c, u) \
        a[0] = fmaf(c, bf_lo(u.x), a[0]); a[1] = fmaf(c, bf_hi(u.x), a[1]); \
        a[2] = fmaf(c, bf_lo(u.y), a[2]); a[3] = fmaf(c, bf_hi(u.y), a[3]); \
        a[4] = fmaf(c, bf_lo(u.z), a[4]); a[5] = fmaf(c, bf_hi(u.z), a[5]); \
        a[6] = fmaf(c, bf_lo(u.w), a[6]); a[7] = fmaf(c, bf_hi(u.w), a[7]);
    for (; p + 3 < end; p += 4) {
        int s0 = csr_src[p], s1 = csr_src[p + 1], s2 = csr_src[p + 2], s3 = csr_src[p + 3];
        uint4 u0 = *(const uint4*)(h1 + (size_t)s0 * F1 + lane * 8);
        uint4 u1 = *(const uint4*)(h1 + (size_t)s1 * F1 + lane * 8);
        uint4 u2 = *(const uint4*)(h1 + (size_t)s2 * F1 + lane * 8);
        uint4 u3 = *(const uint4*)(h1 + (size_t)s3 * F1 + lane * 8);
        float c0 = expf(LREL(a_src[s0 * 4 + head] + adh) - m);
        float c1 = expf(LREL(a_src[s1 * 4 + head] + adh) - m);
        float c2 = expf(LREL(a_src[s2 * 4 + head] + adh) - m);
        float c3 = expf(LREL(a_src[s3 * 4 + head] + adh) - m);
        ssum += c0 + c1 + c2 + c3;
        ACC8(c0, u0) ACC8(c1, u1) ACC8(c2, u2) ACC8(c3, u3)
    }
    for (; p < end; p++) {
        int s0 = csr_src[p];
        uint4 u0 = *(const uint4*)(h1 + (size_t)s0 * F1 + lane * 8);
        float c0 = expf(LREL(a_src[s0 * 4 + head] + adh) - m);
        ssum += c0;
        ACC8(c0, u0)
    }
#undef ACC8
    const float inv = 1.0f / (ssum + 1e-16f);
    const int ch = lane * 8;
    float4 bA = *(const float4*)(b1 + ch);
    float4 bB = *(const float4*)(b1 + ch + 4);
    uint4 ov;
    ov.x = (uint32_t)f2bf(fmaxf(fmaf(a[0], inv, bA.x), 0.f)) | ((uint32_t)f2bf(fmaxf(fmaf(a[1], inv, bA.y), 0.f)) << 16);
    ov.y = (uint32_t)f2bf(fmaxf(fmaf(a[2], inv, bA.z), 0.f)) | ((uint32_t)f2bf(fmaxf(fmaf(a[3], inv, bA.w), 0.f)) << 16);
    ov.z = (uint32_t)f2bf(fmaxf(fmaf(a[4], inv, bB.x), 0.f)) | ((uint32_t)f2bf(fmaxf(fmaf(a[5], inv, bB.y), 0.f)) << 16);
    ov.w = (uint32_t)f2bf(fmaxf(fmaf(a[6], inv, bB.z), 0.f)) | ((uint32_t)f2bf(fmaxf(fmaf(a[7], inv, bB.w), 0.f)) << 16);
    *(uint4*)(g1 + (size_t)n * F1 + ch) = ov;
}

// ---------------- aggregation layer2 + final linear: one wave per node ------
__global__ __launch_bounds__(256) void k_agg2(
    const ushort_t* __restrict__ h2, const float* __restrict__ a_src, const float* __restrict__ a_dst,
    const int* __restrict__ row_ptr, const int* __restrict__ csr_src,
    const float* __restrict__ b2, const float* __restrict__ outW, const float* __restrict__ outb,
    float* __restrict__ out)
{
    const int n = blockIdx.x * 4 + (threadIdx.x >> 6);
    const int lane = threadIdx.x & 63;
    const int beg = row_ptr[n], end = row_ptr[n + 1];
    const float ad = a_dst[n];

    // pass 1: max
    float mx = -1e30f;
    for (int p = beg + lane; p < end; p += 64) {
        float v = a_src[csr_src[p]] + ad;
        v = v >= 0.f ? v : 0.2f * v;
        mx = fmaxf(mx, v);
    }
#pragma unroll
    for (int o = 32; o; o >>= 1) mx = fmaxf(mx, __shfl_xor(mx, o));

    // pass 2: 4-edge unroll
    float ssum = 0.f;
    float a0 = 0.f, a1 = 0.f;
    int p = beg;
    for (; p + 3 < end; p += 4) {
        int s0 = csr_src[p], s1 = csr_src[p + 1], s2 = csr_src[p + 2], s3 = csr_src[p + 3];
        uint32_t u0 = *(const uint32_t*)(h2 + (size_t)s0 * F2 + lane * 2);
        uint32_t u1 = *(const uint32_t*)(h2 + (size_t)s1 * F2 + lane * 2);
        uint32_t u2 = *(const uint32_t*)(h2 + (size_t)s2 * F2 + lane * 2);
        uint32_t u3 = *(const uint32_t*)(h2 + (size_t)s3 * F2 + lane * 2);
        float c0 = expf(LREL(a_src[s0] + ad) - mx);
        float c1 = expf(LREL(a_src[s1] + ad) - mx);
        float c2 = expf(LREL(a_src[s2] + ad) - mx);
        float c3 = expf(LREL(a_src[s3] + ad) - mx);
        ssum += c0 + c1 + c2 + c3;
        a0 = fmaf(c0, bf_lo(u0), a0); a1 = fmaf(c0, bf_hi(u0), a1);
        a0 = fmaf(c1, bf_lo(u1), a0); a1 = fmaf(c1, bf_hi(u1), a1);
        a0 = fmaf(c2, bf_lo(u2), a0); a1 = fmaf(c2, bf_hi(u2), a1);
        a0 = fmaf(c3, bf_lo(u3), a0); a1 = fmaf(c3, bf_hi(u3), a1);
    }
    for (; p < end; p++) {
        int s0 = csr_src[p];
        uint32_t u0 = *(const uint32_t*)(h2 + (size_t)s0 * F2 + lane * 2);
        float c0 = expf(LREL(a_src[s0] + ad) - mx);
        ssum += c0;
        a0 = fmaf(c0, bf_lo(u0), a0); a1 = fmaf(c0, bf_hi(u0), a1);
    }
    const float inv = 1.0f / (ssum + 1e-16f);
    float v0 = fmaf(a0, inv, b2[lane * 2]);     v0 = v0 > 0.f ? v0 : 0.f;
    float v1 = fmaf(a1, inv, b2[lane * 2 + 1]); v1 = v1 > 0.f ? v1 : 0.f;
    float pr = v0 * outW[lane * 2] + v1 * outW[lane * 2 + 1];
    for (int o = 32; o; o >>= 1) pr += __shfl_xor(pr, o);
    if (lane == 0) out[n] = pr + outb[0];
}

// =======================================================================
extern "C" void kernel_launch(void* const* d_in, const int* in_sizes, int n_in,
                              void* d_out, int out_size, void* d_ws, size_t ws_size,
                              hipStream_t stream)
{
    const float* x        = (const float*)d_in[0];   // [NN, INCH]
    const float* cond     = (const float*)d_in[1];   // [NG, CONDCH]
    const float* W1       = (const float*)d_in[2];   // [INCH+CONDCH, F1]
    const float* att_src1 = (const float*)d_in[3];
    const float* att_dst1 = (const float*)d_in[4];
    const float* b1       = (const float*)d_in[5];
    const float* W2       = (const float*)d_in[6];   // [F1, F2]
    const float* att_src2 = (const float*)d_in[7];
    const float* att_dst2 = (const float*)d_in[8];
    const float* b2       = (const float*)d_in[9];
    const float* outW     = (const float*)d_in[10];
    const float* outb     = (const float*)d_in[11];
    const int*   ei       = (const int*)d_in[12];    // [2, NE]
    const int*   batch    = (const int*)d_in[13];    // [NN]
    float* out = (float*)d_out;

    // ---- workspace layout ----
    char* ws = (char*)d_ws;
    size_t off = 0;
    auto alloc = [&](size_t bytes) { void* p = ws + off; off += (bytes + 255) & ~size_t(255); return p; };
    ushort_t* xb      = (ushort_t*)alloc((size_t)MPAD * INCH * 2);    // 77.1 MB (aliased by g1b)
    ushort_t* condb   = (ushort_t*)alloc((size_t)NG * CONDCH * 2);
    ushort_t* W1aT    = (ushort_t*)alloc((size_t)F1 * INCH * 2);      // [512][768]
    ushort_t* W1cT    = (ushort_t*)alloc((size_t)F1 * CONDCH * 2);    // [512][768]
    ushort_t* W2T     = (ushort_t*)alloc((size_t)F2 * F1 * 2);        // [128][512]
    float*    C2      = (float*)alloc((size_t)NG * F1 * 4);           // [128][512]
    ushort_t* h1b     = (ushort_t*)alloc((size_t)NN * F1 * 2);        // 51.2 MB
    float*    a_src1  = (float*)alloc((size_t)NN * NHEAD * 4);
    float*    a_dst1  = (float*)alloc((size_t)NN * NHEAD * 4);
    int*      deg     = (int*)alloc((size_t)NN * 4);
    int*      cursor  = (int*)alloc((size_t)NN * 4);
    int*      row_ptr = (int*)alloc((size_t)(NN + 1) * 4);
    int*      csr_src = (int*)alloc((size_t)ET * 4);
    int*      bsum    = (int*)alloc((size_t)SCB * 4);
    int*      bbase   = (int*)alloc((size_t)SCB * 4);
    ushort_t* h2b     = (ushort_t*)alloc((size_t)NN * F2 * 2);        // 12.8 MB
    float*    a_src2  = (float*)alloc((size_t)NN * 4);
    float*    a_dst2  = (float*)alloc((size_t)NN * 4);
    ushort_t* g1b     = xb;   // alias: xb dead after GEMM1; g1b written in agg1
    (void)ws_size;

    // ---- prep: cond cvt + weight transposes + deg=1 init ----
    k_prep<<<(R3 + 255) / 256, 256, 0, stream>>>(W1, W2, cond, W1aT, W1cT, W2T, condb, deg);

    // ---- x cvt + fused edge-degree atomics ----
    {
        long n4 = (long)NN * INCH / 4;
        k_cvt_x<<<(int)((n4 + 255) / 256), 256, 0, stream>>>(x, xb, n4, ei, deg);
    }

    // ---- CSR skeleton ----
    k_deg_bsum<<<SCB, 256, 0, stream>>>(deg, bsum);
    k_bsum_scan<<<1, 256, 0, stream>>>(bsum, bbase, row_ptr);
    k_scan_final<<<SCB, 256, 0, stream>>>(deg, bbase, row_ptr, cursor);
    k_scatter<<<(ET + 255) / 256, 256, 0, stream>>>(ei, cursor, csr_src);

    // ---- C2 = cond @ W1c  -> f32 [128][512] ----
    k_mgemm<128, false, false, false><<<4, 256, 0, stream>>>(
        condb, W1cT, C2, NG, F1, CONDCH, 4,
        nullptr, nullptr, nullptr, nullptr, nullptr, nullptr, 0);
    // ---- h1 = bf16( x @ W1a + C2[batch] ), fused att1 logits ----
    k_mgemm<256, true, true, true><<<(MPAD / 256) * 4, 512, 0, stream>>>(
        xb, W1aT, h1b, NN, F1, INCH, 4,
        C2, batch, att_src1, att_dst1, a_src1, a_dst1, NHEAD);
    // ---- aggregate layer1 (in-kernel softmax, +b1, relu) -> g1 bf16 ----
    k_agg1<<<NN / 4, 256, 0, stream>>>(h1b, a_src1, a_dst1, row_ptr, csr_src, b1, g1b);
    // ---- h2 = bf16( g1 @ W2 ), fused att2 logits ----
    k_mgemm<256, false, true, true><<<MPAD / 256, 512, 0, stream>>>(
        g1b, W2T, h2b, NN, F2, F1, 1,
        nullptr, nullptr, att_src2, att_dst2, a_src2, a_dst2, 1);
    // ---- aggregate layer2 (in-kernel softmax) + final linear -> out ----
    k_agg2<<<NN / 4, 256, 0, stream>>>(h2b, a_src2, a_dst2, row_ptr, csr_src, b2, outW, outb, out);
}

// Round 10
// 278.425 us; speedup vs baseline: 5.7495x; 1.1006x over previous
//
#include <hip/hip_runtime.h>
#include <hip/hip_bf16.h>
#include <cstdint>
#include <cstddef>

#define NN 50000        // nodes
#define NE 400000       // edges (without self loops)
#define NG 128          // graphs
#define INCH 768
#define CONDCH 768
#define HIDD 128
#define NHEAD 4
#define F1 (NHEAD * HIDD)   // 512
#define F2 HIDD             // 128
#define MPAD 50176          // 196 * 256
#define CAP 64              // per-node edge bucket capacity (deg ~ Poisson(8))

typedef unsigned short ushort_t;
typedef float f32x4 __attribute__((ext_vector_type(4)));
typedef __bf16 bf16x8 __attribute__((ext_vector_type(8)));

typedef const void __attribute__((address_space(1))) as1_void;
typedef void __attribute__((address_space(3))) as3_void;

__device__ __forceinline__ void gload_lds16(const void* g, void* l) {
    __builtin_amdgcn_global_load_lds((as1_void*)g, (as3_void*)l, 16, 0, 0);
}

__device__ __forceinline__ ushort_t f2bf(float f) {
    uint32_t u = __float_as_uint(f);
    uint32_t r = (u + 0x7fffu + ((u >> 16) & 1u)) >> 16;
    return (ushort_t)r;
}
__device__ __forceinline__ float bf_lo(uint32_t u) { return __uint_as_float(u << 16); }
__device__ __forceinline__ float bf_hi(uint32_t u) { return __uint_as_float(u & 0xffff0000u); }

// ---------------- k_prep: cond->bf16, weight transposes, bucket seed -----------
// idx<NN: cursor=1, csr[n*CAP]=n (self loop). cond idx<CND4 float4 cvt. weights [0,R3).
#define R1 (F1 * INCH)
#define R2 (R1 + F1 * CONDCH)
#define R3 (R2 + F2 * F1)
#define CND4 (NG * CONDCH / 4)
__global__ __launch_bounds__(256) void k_prep(
    const float* __restrict__ W1, const float* __restrict__ W2, const float* __restrict__ cond,
    ushort_t* __restrict__ W1aT, ushort_t* __restrict__ W1cT, ushort_t* __restrict__ W2T,
    ushort_t* __restrict__ condb, int* __restrict__ cursor, int* __restrict__ csr_src)
{
    int idx = blockIdx.x * blockDim.x + threadIdx.x;
    if (idx < NN) {
        cursor[idx] = 1;                       // self-loop pre-seeded
        csr_src[(size_t)idx * CAP] = idx;
    }
    if (idx < CND4) {
        float4 v = *(const float4*)(cond + (size_t)idx * 4);
        ushort4 o;
        o.x = f2bf(v.x); o.y = f2bf(v.y); o.z = f2bf(v.z); o.w = f2bf(v.w);
        *(ushort4*)(condb + (size_t)idx * 4) = o;
    }
    if (idx >= R3) return;
    if (idx < R1) {
        int n = idx / INCH, k = idx % INCH;
        W1aT[idx] = f2bf(W1[(size_t)k * F1 + n]);
    } else if (idx < R2) {
        int j = idx - R1;
        int n = j / CONDCH, k = j % CONDCH;
        W1cT[j] = f2bf(W1[(size_t)(INCH + k) * F1 + n]);
    } else {
        int j = idx - R2;
        int n = j / F1, k = j % F1;
        W2T[j] = f2bf(W2[(size_t)k * F2 + n]);
    }
}

// ---------------- x -> bf16 convert + fused bucket scatter ---------------------
__global__ __launch_bounds__(256) void k_cvt_x(const float* __restrict__ in,
                                               ushort_t* __restrict__ out, long n4,
                                               const int* __restrict__ ei,
                                               int* __restrict__ cursor,
                                               int* __restrict__ csr_src) {
    long i = (long)blockIdx.x * blockDim.x + threadIdx.x;
    if (i < NE) {
        int src = ei[i];
        int dst = ei[NE + i];
        int pos = atomicAdd(&cursor[dst], 1);
        csr_src[(size_t)dst * CAP + pos] = src;
    }
    if (i >= n4) return;
    float4 v = *(const float4*)(in + i * 4);
    ushort4 o;
    o.x = f2bf(v.x); o.y = f2bf(v.y); o.z = f2bf(v.z); o.w = f2bf(v.w);
    *(ushort4*)(out + i * 4) = o;
}

// ---------------- bf16 MFMA GEMM: C[M,N] = A[M,K] @ BT[N,K]^T (+G[gidx[m],:]) ----
// TM x 128 tile, double-buffered LDS, 1 barrier per K-step:
//   { vmcnt(0); s_barrier; STAGE(t+1 -> buf^1); compute buf }
// 1-D grid, XCD-chunked bijective swizzle, n-fast ordering.
// FUSE_ATT: per-row dots with attS/attD -> aS/aD[m*attStride + by].
template <int TM, bool ADD_GATHER, bool OUT_BF16, bool FUSE_ATT>
__global__ __launch_bounds__(TM * 2) void k_mgemm(
    const ushort_t* __restrict__ A, const ushort_t* __restrict__ BT, void* __restrict__ Cv,
    int M, int N, int K, int nBN,
    const float* __restrict__ G, const int* __restrict__ gidx,
    const float* __restrict__ attS, const float* __restrict__ attD,
    float* __restrict__ aS, float* __restrict__ aD, int attStride)
{
    constexpr int SA = TM * 64;     // bytes per A buffer (TM rows x 64B)
    constexpr int SB = 8192;        // bytes per B buffer (128 rows x 64B)
    __shared__ __align__(16) char smem[2 * SA + 2 * SB];
    char* sA = smem;
    char* sB = smem + 2 * SA;

    const int nwg = gridDim.x;
    const int orig = blockIdx.x;
    const int q = nwg >> 3, r = nwg & 7;
    const int xcd = orig & 7, sid = orig >> 3;
    const int wg = (xcd < r ? xcd * (q + 1) : r * (q + 1) + (xcd - r) * q) + sid;
    const int bx = wg / nBN, by = wg % nBN;

    const int tid = threadIdx.x;
    const int lane = tid & 63;
    const int wave = tid >> 6;
    const int wr = wave >> 1, wc = wave & 1;
    const int m0 = bx * TM, n0 = by * 128;

    const int sr = tid >> 2;
    const int sc = (tid & 3) * 8;
    const ushort_t* gA = A + (size_t)(m0 + sr) * K + sc;
    const ushort_t* gB = BT + (size_t)(n0 + sr) * K + sc;
    const int ldsw = wave * 1024;

    const int a_off = (wr * 64 + (lane & 15)) * 64 + (lane >> 4) * 16;
    const int b_off = (wc * 64 + (lane & 15)) * 64 + (lane >> 4) * 16;

    auto STAGE = [&](int kt, int b) {
        char* dA = sA + b * SA + ldsw;
        gload_lds16(gA + kt, dA);
        gload_lds16(gA + (size_t)(TM / 2) * K + kt, dA + SA / 2);
        char* dB = sB + b * SB + ldsw;
        gload_lds16(gB + kt, dB);
        if (TM == 128)
            gload_lds16(gB + (size_t)64 * K + kt, dB + 4096);
    };

    f32x4 acc[4][4];
#pragma unroll
    for (int i = 0; i < 4; i++)
#pragma unroll
        for (int j = 0; j < 4; j++) acc[i][j] = 0.f;

    STAGE(0, 0);
    const int nt = K / 32;   // even for K in {768, 512}
    for (int t = 0; t < nt; t++) {
        const int cur = t & 1;
        asm volatile("s_waitcnt vmcnt(0)" ::: "memory");   // stage(t) landed
        __builtin_amdgcn_s_barrier();
        __builtin_amdgcn_sched_barrier(0);
        if (t + 1 < nt) STAGE((t + 1) * 32, cur ^ 1);      // in flight across compute
        bf16x8 af[4], bfr[4];
#pragma unroll
        for (int i = 0; i < 4; i++) af[i]  = *(const bf16x8*)(sA + cur * SA + a_off + i * 1024);
#pragma unroll
        for (int j = 0; j < 4; j++) bfr[j] = *(const bf16x8*)(sB + cur * SB + b_off + j * 1024);
#pragma unroll
        for (int i = 0; i < 4; i++)
#pragma unroll
            for (int j = 0; j < 4; j++)
                acc[i][j] = __builtin_amdgcn_mfma_f32_16x16x32_bf16(af[i], bfr[j], acc[i][j], 0, 0, 0);
    }
    // nt even => last compute read buffer 1; epilogue reuses buffer-0 region.

    float asv[4], adv[4];
    if (FUSE_ATT) {
#pragma unroll
        for (int j = 0; j < 4; j++) {
            int col = wc * 64 + j * 16 + (lane & 15);
            asv[j] = attS[by * 128 + col];
            adv[j] = attD[by * 128 + col];
        }
    }
    float* redS = (float*)smem;              // [2(wc)][TM]  (buffer-0 region)
    float* redD = (float*)smem + 2 * TM;

#pragma unroll
    for (int i = 0; i < 4; i++) {
        int mbase = m0 + wr * 64 + i * 16 + (lane >> 4) * 4;
#pragma unroll
        for (int rr = 0; rr < 4; rr++) {
            int m = mbase + rr;
            if (m >= M) continue;
            const float* grow = nullptr;
            if (ADD_GATHER) grow = G + (size_t)gidx[m] * N;
            float vs = 0.f, vd = 0.f;
#pragma unroll
            for (int j = 0; j < 4; j++) {
                int n = n0 + wc * 64 + j * 16 + (lane & 15);
                float v = acc[i][j][rr];
                if (ADD_GATHER) v += grow[n];
                if (OUT_BF16) ((ushort_t*)Cv)[(size_t)m * N + n] = f2bf(v);
                else          ((float*)Cv)[(size_t)m * N + n] = v;
                if (FUSE_ATT) { vs = fmaf(v, asv[j], vs); vd = fmaf(v, adv[j], vd); }
            }
            if (FUSE_ATT) {
#pragma unroll
                for (int o = 1; o < 16; o <<= 1) { vs += __shfl_xor(vs, o); vd += __shfl_xor(vd, o); }
                if ((lane & 15) == 0) {
                    int mloc = wr * 64 + i * 16 + (lane >> 4) * 4 + rr;
                    redS[wc * TM + mloc] = vs;
                    redD[wc * TM + mloc] = vd;
                }
            }
        }
    }
    if (FUSE_ATT) {
        __syncthreads();
        int sd = tid >= TM ? 1 : 0, mloc = tid & (TM - 1);
        int m = m0 + mloc;
        if (m < M) {
            const float* rb = sd ? redD : redS;
            float v = rb[mloc] + rb[TM + mloc];
            (sd ? aD : aS)[(size_t)m * attStride + by] = v;
        }
    }
}

// ---------------- aggregation layer1: one wave per node, in-kernel softmax ------
__global__ __launch_bounds__(256) void k_agg1(
    const ushort_t* __restrict__ h1, const float* __restrict__ a_src, const float* __restrict__ a_dst,
    const int* __restrict__ cnt, const int* __restrict__ csr_src,
    const float* __restrict__ b1, ushort_t* __restrict__ g1)
{
    const int n = blockIdx.x * 4 + (threadIdx.x >> 6);
    const int lane = threadIdx.x & 63;
    const int head = lane >> 4;
    const int beg = n * CAP;
    const int end = beg + cnt[n];
    const float4 ad = *(const float4*)(a_dst + (size_t)n * 4);

    // pass 1: per-head max (lanes parallel; deg<=CAP=64 -> single iteration)
    float mx[4] = {-1e30f, -1e30f, -1e30f, -1e30f};
    for (int p = beg + lane; p < end; p += 64) {
        int src = csr_src[p];
        float4 as = *(const float4*)(a_src + (size_t)src * 4);
        float v;
        v = as.x + ad.x; v = v >= 0.f ? v : 0.2f * v; mx[0] = fmaxf(mx[0], v);
        v = as.y + ad.y; v = v >= 0.f ? v : 0.2f * v; mx[1] = fmaxf(mx[1], v);
        v = as.z + ad.z; v = v >= 0.f ? v : 0.2f * v; mx[2] = fmaxf(mx[2], v);
        v = as.w + ad.w; v = v >= 0.f ? v : 0.2f * v; mx[3] = fmaxf(mx[3], v);
    }
#pragma unroll
    for (int o = 32; o; o >>= 1) {
        mx[0] = fmaxf(mx[0], __shfl_xor(mx[0], o));
        mx[1] = fmaxf(mx[1], __shfl_xor(mx[1], o));
        mx[2] = fmaxf(mx[2], __shfl_xor(mx[2], o));
        mx[3] = fmaxf(mx[3], __shfl_xor(mx[3], o));
    }
    const float m   = (head & 1) ? ((head & 2) ? mx[3] : mx[1]) : ((head & 2) ? mx[2] : mx[0]);
    const float adh = (head & 1) ? ((head & 2) ? ad.w : ad.y)   : ((head & 2) ? ad.z : ad.x);

    // pass 2: gather + exp + accumulate, 4-edge unroll
    float ssum = 0.f;
    float a[8] = {0.f, 0.f, 0.f, 0.f, 0.f, 0.f, 0.f, 0.f};
    int p = beg;
#define LREL(l) ((l) >= 0.f ? (l) : 0.2f * (l))
#define ACC8(c, u) \
        a[0] = fmaf(c, bf_lo(u.x), a[0]); a[1] = fmaf(c, bf_hi(u.x), a[1]); \
        a[2] = fmaf(c, bf_lo(u.y), a[2]); a[3] = fmaf(c, bf_hi(u.y), a[3]); \
        a[4] = fmaf(c, bf_lo(u.z), a[4]); a[5] = fmaf(c, bf_hi(u.z), a[5]); \
        a[6] = fmaf(c, bf_lo(u.w), a[6]); a[7] = fmaf(c, bf_hi(u.w), a[7]);
    for (; p + 3 < end; p += 4) {
        int s0 = csr_src[p], s1 = csr_src[p + 1], s2 = csr_src[p + 2], s3 = csr_src[p + 3];
        uint4 u0 = *(const uint4*)(h1 + (size_t)s0 * F1 + lane * 8);
        uint4 u1 = *(const uint4*)(h1 + (size_t)s1 * F1 + lane * 8);
        uint4 u2 = *(const uint4*)(h1 + (size_t)s2 * F1 + lane * 8);
        uint4 u3 = *(const uint4*)(h1 + (size_t)s3 * F1 + lane * 8);
        float c0 = expf(LREL(a_src[s0 * 4 + head] + adh) - m);
        float c1 = expf(LREL(a_src[s1 * 4 + head] + adh) - m);
        float c2 = expf(LREL(a_src[s2 * 4 + head] + adh) - m);
        float c3 = expf(LREL(a_src[s3 * 4 + head] + adh) - m);
        ssum += c0 + c1 + c2 + c3;
        ACC8(c0, u0) ACC8(c1, u1) ACC8(c2, u2) ACC8(c3, u3)
    }
    for (; p < end; p++) {
        int s0 = csr_src[p];
        uint4 u0 = *(const uint4*)(h1 + (size_t)s0 * F1 + lane * 8);
        float c0 = expf(LREL(a_src[s0 * 4 + head] + adh) - m);
        ssum += c0;
        ACC8(c0, u0)
    }
#undef ACC8
    const float inv = 1.0f / (ssum + 1e-16f);
    const int ch = lane * 8;
    float4 bA = *(const float4*)(b1 + ch);
    float4 bB = *(const float4*)(b1 + ch + 4);
    uint4 ov;
    ov.x = (uint32_t)f2bf(fmaxf(fmaf(a[0], inv, bA.x), 0.f)) | ((uint32_t)f2bf(fmaxf(fmaf(a[1], inv, bA.y), 0.f)) << 16);
    ov.y = (uint32_t)f2bf(fmaxf(fmaf(a[2], inv, bA.z), 0.f)) | ((uint32_t)f2bf(fmaxf(fmaf(a[3], inv, bA.w), 0.f)) << 16);
    ov.z = (uint32_t)f2bf(fmaxf(fmaf(a[4], inv, bB.x), 0.f)) | ((uint32_t)f2bf(fmaxf(fmaf(a[5], inv, bB.y), 0.f)) << 16);
    ov.w = (uint32_t)f2bf(fmaxf(fmaf(a[6], inv, bB.z), 0.f)) | ((uint32_t)f2bf(fmaxf(fmaf(a[7], inv, bB.w), 0.f)) << 16);
    *(uint4*)(g1 + (size_t)n * F1 + ch) = ov;
}

// ---------------- aggregation layer2 + final linear: one wave per node ------
__global__ __launch_bounds__(256) void k_agg2(
    const ushort_t* __restrict__ h2, const float* __restrict__ a_src, const float* __restrict__ a_dst,
    const int* __restrict__ cnt, const int* __restrict__ csr_src,
    const float* __restrict__ b2, const float* __restrict__ outW, const float* __restrict__ outb,
    float* __restrict__ out)
{
    const int n = blockIdx.x * 4 + (threadIdx.x >> 6);
    const int lane = threadIdx.x & 63;
    const int beg = n * CAP;
    const int end = beg + cnt[n];
    const float ad = a_dst[n];

    // pass 1: max
    float mx = -1e30f;
    for (int p = beg + lane; p < end; p += 64) {
        float v = a_src[csr_src[p]] + ad;
        v = v >= 0.f ? v : 0.2f * v;
        mx = fmaxf(mx, v);
    }
#pragma unroll
    for (int o = 32; o; o >>= 1) mx = fmaxf(mx, __shfl_xor(mx, o));

    // pass 2: 4-edge unroll
    float ssum = 0.f;
    float a0 = 0.f, a1 = 0.f;
    int p = beg;
    for (; p + 3 < end; p += 4) {
        int s0 = csr_src[p], s1 = csr_src[p + 1], s2 = csr_src[p + 2], s3 = csr_src[p + 3];
        uint32_t u0 = *(const uint32_t*)(h2 + (size_t)s0 * F2 + lane * 2);
        uint32_t u1 = *(const uint32_t*)(h2 + (size_t)s1 * F2 + lane * 2);
        uint32_t u2 = *(const uint32_t*)(h2 + (size_t)s2 * F2 + lane * 2);
        uint32_t u3 = *(const uint32_t*)(h2 + (size_t)s3 * F2 + lane * 2);
        float c0 = expf(LREL(a_src[s0] + ad) - mx);
        float c1 = expf(LREL(a_src[s1] + ad) - mx);
        float c2 = expf(LREL(a_src[s2] + ad) - mx);
        float c3 = expf(LREL(a_src[s3] + ad) - mx);
        ssum += c0 + c1 + c2 + c3;
        a0 = fmaf(c0, bf_lo(u0), a0); a1 = fmaf(c0, bf_hi(u0), a1);
        a0 = fmaf(c1, bf_lo(u1), a0); a1 = fmaf(c1, bf_hi(u1), a1);
        a0 = fmaf(c2, bf_lo(u2), a0); a1 = fmaf(c2, bf_hi(u2), a1);
        a0 = fmaf(c3, bf_lo(u3), a0); a1 = fmaf(c3, bf_hi(u3), a1);
    }
    for (; p < end; p++) {
        int s0 = csr_src[p];
        uint32_t u0 = *(const uint32_t*)(h2 + (size_t)s0 * F2 + lane * 2);
        float c0 = expf(LREL(a_src[s0] + ad) - mx);
        ssum += c0;
        a0 = fmaf(c0, bf_lo(u0), a0); a1 = fmaf(c0, bf_hi(u0), a1);
    }
    const float inv = 1.0f / (ssum + 1e-16f);
    float v0 = fmaf(a0, inv, b2[lane * 2]);     v0 = v0 > 0.f ? v0 : 0.f;
    float v1 = fmaf(a1, inv, b2[lane * 2 + 1]); v1 = v1 > 0.f ? v1 : 0.f;
    float pr = v0 * outW[lane * 2] + v1 * outW[lane * 2 + 1];
    for (int o = 32; o; o >>= 1) pr += __shfl_xor(pr, o);
    if (lane == 0) out[n] = pr + outb[0];
}

// =======================================================================
extern "C" void kernel_launch(void* const* d_in, const int* in_sizes, int n_in,
                              void* d_out, int out_size, void* d_ws, size_t ws_size,
                              hipStream_t stream)
{
    const float* x        = (const float*)d_in[0];   // [NN, INCH]
    const float* cond     = (const float*)d_in[1];   // [NG, CONDCH]
    const float* W1       = (const float*)d_in[2];   // [INCH+CONDCH, F1]
    const float* att_src1 = (const float*)d_in[3];
    const float* att_dst1 = (const float*)d_in[4];
    const float* b1       = (const float*)d_in[5];
    const float* W2       = (const float*)d_in[6];   // [F1, F2]
    const float* att_src2 = (const float*)d_in[7];
    const float* att_dst2 = (const float*)d_in[8];
    const float* b2       = (const float*)d_in[9];
    const float* outW     = (const float*)d_in[10];
    const float* outb     = (const float*)d_in[11];
    const int*   ei       = (const int*)d_in[12];    // [2, NE]
    const int*   batch    = (const int*)d_in[13];    // [NN]
    float* out = (float*)d_out;

    // ---- workspace layout ----
    char* ws = (char*)d_ws;
    size_t off = 0;
    auto alloc = [&](size_t bytes) { void* p = ws + off; off += (bytes + 255) & ~size_t(255); return p; };
    ushort_t* xb      = (ushort_t*)alloc((size_t)MPAD * INCH * 2);    // 77.1 MB (aliased by g1b)
    ushort_t* condb   = (ushort_t*)alloc((size_t)NG * CONDCH * 2);
    ushort_t* W1aT    = (ushort_t*)alloc((size_t)F1 * INCH * 2);      // [512][768]
    ushort_t* W1cT    = (ushort_t*)alloc((size_t)F1 * CONDCH * 2);    // [512][768]
    ushort_t* W2T     = (ushort_t*)alloc((size_t)F2 * F1 * 2);        // [128][512]
    float*    C2      = (float*)alloc((size_t)NG * F1 * 4);           // [128][512]
    ushort_t* h1b     = (ushort_t*)alloc((size_t)NN * F1 * 2);        // 51.2 MB
    float*    a_src1  = (float*)alloc((size_t)NN * NHEAD * 4);
    float*    a_dst1  = (float*)alloc((size_t)NN * NHEAD * 4);
    int*      cursor  = (int*)alloc((size_t)NN * 4);
    int*      csr_src = (int*)alloc((size_t)NN * CAP * 4);            // 12.8 MB buckets
    ushort_t* h2b     = (ushort_t*)alloc((size_t)NN * F2 * 2);        // 12.8 MB
    float*    a_src2  = (float*)alloc((size_t)NN * 4);
    float*    a_dst2  = (float*)alloc((size_t)NN * 4);
    ushort_t* g1b     = xb;   // alias: xb dead after GEMM1; g1b written in agg1
    (void)ws_size;

    // ---- prep: cond cvt + weight transposes + bucket seed (cursor=1, self loop) ----
    k_prep<<<(R3 + 255) / 256, 256, 0, stream>>>(W1, W2, cond, W1aT, W1cT, W2T, condb,
                                                 cursor, csr_src);

    // ---- x cvt + fused bucket scatter ----
    {
        long n4 = (long)NN * INCH / 4;
        k_cvt_x<<<(int)((n4 + 255) / 256), 256, 0, stream>>>(x, xb, n4, ei, cursor, csr_src);
    }

    // ---- C2 = cond @ W1c  -> f32 [128][512] ----
    k_mgemm<128, false, false, false><<<4, 256, 0, stream>>>(
        condb, W1cT, C2, NG, F1, CONDCH, 4,
        nullptr, nullptr, nullptr, nullptr, nullptr, nullptr, 0);
    // ---- h1 = bf16( x @ W1a + C2[batch] ), fused att1 logits ----
    k_mgemm<256, true, true, true><<<(MPAD / 256) * 4, 512, 0, stream>>>(
        xb, W1aT, h1b, NN, F1, INCH, 4,
        C2, batch, att_src1, att_dst1, a_src1, a_dst1, NHEAD);
    // ---- aggregate layer1 (in-kernel softmax, +b1, relu) -> g1 bf16 ----
    k_agg1<<<NN / 4, 256, 0, stream>>>(h1b, a_src1, a_dst1, cursor, csr_src, b1, g1b);
    // ---- h2 = bf16( g1 @ W2 ), fused att2 logits (TM=128: 392 blocks, better balance) ----
    k_mgemm<128, false, true, true><<<MPAD / 128, 256, 0, stream>>>(
        g1b, W2T, h2b, NN, F2, F1, 1,
        nullptr, nullptr, att_src2, att_dst2, a_src2, a_dst2, 1);
    // ---- aggregate layer2 (in-kernel softmax) + final linear -> out ----
    k_agg2<<<NN / 4, 256, 0, stream>>>(h2b, a_src2, a_dst2, cursor, csr_src, b2, outW, outb, out);
}

// Round 11
// 277.531 us; speedup vs baseline: 5.7681x; 1.0032x over previous
//
#include <hip/hip_runtime.h>
#include <hip/hip_bf16.h>
#include <cstdint>
#include <cstddef>

#define NN 50000        // nodes
#define NE 400000       // edges (without self loops)
#define NG 128          // graphs
#define INCH 768
#define CONDCH 768
#define HIDD 128
#define NHEAD 4
#define F1 (NHEAD * HIDD)   // 512
#define F2 HIDD             // 128
#define MPAD 50176          // 196 * 256
#define CAP 64              // per-node edge bucket capacity (deg ~ Poisson(8))

typedef unsigned short ushort_t;
typedef float f32x4 __attribute__((ext_vector_type(4)));
typedef __bf16 bf16x8 __attribute__((ext_vector_type(8)));

typedef const void __attribute__((address_space(1))) as1_void;
typedef void __attribute__((address_space(3))) as3_void;

__device__ __forceinline__ void gload_lds16(const void* g, void* l) {
    __builtin_amdgcn_global_load_lds((as1_void*)g, (as3_void*)l, 16, 0, 0);
}

__device__ __forceinline__ ushort_t f2bf(float f) {
    uint32_t u = __float_as_uint(f);
    uint32_t r = (u + 0x7fffu + ((u >> 16) & 1u)) >> 16;
    return (ushort_t)r;
}
__device__ __forceinline__ uint32_t pack2(float a, float b) {
    return (uint32_t)f2bf(a) | ((uint32_t)f2bf(b) << 16);
}
__device__ __forceinline__ float bf_lo(uint32_t u) { return __uint_as_float(u << 16); }
__device__ __forceinline__ float bf_hi(uint32_t u) { return __uint_as_float(u & 0xffff0000u); }

// ---------------- k_prep: cond->bf16, weight transposes, bucket seed -----------
#define R1 (F1 * INCH)
#define R2 (R1 + F1 * CONDCH)
#define R3 (R2 + F2 * F1)
#define CND4 (NG * CONDCH / 4)
__global__ __launch_bounds__(256) void k_prep(
    const float* __restrict__ W1, const float* __restrict__ W2, const float* __restrict__ cond,
    ushort_t* __restrict__ W1aT, ushort_t* __restrict__ W1cT, ushort_t* __restrict__ W2T,
    ushort_t* __restrict__ condb, int* __restrict__ cursor, int* __restrict__ csr_src)
{
    int idx = blockIdx.x * blockDim.x + threadIdx.x;
    if (idx < NN) {
        cursor[idx] = 1;                       // self-loop pre-seeded
        csr_src[(size_t)idx * CAP] = idx;
    }
    if (idx < CND4) {
        float4 v = *(const float4*)(cond + (size_t)idx * 4);
        ushort4 o;
        o.x = f2bf(v.x); o.y = f2bf(v.y); o.z = f2bf(v.z); o.w = f2bf(v.w);
        *(ushort4*)(condb + (size_t)idx * 4) = o;
    }
    if (idx >= R3) return;
    if (idx < R1) {
        int n = idx / INCH, k = idx % INCH;
        W1aT[idx] = f2bf(W1[(size_t)k * F1 + n]);
    } else if (idx < R2) {
        int j = idx - R1;
        int n = j / CONDCH, k = j % CONDCH;
        W1cT[j] = f2bf(W1[(size_t)(INCH + k) * F1 + n]);
    } else {
        int j = idx - R2;
        int n = j / F1, k = j % F1;
        W2T[j] = f2bf(W2[(size_t)k * F2 + n]);
    }
}

// ---------------- edge scatter into buckets (standalone) -----------------------
__global__ __launch_bounds__(256) void k_scat(const int* __restrict__ ei,
                                              int* __restrict__ cursor,
                                              int* __restrict__ csr_src) {
    int e = blockIdx.x * blockDim.x + threadIdx.x;
    if (e >= NE) return;
    int src = ei[e];
    int dst = ei[NE + e];
    int pos = atomicAdd(&cursor[dst], 1);
    csr_src[(size_t)dst * CAP + pos] = src;
}

// ---------------- x -> bf16 pure convert, 8 elems/thread -----------------------
__global__ __launch_bounds__(256) void k_cvt8(const float* __restrict__ in,
                                              ushort_t* __restrict__ out, long n8) {
    long i = (long)blockIdx.x * blockDim.x + threadIdx.x;
    if (i >= n8) return;
    float4 v0 = *(const float4*)(in + i * 8);
    float4 v1 = *(const float4*)(in + i * 8 + 4);
    uint4 o;
    o.x = pack2(v0.x, v0.y);
    o.y = pack2(v0.z, v0.w);
    o.z = pack2(v1.x, v1.y);
    o.w = pack2(v1.z, v1.w);
    *(uint4*)(out + i * 8) = o;
}

// ---------------- bf16 MFMA GEMM: C[M,N] = A[M,K] @ BT[N,K]^T (+G[gidx[m],:]) ----
// TM x 128 tile, double-buffered LDS, 1 barrier per K-step:
//   { vmcnt(0); s_barrier; STAGE(t+1 -> buf^1); compute buf }
// 1-D grid, XCD-chunked bijective swizzle, n-fast ordering.
// FUSE_ATT: per-row dots with attS/attD -> aS/aD[m*attStride + by].
template <int TM, bool ADD_GATHER, bool OUT_BF16, bool FUSE_ATT>
__global__ __launch_bounds__(TM * 2) void k_mgemm(
    const ushort_t* __restrict__ A, const ushort_t* __restrict__ BT, void* __restrict__ Cv,
    int M, int N, int K, int nBN,
    const float* __restrict__ G, const int* __restrict__ gidx,
    const float* __restrict__ attS, const float* __restrict__ attD,
    float* __restrict__ aS, float* __restrict__ aD, int attStride)
{
    constexpr int SA = TM * 64;     // bytes per A buffer (TM rows x 64B)
    constexpr int SB = 8192;        // bytes per B buffer (128 rows x 64B)
    __shared__ __align__(16) char smem[2 * SA + 2 * SB];
    char* sA = smem;
    char* sB = smem + 2 * SA;

    const int nwg = gridDim.x;
    const int orig = blockIdx.x;
    const int q = nwg >> 3, r = nwg & 7;
    const int xcd = orig & 7, sid = orig >> 3;
    const int wg = (xcd < r ? xcd * (q + 1) : r * (q + 1) + (xcd - r) * q) + sid;
    const int bx = wg / nBN, by = wg % nBN;

    const int tid = threadIdx.x;
    const int lane = tid & 63;
    const int wave = tid >> 6;
    const int wr = wave >> 1, wc = wave & 1;
    const int m0 = bx * TM, n0 = by * 128;

    const int sr = tid >> 2;
    const int sc = (tid & 3) * 8;
    const ushort_t* gA = A + (size_t)(m0 + sr) * K + sc;
    const ushort_t* gB = BT + (size_t)(n0 + sr) * K + sc;
    const int ldsw = wave * 1024;

    const int a_off = (wr * 64 + (lane & 15)) * 64 + (lane >> 4) * 16;
    const int b_off = (wc * 64 + (lane & 15)) * 64 + (lane >> 4) * 16;

    auto STAGE = [&](int kt, int b) {
        char* dA = sA + b * SA + ldsw;
        gload_lds16(gA + kt, dA);
        gload_lds16(gA + (size_t)(TM / 2) * K + kt, dA + SA / 2);
        char* dB = sB + b * SB + ldsw;
        gload_lds16(gB + kt, dB);
        if (TM == 128)
            gload_lds16(gB + (size_t)64 * K + kt, dB + 4096);
    };

    f32x4 acc[4][4];
#pragma unroll
    for (int i = 0; i < 4; i++)
#pragma unroll
        for (int j = 0; j < 4; j++) acc[i][j] = 0.f;

    STAGE(0, 0);
    const int nt = K / 32;   // even for K in {768, 512}
    for (int t = 0; t < nt; t++) {
        const int cur = t & 1;
        asm volatile("s_waitcnt vmcnt(0)" ::: "memory");   // stage(t) landed
        __builtin_amdgcn_s_barrier();
        __builtin_amdgcn_sched_barrier(0);
        if (t + 1 < nt) STAGE((t + 1) * 32, cur ^ 1);      // in flight across compute
        bf16x8 af[4], bfr[4];
#pragma unroll
        for (int i = 0; i < 4; i++) af[i]  = *(const bf16x8*)(sA + cur * SA + a_off + i * 1024);
#pragma unroll
        for (int j = 0; j < 4; j++) bfr[j] = *(const bf16x8*)(sB + cur * SB + b_off + j * 1024);
#pragma unroll
        for (int i = 0; i < 4; i++)
#pragma unroll
            for (int j = 0; j < 4; j++)
                acc[i][j] = __builtin_amdgcn_mfma_f32_16x16x32_bf16(af[i], bfr[j], acc[i][j], 0, 0, 0);
    }
    // nt even => last compute read buffer 1; epilogue reuses buffer-0 region.

    float asv[4], adv[4];
    if (FUSE_ATT) {
#pragma unroll
        for (int j = 0; j < 4; j++) {
            int col = wc * 64 + j * 16 + (lane & 15);
            asv[j] = attS[by * 128 + col];
            adv[j] = attD[by * 128 + col];
        }
    }
    float* redS = (float*)smem;              // [2(wc)][TM]  (buffer-0 region)
    float* redD = (float*)smem + 2 * TM;

#pragma unroll
    for (int i = 0; i < 4; i++) {
        int mbase = m0 + wr * 64 + i * 16 + (lane >> 4) * 4;
#pragma unroll
        for (int rr = 0; rr < 4; rr++) {
            int m = mbase + rr;
            if (m >= M) continue;
            const float* grow = nullptr;
            if (ADD_GATHER) grow = G + (size_t)gidx[m] * N;
            float vs = 0.f, vd = 0.f;
#pragma unroll
            for (int j = 0; j < 4; j++) {
                int n = n0 + wc * 64 + j * 16 + (lane & 15);
                float v = acc[i][j][rr];
                if (ADD_GATHER) v += grow[n];
                if (OUT_BF16) ((ushort_t*)Cv)[(size_t)m * N + n] = f2bf(v);
                else          ((float*)Cv)[(size_t)m * N + n] = v;
                if (FUSE_ATT) { vs = fmaf(v, asv[j], vs); vd = fmaf(v, adv[j], vd); }
            }
            if (FUSE_ATT) {
#pragma unroll
                for (int o = 1; o < 16; o <<= 1) { vs += __shfl_xor(vs, o); vd += __shfl_xor(vd, o); }
                if ((lane & 15) == 0) {
                    int mloc = wr * 64 + i * 16 + (lane >> 4) * 4 + rr;
                    redS[wc * TM + mloc] = vs;
                    redD[wc * TM + mloc] = vd;
                }
            }
        }
    }
    if (FUSE_ATT) {
        __syncthreads();
        int sd = tid >= TM ? 1 : 0, mloc = tid & (TM - 1);
        int m = m0 + mloc;
        if (m < M) {
            const float* rb = sd ? redD : redS;
            float v = rb[mloc] + rb[TM + mloc];
            (sd ? aD : aS)[(size_t)m * attStride + by] = v;
        }
    }
}

// ---------------- aggregation layer1: one wave per node, in-kernel softmax ------
__global__ __launch_bounds__(256) void k_agg1(
    const ushort_t* __restrict__ h1, const float* __restrict__ a_src, const float* __restrict__ a_dst,
    const int* __restrict__ cnt, const int* __restrict__ csr_src,
    const float* __restrict__ b1, ushort_t* __restrict__ g1)
{
    const int n = blockIdx.x * 4 + (threadIdx.x >> 6);
    const int lane = threadIdx.x & 63;
    const int head = lane >> 4;
    const int beg = n * CAP;
    const int end = beg + cnt[n];
    const float4 ad = *(const float4*)(a_dst + (size_t)n * 4);

    // pass 1: per-head max (lanes parallel; deg<=CAP=64 -> single iteration)
    float mx[4] = {-1e30f, -1e30f, -1e30f, -1e30f};
    for (int p = beg + lane; p < end; p += 64) {
        int src = csr_src[p];
        float4 as = *(const float4*)(a_src + (size_t)src * 4);
        float v;
        v = as.x + ad.x; v = v >= 0.f ? v : 0.2f * v; mx[0] = fmaxf(mx[0], v);
        v = as.y + ad.y; v = v >= 0.f ? v : 0.2f * v; mx[1] = fmaxf(mx[1], v);
        v = as.z + ad.z; v = v >= 0.f ? v : 0.2f * v; mx[2] = fmaxf(mx[2], v);
        v = as.w + ad.w; v = v >= 0.f ? v : 0.2f * v; mx[3] = fmaxf(mx[3], v);
    }
#pragma unroll
    for (int o = 32; o; o >>= 1) {
        mx[0] = fmaxf(mx[0], __shfl_xor(mx[0], o));
        mx[1] = fmaxf(mx[1], __shfl_xor(mx[1], o));
        mx[2] = fmaxf(mx[2], __shfl_xor(mx[2], o));
        mx[3] = fmaxf(mx[3], __shfl_xor(mx[3], o));
    }
    const float m   = (head & 1) ? ((head & 2) ? mx[3] : mx[1]) : ((head & 2) ? mx[2] : mx[0]);
    const float adh = (head & 1) ? ((head & 2) ? ad.w : ad.y)   : ((head & 2) ? ad.z : ad.x);

    // pass 2: gather + exp + accumulate, 4-edge unroll, int4 index loads
    float ssum = 0.f;
    float a[8] = {0.f, 0.f, 0.f, 0.f, 0.f, 0.f, 0.f, 0.f};
    int p = beg;
#define LREL(l) ((l) >= 0.f ? (l) : 0.2f * (l))
#define ACC8(c, u) \
        a[0] = fmaf(c, bf_lo(u.x), a[0]); a[1] = fmaf(c, bf_hi(u.x), a[1]); \
        a[2] = fmaf(c, bf_lo(u.y), a[2]); a[3] = fmaf(c, bf_hi(u.y), a[3]); \
        a[4] = fmaf(c, bf_lo(u.z), a[4]); a[5] = fmaf(c, bf_hi(u.z), a[5]); \
        a[6] = fmaf(c, bf_lo(u.w), a[6]); a[7] = fmaf(c, bf_hi(u.w), a[7]);
    for (; p + 3 < end; p += 4) {
        int4 s4 = *(const int4*)(csr_src + p);   // bucket base 64-aligned -> p 4-aligned
        uint4 u0 = *(const uint4*)(h1 + (size_t)s4.x * F1 + lane * 8);
        uint4 u1 = *(const uint4*)(h1 + (size_t)s4.y * F1 + lane * 8);
        uint4 u2 = *(const uint4*)(h1 + (size_t)s4.z * F1 + lane * 8);
        uint4 u3 = *(const uint4*)(h1 + (size_t)s4.w * F1 + lane * 8);
        float c0 = expf(LREL(a_src[s4.x * 4 + head] + adh) - m);
        float c1 = expf(LREL(a_src[s4.y * 4 + head] + adh) - m);
        float c2 = expf(LREL(a_src[s4.z * 4 + head] + adh) - m);
        float c3 = expf(LREL(a_src[s4.w * 4 + head] + adh) - m);
        ssum += c0 + c1 + c2 + c3;
        ACC8(c0, u0) ACC8(c1, u1) ACC8(c2, u2) ACC8(c3, u3)
    }
    for (; p < end; p++) {
        int s0 = csr_src[p];
        uint4 u0 = *(const uint4*)(h1 + (size_t)s0 * F1 + lane * 8);
        float c0 = expf(LREL(a_src[s0 * 4 + head] + adh) - m);
        ssum += c0;
        ACC8(c0, u0)
    }
#undef ACC8
    const float inv = 1.0f / (ssum + 1e-16f);
    const int ch = lane * 8;
    float4 bA = *(const float4*)(b1 + ch);
    float4 bB = *(const float4*)(b1 + ch + 4);
    uint4 ov;
    ov.x = pack2(fmaxf(fmaf(a[0], inv, bA.x), 0.f), fmaxf(fmaf(a[1], inv, bA.y), 0.f));
    ov.y = pack2(fmaxf(fmaf(a[2], inv, bA.z), 0.f), fmaxf(fmaf(a[3], inv, bA.w), 0.f));
    ov.z = pack2(fmaxf(fmaf(a[4], inv, bB.x), 0.f), fmaxf(fmaf(a[5], inv, bB.y), 0.f));
    ov.w = pack2(fmaxf(fmaf(a[6], inv, bB.z), 0.f), fmaxf(fmaf(a[7], inv, bB.w), 0.f));
    *(uint4*)(g1 + (size_t)n * F1 + ch) = ov;
}

// ---------------- aggregation layer2 + final linear: one wave per node ------
__global__ __launch_bounds__(256) void k_agg2(
    const ushort_t* __restrict__ h2, const float* __restrict__ a_src, const float* __restrict__ a_dst,
    const int* __restrict__ cnt, const int* __restrict__ csr_src,
    const float* __restrict__ b2, const float* __restrict__ outW, const float* __restrict__ outb,
    float* __restrict__ out)
{
    const int n = blockIdx.x * 4 + (threadIdx.x >> 6);
    const int lane = threadIdx.x & 63;
    const int beg = n * CAP;
    const int end = beg + cnt[n];
    const float ad = a_dst[n];

    // pass 1: max
    float mx = -1e30f;
    for (int p = beg + lane; p < end; p += 64) {
        float v = a_src[csr_src[p]] + ad;
        v = v >= 0.f ? v : 0.2f * v;
        mx = fmaxf(mx, v);
    }
#pragma unroll
    for (int o = 32; o; o >>= 1) mx = fmaxf(mx, __shfl_xor(mx, o));

    // pass 2: 4-edge unroll, int4 index loads
    float ssum = 0.f;
    float a0 = 0.f, a1 = 0.f;
    int p = beg;
    for (; p + 3 < end; p += 4) {
        int4 s4 = *(const int4*)(csr_src + p);
        uint32_t u0 = *(const uint32_t*)(h2 + (size_t)s4.x * F2 + lane * 2);
        uint32_t u1 = *(const uint32_t*)(h2 + (size_t)s4.y * F2 + lane * 2);
        uint32_t u2 = *(const uint32_t*)(h2 + (size_t)s4.z * F2 + lane * 2);
        uint32_t u3 = *(const uint32_t*)(h2 + (size_t)s4.w * F2 + lane * 2);
        float c0 = expf(LREL(a_src[s4.x] + ad) - mx);
        float c1 = expf(LREL(a_src[s4.y] + ad) - mx);
        float c2 = expf(LREL(a_src[s4.z] + ad) - mx);
        float c3 = expf(LREL(a_src[s4.w] + ad) - mx);
        ssum += c0 + c1 + c2 + c3;
        a0 = fmaf(c0, bf_lo(u0), a0); a1 = fmaf(c0, bf_hi(u0), a1);
        a0 = fmaf(c1, bf_lo(u1), a0); a1 = fmaf(c1, bf_hi(u1), a1);
        a0 = fmaf(c2, bf_lo(u2), a0); a1 = fmaf(c2, bf_hi(u2), a1);
        a0 = fmaf(c3, bf_lo(u3), a0); a1 = fmaf(c3, bf_hi(u3), a1);
    }
    for (; p < end; p++) {
        int s0 = csr_src[p];
        uint32_t u0 = *(const uint32_t*)(h2 + (size_t)s0 * F2 + lane * 2);
        float c0 = expf(LREL(a_src[s0] + ad) - mx);
        ssum += c0;
        a0 = fmaf(c0, bf_lo(u0), a0); a1 = fmaf(c0, bf_hi(u0), a1);
    }
    const float inv = 1.0f / (ssum + 1e-16f);
    float v0 = fmaf(a0, inv, b2[lane * 2]);     v0 = v0 > 0.f ? v0 : 0.f;
    float v1 = fmaf(a1, inv, b2[lane * 2 + 1]); v1 = v1 > 0.f ? v1 : 0.f;
    float pr = v0 * outW[lane * 2] + v1 * outW[lane * 2 + 1];
    for (int o = 32; o; o >>= 1) pr += __shfl_xor(pr, o);
    if (lane == 0) out[n] = pr + outb[0];
}

// =======================================================================
extern "C" void kernel_launch(void* const* d_in, const int* in_sizes, int n_in,
                              void* d_out, int out_size, void* d_ws, size_t ws_size,
                              hipStream_t stream)
{
    const float* x        = (const float*)d_in[0];   // [NN, INCH]
    const float* cond     = (const float*)d_in[1];   // [NG, CONDCH]
    const float* W1       = (const float*)d_in[2];   // [INCH+CONDCH, F1]
    const float* att_src1 = (const float*)d_in[3];
    const float* att_dst1 = (const float*)d_in[4];
    const float* b1       = (const float*)d_in[5];
    const float* W2       = (const float*)d_in[6];   // [F1, F2]
    const float* att_src2 = (const float*)d_in[7];
    const float* att_dst2 = (const float*)d_in[8];
    const float* b2       = (const float*)d_in[9];
    const float* outW     = (const float*)d_in[10];
    const float* outb     = (const float*)d_in[11];
    const int*   ei       = (const int*)d_in[12];    // [2, NE]
    const int*   batch    = (const int*)d_in[13];    // [NN]
    float* out = (float*)d_out;

    // ---- workspace layout ----
    char* ws = (char*)d_ws;
    size_t off = 0;
    auto alloc = [&](size_t bytes) { void* p = ws + off; off += (bytes + 255) & ~size_t(255); return p; };
    ushort_t* xb      = (ushort_t*)alloc((size_t)MPAD * INCH * 2);    // 77.1 MB (aliased by g1b)
    ushort_t* condb   = (ushort_t*)alloc((size_t)NG * CONDCH * 2);
    ushort_t* W1aT    = (ushort_t*)alloc((size_t)F1 * INCH * 2);      // [512][768]
    ushort_t* W1cT    = (ushort_t*)alloc((size_t)F1 * CONDCH * 2);    // [512][768]
    ushort_t* W2T     = (ushort_t*)alloc((size_t)F2 * F1 * 2);        // [128][512]
    float*    C2      = (float*)alloc((size_t)NG * F1 * 4);           // [128][512]
    ushort_t* h1b     = (ushort_t*)alloc((size_t)NN * F1 * 2);        // 51.2 MB
    float*    a_src1  = (float*)alloc((size_t)NN * NHEAD * 4);
    float*    a_dst1  = (float*)alloc((size_t)NN * NHEAD * 4);
    int*      cursor  = (int*)alloc((size_t)NN * 4);
    int*      csr_src = (int*)alloc((size_t)NN * CAP * 4);            // 12.8 MB buckets
    ushort_t* h2b     = (ushort_t*)alloc((size_t)NN * F2 * 2);        // 12.8 MB
    float*    a_src2  = (float*)alloc((size_t)NN * 4);
    float*    a_dst2  = (float*)alloc((size_t)NN * 4);
    ushort_t* g1b     = xb;   // alias: xb dead after GEMM1; g1b written in agg1
    (void)ws_size;

    // ---- prep: cond cvt + weight transposes + bucket seed (cursor=1, self loop) ----
    k_prep<<<(R3 + 255) / 256, 256, 0, stream>>>(W1, W2, cond, W1aT, W1cT, W2T, condb,
                                                 cursor, csr_src);

    // ---- edge scatter (standalone; atomics no longer throttle the convert) ----
    k_scat<<<(NE + 255) / 256, 256, 0, stream>>>(ei, cursor, csr_src);

    // ---- x -> bf16 pure streaming convert, 8 elems/thread ----
    {
        long n8 = (long)NN * INCH / 8;
        k_cvt8<<<(int)((n8 + 255) / 256), 256, 0, stream>>>(x, xb, n8);
    }

    // ---- C2 = cond @ W1c  -> f32 [128][512] ----
    k_mgemm<128, false, false, false><<<4, 256, 0, stream>>>(
        condb, W1cT, C2, NG, F1, CONDCH, 4,
        nullptr, nullptr, nullptr, nullptr, nullptr, nullptr, 0);
    // ---- h1 = bf16( x @ W1a + C2[batch] ), fused att1 logits ----
    k_mgemm<256, true, true, true><<<(MPAD / 256) * 4, 512, 0, stream>>>(
        xb, W1aT, h1b, NN, F1, INCH, 4,
        C2, batch, att_src1, att_dst1, a_src1, a_dst1, NHEAD);
    // ---- aggregate layer1 (in-kernel softmax, +b1, relu) -> g1 bf16 ----
    k_agg1<<<NN / 4, 256, 0, stream>>>(h1b, a_src1, a_dst1, cursor, csr_src, b1, g1b);
    // ---- h2 = bf16( g1 @ W2 ), fused att2 logits ----
    k_mgemm<128, false, true, true><<<MPAD / 128, 256, 0, stream>>>(
        g1b, W2T, h2b, NN, F2, F1, 1,
        nullptr, nullptr, att_src2, att_dst2, a_src2, a_dst2, 1);
    // ---- aggregate layer2 (in-kernel softmax) + final linear -> out ----
    k_agg2<<<NN / 4, 256, 0, stream>>>(h2b, a_src2, a_dst2, cursor, csr_src, b2, outW, outb, out);
}

// Round 13
// 276.032 us; speedup vs baseline: 5.7994x; 1.0054x over previous
//
#include <hip/hip_runtime.h>
#include <hip/hip_bf16.h>
#include <cstdint>
#include <cstddef>

#define NN 50000        // nodes
#define NE 400000       // edges (without self loops)
#define NG 128          // graphs
#define INCH 768
#define CONDCH 768
#define HIDD 128
#define NHEAD 4
#define F1 (NHEAD * HIDD)   // 512
#define F2 HIDD             // 128
#define MPAD 50176          // 196 * 256
#define CAP 64              // per-node edge bucket capacity (deg ~ Poisson(8))

typedef unsigned short ushort_t;
typedef float f32x4 __attribute__((ext_vector_type(4)));
typedef __bf16 bf16x8 __attribute__((ext_vector_type(8)));

typedef const void __attribute__((address_space(1))) as1_void;
typedef void __attribute__((address_space(3))) as3_void;

__device__ __forceinline__ void gload_lds16(const void* g, void* l) {
    __builtin_amdgcn_global_load_lds((as1_void*)g, (as3_void*)l, 16, 0, 0);
}

__device__ __forceinline__ ushort_t f2bf(float f) {
    uint32_t u = __float_as_uint(f);
    uint32_t r = (u + 0x7fffu + ((u >> 16) & 1u)) >> 16;
    return (ushort_t)r;
}
__device__ __forceinline__ uint32_t pack2(float a, float b) {
    return (uint32_t)f2bf(a) | ((uint32_t)f2bf(b) << 16);
}
__device__ __forceinline__ float bf_lo(uint32_t u) { return __uint_as_float(u << 16); }
__device__ __forceinline__ float bf_hi(uint32_t u) { return __uint_as_float(u & 0xffff0000u); }

// ---------------- k_prep: cond->bf16, weight transposes, bucket seed ------------
#define R1 (F1 * INCH)
#define R2 (R1 + F1 * CONDCH)
#define R3 (R2 + F2 * F1)
#define CND4 (NG * CONDCH / 4)
__global__ __launch_bounds__(256) void k_prep(
    const float* __restrict__ W1, const float* __restrict__ W2, const float* __restrict__ cond,
    ushort_t* __restrict__ W1aT, ushort_t* __restrict__ W1cT, ushort_t* __restrict__ W2T,
    ushort_t* __restrict__ condb, int* __restrict__ cursor, int* __restrict__ csr_src)
{
    int idx = blockIdx.x * blockDim.x + threadIdx.x;
    if (idx < NN) {
        cursor[idx] = 1;                       // self-loop pre-seeded
        csr_src[(size_t)idx * CAP] = idx;
    }
    if (idx < CND4) {
        float4 v = *(const float4*)(cond + (size_t)idx * 4);
        ushort4 o;
        o.x = f2bf(v.x); o.y = f2bf(v.y); o.z = f2bf(v.z); o.w = f2bf(v.w);
        *(ushort4*)(condb + (size_t)idx * 4) = o;
    }
    if (idx >= R3) return;
    if (idx < R1) {
        int n = idx / INCH, k = idx % INCH;
        W1aT[idx] = f2bf(W1[(size_t)k * F1 + n]);
    } else if (idx < R2) {
        int j = idx - R1;
        int n = j / CONDCH, k = j % CONDCH;
        W1cT[j] = f2bf(W1[(size_t)(INCH + k) * F1 + n]);
    } else {
        int j = idx - R2;
        int n = j / F1, k = j % F1;
        W2T[j] = f2bf(W2[(size_t)k * F2 + n]);
    }
}

// ---------------- edge scatter into buckets -----------------------
__global__ __launch_bounds__(256) void k_scat(const int* __restrict__ ei,
                                              int* __restrict__ cursor,
                                              int* __restrict__ csr_src) {
    int e = blockIdx.x * blockDim.x + threadIdx.x;
    if (e >= NE) return;
    int src = ei[e];
    int dst = ei[NE + e];
    int pos = atomicAdd(&cursor[dst], 1);
    csr_src[(size_t)dst * CAP + pos] = src;
}

// ---------------- bf16 MFMA GEMM, optional raw-f32 A staging --------------------
// C[M,N] = A @ BT^T (+G[gidx[m],:]).  TM x 128 tile, double-buffered LDS,
// 1 barrier per K-step: { vmcnt(0); s_barrier; STAGE(t+1->buf^1); compute buf }.
// A_F32: A staged as raw f32 via global_load_lds, 4 issues x (TM/4 rows) each
// (each issue stages threads*16B = TM/4 rows of 128B), both-sides XOR chunk
// swizzle (source chunk = (t&7)^(rowInIss&7); read chunk ^= row&7), converted
// to bf16 in-register at fragment-read time. No conversion pass needed.
// 1-D grid, XCD-chunked bijective swizzle, n-fast ordering.
// FUSE_ATT: per-row dots with attS/attD -> aS/aD[m*attStride + by].
template <int TM, bool A_F32, bool ADD_GATHER, bool OUT_BF16, bool FUSE_ATT>
__global__ __launch_bounds__(TM * 2, 4) void k_mgemm(
    const ushort_t* __restrict__ A, const float* __restrict__ Af, int Arowmax,
    const ushort_t* __restrict__ BT, void* __restrict__ Cv,
    int M, int N, int K, int nBN,
    const float* __restrict__ G, const int* __restrict__ gidx,
    const float* __restrict__ attS, const float* __restrict__ attD,
    float* __restrict__ aS, float* __restrict__ aD, int attStride)
{
    constexpr int SAB = A_F32 ? TM * 128 : TM * 64;  // bytes per A buffer
    constexpr int SB = 8192;                          // bytes per B buffer
    constexpr int ISS_BYTES = TM * 32;                // f32: LDS bytes per issue
    __shared__ __align__(16) char smem[2 * SAB + 2 * SB];
    char* sA = smem;
    char* sB = smem + 2 * SAB;

    const int nwg = gridDim.x;
    const int orig = blockIdx.x;
    const int q = nwg >> 3, r = nwg & 7;
    const int xcd = orig & 7, sid = orig >> 3;
    const int wg = (xcd < r ? xcd * (q + 1) : r * (q + 1) + (xcd - r) * q) + sid;
    const int bx = wg / nBN, by = wg % nBN;

    const int tid = threadIdx.x;
    const int lane = tid & 63;
    const int wave = tid >> 6;
    const int wr = wave >> 1, wc = wave & 1;
    const int m0 = bx * TM, n0 = by * 128;

    // bf16 staging: thread t covers row t>>2, 16B chunk (t&3)*8 elems
    const int sr = tid >> 2;
    const int sc = (tid & 3) * 8;
    const ushort_t* gA = A_F32 ? nullptr : (A + (size_t)(m0 + sr) * K + sc);
    const ushort_t* gB = BT + (size_t)(n0 + sr) * K + sc;
    const int ldsw = wave * 1024;

    // f32 A staging: 4 issues, issue j covers rows [j*(TM/4), (j+1)*(TM/4));
    // thread t -> rowInIss = t>>3 (0..TM/4-1), source chunk pre-swizzled.
    const float* gAf_base[4];
    if constexpr (A_F32) {
        const int rowInIss = tid >> 3;                      // 0..TM/4-1
        const int chunkS = (tid & 7) ^ (rowInIss & 7);      // both-sides swizzle
#pragma unroll
        for (int j = 0; j < 4; j++) {
            int rr = m0 + j * (TM / 4) + rowInIss;
            if (rr > Arowmax) rr = Arowmax;
            gAf_base[j] = Af + (size_t)rr * K + chunkS * 4;
        }
    }

    const int a_off = (wr * 64 + (lane & 15)) * 64 + (lane >> 4) * 16;
    const int b_off = (wc * 64 + (lane & 15)) * 64 + (lane >> 4) * 16;

    auto STAGE = [&](int kt, int b) {
        if constexpr (A_F32) {
#pragma unroll
            for (int j = 0; j < 4; j++)
                gload_lds16(gAf_base[j] + kt, sA + b * SAB + j * ISS_BYTES + ldsw);
        } else {
            char* dA = sA + b * SAB + ldsw;
            gload_lds16(gA + kt, dA);
            gload_lds16(gA + (size_t)(TM / 2) * K + kt, dA + SAB / 2);
        }
        char* dB = sB + b * SB + ldsw;
        gload_lds16(gB + kt, dB);
        if (TM == 128)
            gload_lds16(gB + (size_t)64 * K + kt, dB + 4096);
    };

    f32x4 acc[4][4];
#pragma unroll
    for (int i = 0; i < 4; i++)
#pragma unroll
        for (int j = 0; j < 4; j++) acc[i][j] = 0.f;

    STAGE(0, 0);
    const int nt = K / 32;   // even for K in {768, 512}
    for (int t = 0; t < nt; t++) {
        const int cur = t & 1;
        asm volatile("s_waitcnt vmcnt(0)" ::: "memory");   // stage(t) landed
        __builtin_amdgcn_s_barrier();
        __builtin_amdgcn_sched_barrier(0);
        if (t + 1 < nt) STAGE((t + 1) * 32, cur ^ 1);      // in flight across compute
        bf16x8 af[4], bfr[4];
        if constexpr (A_F32) {
            const int q32 = (lane >> 4) * 32;
#pragma unroll
            for (int i = 0; i < 4; i++) {
                int rw = wr * 64 + i * 16 + (lane & 15);
                int sw = (rw & 7) << 4;
                const char* base = sA + cur * SAB + rw * 128;
                float4 lo = *(const float4*)(base + (q32 ^ sw));
                float4 hi = *(const float4*)(base + ((q32 + 16) ^ sw));
                bf16x8 v;
                v[0] = (__bf16)lo.x; v[1] = (__bf16)lo.y; v[2] = (__bf16)lo.z; v[3] = (__bf16)lo.w;
                v[4] = (__bf16)hi.x; v[5] = (__bf16)hi.y; v[6] = (__bf16)hi.z; v[7] = (__bf16)hi.w;
                af[i] = v;
            }
        } else {
#pragma unroll
            for (int i = 0; i < 4; i++) af[i] = *(const bf16x8*)(sA + cur * SAB + a_off + i * 1024);
        }
#pragma unroll
        for (int j = 0; j < 4; j++) bfr[j] = *(const bf16x8*)(sB + cur * SB + b_off + j * 1024);
#pragma unroll
        for (int i = 0; i < 4; i++)
#pragma unroll
            for (int j = 0; j < 4; j++)
                acc[i][j] = __builtin_amdgcn_mfma_f32_16x16x32_bf16(af[i], bfr[j], acc[i][j], 0, 0, 0);
    }
    // nt even => last compute read buffer 1; epilogue reuses buffer-0 region.

    float asv[4], adv[4];
    if (FUSE_ATT) {
#pragma unroll
        for (int j = 0; j < 4; j++) {
            int col = wc * 64 + j * 16 + (lane & 15);
            asv[j] = attS[by * 128 + col];
            adv[j] = attD[by * 128 + col];
        }
    }
    float* redS = (float*)smem;              // [2(wc)][TM]  (buffer-0 region)
    float* redD = (float*)smem + 2 * TM;

#pragma unroll
    for (int i = 0; i < 4; i++) {
        int mbase = m0 + wr * 64 + i * 16 + (lane >> 4) * 4;
#pragma unroll
        for (int rr = 0; rr < 4; rr++) {
            int m = mbase + rr;
            if (m >= M) continue;
            const float* grow = nullptr;
            if (ADD_GATHER) grow = G + (size_t)gidx[m] * N;
            float vs = 0.f, vd = 0.f;
#pragma unroll
            for (int j = 0; j < 4; j++) {
                int n = n0 + wc * 64 + j * 16 + (lane & 15);
                float v = acc[i][j][rr];
                if (ADD_GATHER) v += grow[n];
                if (OUT_BF16) ((ushort_t*)Cv)[(size_t)m * N + n] = f2bf(v);
                else          ((float*)Cv)[(size_t)m * N + n] = v;
                if (FUSE_ATT) { vs = fmaf(v, asv[j], vs); vd = fmaf(v, adv[j], vd); }
            }
            if (FUSE_ATT) {
#pragma unroll
                for (int o = 1; o < 16; o <<= 1) { vs += __shfl_xor(vs, o); vd += __shfl_xor(vd, o); }
                if ((lane & 15) == 0) {
                    int mloc = wr * 64 + i * 16 + (lane >> 4) * 4 + rr;
                    redS[wc * TM + mloc] = vs;
                    redD[wc * TM + mloc] = vd;
                }
            }
        }
    }
    if (FUSE_ATT) {
        __syncthreads();
        int sd = tid >= TM ? 1 : 0, mloc = tid & (TM - 1);
        int m = m0 + mloc;
        if (m < M) {
            const float* rb = sd ? redD : redS;
            float v = rb[mloc] + rb[TM + mloc];
            (sd ? aD : aS)[(size_t)m * attStride + by] = v;
        }
    }
}

// ---------------- aggregation layer1: one wave per node, in-kernel softmax ------
__global__ __launch_bounds__(256) void k_agg1(
    const ushort_t* __restrict__ h1, const float* __restrict__ a_src, const float* __restrict__ a_dst,
    const int* __restrict__ cnt, const int* __restrict__ csr_src,
    const float* __restrict__ b1, ushort_t* __restrict__ g1)
{
    const int n = blockIdx.x * 4 + (threadIdx.x >> 6);
    const int lane = threadIdx.x & 63;
    const int head = lane >> 4;
    const int beg = n * CAP;
    const int end = beg + cnt[n];
    const float4 ad = *(const float4*)(a_dst + (size_t)n * 4);

    // pass 1: per-head max (lanes parallel; deg<=CAP=64 -> single iteration)
    float mx[4] = {-1e30f, -1e30f, -1e30f, -1e30f};
    for (int p = beg + lane; p < end; p += 64) {
        int src = csr_src[p];
        float4 as = *(const float4*)(a_src + (size_t)src * 4);
        float v;
        v = as.x + ad.x; v = v >= 0.f ? v : 0.2f * v; mx[0] = fmaxf(mx[0], v);
        v = as.y + ad.y; v = v >= 0.f ? v : 0.2f * v; mx[1] = fmaxf(mx[1], v);
        v = as.z + ad.z; v = v >= 0.f ? v : 0.2f * v; mx[2] = fmaxf(mx[2], v);
        v = as.w + ad.w; v = v >= 0.f ? v : 0.2f * v; mx[3] = fmaxf(mx[3], v);
    }
#pragma unroll
    for (int o = 32; o; o >>= 1) {
        mx[0] = fmaxf(mx[0], __shfl_xor(mx[0], o));
        mx[1] = fmaxf(mx[1], __shfl_xor(mx[1], o));
        mx[2] = fmaxf(mx[2], __shfl_xor(mx[2], o));
        mx[3] = fmaxf(mx[3], __shfl_xor(mx[3], o));
    }
    const float m   = (head & 1) ? ((head & 2) ? mx[3] : mx[1]) : ((head & 2) ? mx[2] : mx[0]);
    const float adh = (head & 1) ? ((head & 2) ? ad.w : ad.y)   : ((head & 2) ? ad.z : ad.x);

    // pass 2: gather + exp + accumulate, 4-edge unroll, int4 index loads
    float ssum = 0.f;
    float a[8] = {0.f, 0.f, 0.f, 0.f, 0.f, 0.f, 0.f, 0.f};
    int p = beg;
#define LREL(l) ((l) >= 0.f ? (l) : 0.2f * (l))
#define ACC8(c, u) \
        a[0] = fmaf(c, bf_lo(u.x), a[0]); a[1] = fmaf(c, bf_hi(u.x), a[1]); \
        a[2] = fmaf(c, bf_lo(u.y), a[2]); a[3] = fmaf(c, bf_hi(u.y), a[3]); \
        a[4] = fmaf(c, bf_lo(u.z), a[4]); a[5] = fmaf(c, bf_hi(u.z), a[5]); \
        a[6] = fmaf(c, bf_lo(u.w), a[6]); a[7] = fmaf(c, bf_hi(u.w), a[7]);
    for (; p + 3 < end; p += 4) {
        int4 s4 = *(const int4*)(csr_src + p);   // bucket base 64-aligned -> p 4-aligned
        uint4 u0 = *(const uint4*)(h1 + (size_t)s4.x * F1 + lane * 8);
        uint4 u1 = *(const uint4*)(h1 + (size_t)s4.y * F1 + lane * 8);
        uint4 u2 = *(const uint4*)(h1 + (size_t)s4.z * F1 + lane * 8);
        uint4 u3 = *(const uint4*)(h1 + (size_t)s4.w * F1 + lane * 8);
        float c0 = expf(LREL(a_src[s4.x * 4 + head] + adh) - m);
        float c1 = expf(LREL(a_src[s4.y * 4 + head] + adh) - m);
        float c2 = expf(LREL(a_src[s4.z * 4 + head] + adh) - m);
        float c3 = expf(LREL(a_src[s4.w * 4 + head] + adh) - m);
        ssum += c0 + c1 + c2 + c3;
        ACC8(c0, u0) ACC8(c1, u1) ACC8(c2, u2) ACC8(c3, u3)
    }
    for (; p < end; p++) {
        int s0 = csr_src[p];
        uint4 u0 = *(const uint4*)(h1 + (size_t)s0 * F1 + lane * 8);
        float c0 = expf(LREL(a_src[s0 * 4 + head] + adh) - m);
        ssum += c0;
        ACC8(c0, u0)
    }
#undef ACC8
    const float inv = 1.0f / (ssum + 1e-16f);
    const int ch = lane * 8;
    float4 bA = *(const float4*)(b1 + ch);
    float4 bB = *(const float4*)(b1 + ch + 4);
    uint4 ov;
    ov.x = pack2(fmaxf(fmaf(a[0], inv, bA.x), 0.f), fmaxf(fmaf(a[1], inv, bA.y), 0.f));
    ov.y = pack2(fmaxf(fmaf(a[2], inv, bA.z), 0.f), fmaxf(fmaf(a[3], inv, bA.w), 0.f));
    ov.z = pack2(fmaxf(fmaf(a[4], inv, bB.x), 0.f), fmaxf(fmaf(a[5], inv, bB.y), 0.f));
    ov.w = pack2(fmaxf(fmaf(a[6], inv, bB.z), 0.f), fmaxf(fmaf(a[7], inv, bB.w), 0.f));
    *(uint4*)(g1 + (size_t)n * F1 + ch) = ov;
}

// ---------------- aggregation layer2 + final linear: one wave per node ------
__global__ __launch_bounds__(256) void k_agg2(
    const ushort_t* __restrict__ h2, const float* __restrict__ a_src, const float* __restrict__ a_dst,
    const int* __restrict__ cnt, const int* __restrict__ csr_src,
    const float* __restrict__ b2, const float* __restrict__ outW, const float* __restrict__ outb,
    float* __restrict__ out)
{
    const int n = blockIdx.x * 4 + (threadIdx.x >> 6);
    const int lane = threadIdx.x & 63;
    const int beg = n * CAP;
    const int end = beg + cnt[n];
    const float ad = a_dst[n];

    // pass 1: max
    float mx = -1e30f;
    for (int p = beg + lane; p < end; p += 64) {
        float v = a_src[csr_src[p]] + ad;
        v = v >= 0.f ? v : 0.2f * v;
        mx = fmaxf(mx, v);
    }
#pragma unroll
    for (int o = 32; o; o >>= 1) mx = fmaxf(mx, __shfl_xor(mx, o));

    // pass 2: 4-edge unroll, int4 index loads
    float ssum = 0.f;
    float a0 = 0.f, a1 = 0.f;
    int p = beg;
    for (; p + 3 < end; p += 4) {
        int4 s4 = *(const int4*)(csr_src + p);
        uint32_t u0 = *(const uint32_t*)(h2 + (size_t)s4.x * F2 + lane * 2);
        uint32_t u1 = *(const uint32_t*)(h2 + (size_t)s4.y * F2 + lane * 2);
        uint32_t u2 = *(const uint32_t*)(h2 + (size_t)s4.z * F2 + lane * 2);
        uint32_t u3 = *(const uint32_t*)(h2 + (size_t)s4.w * F2 + lane * 2);
        float c0 = expf(LREL(a_src[s4.x] + ad) - mx);
        float c1 = expf(LREL(a_src[s4.y] + ad) - mx);
        float c2 = expf(LREL(a_src[s4.z] + ad) - mx);
        float c3 = expf(LREL(a_src[s4.w] + ad) - mx);
        ssum += c0 + c1 + c2 + c3;
        a0 = fmaf(c0, bf_lo(u0), a0); a1 = fmaf(c0, bf_hi(u0), a1);
        a0 = fmaf(c1, bf_lo(u1), a0); a1 = fmaf(c1, bf_hi(u1), a1);
        a0 = fmaf(c2, bf_lo(u2), a0); a1 = fmaf(c2, bf_hi(u2), a1);
        a0 = fmaf(c3, bf_lo(u3), a0); a1 = fmaf(c3, bf_hi(u3), a1);
    }
    for (; p < end; p++) {
        int s0 = csr_src[p];
        uint32_t u0 = *(const uint32_t*)(h2 + (size_t)s0 * F2 + lane * 2);
        float c0 = expf(LREL(a_src[s0] + ad) - mx);
        ssum += c0;
        a0 = fmaf(c0, bf_lo(u0), a0); a1 = fmaf(c0, bf_hi(u0), a1);
    }
    const float inv = 1.0f / (ssum + 1e-16f);
    float v0 = fmaf(a0, inv, b2[lane * 2]);     v0 = v0 > 0.f ? v0 : 0.f;
    float v1 = fmaf(a1, inv, b2[lane * 2 + 1]); v1 = v1 > 0.f ? v1 : 0.f;
    float pr = v0 * outW[lane * 2] + v1 * outW[lane * 2 + 1];
    for (int o = 32; o; o >>= 1) pr += __shfl_xor(pr, o);
    if (lane == 0) out[n] = pr + outb[0];
}

// =======================================================================
extern "C" void kernel_launch(void* const* d_in, const int* in_sizes, int n_in,
                              void* d_out, int out_size, void* d_ws, size_t ws_size,
                              hipStream_t stream)
{
    const float* x        = (const float*)d_in[0];   // [NN, INCH]
    const float* cond     = (const float*)d_in[1];   // [NG, CONDCH]
    const float* W1       = (const float*)d_in[2];   // [INCH+CONDCH, F1]
    const float* att_src1 = (const float*)d_in[3];
    const float* att_dst1 = (const float*)d_in[4];
    const float* b1       = (const float*)d_in[5];
    const float* W2       = (const float*)d_in[6];   // [F1, F2]
    const float* att_src2 = (const float*)d_in[7];
    const float* att_dst2 = (const float*)d_in[8];
    const float* b2       = (const float*)d_in[9];
    const float* outW     = (const float*)d_in[10];
    const float* outb     = (const float*)d_in[11];
    const int*   ei       = (const int*)d_in[12];    // [2, NE]
    const int*   batch    = (const int*)d_in[13];    // [NN]
    float* out = (float*)d_out;

    // ---- workspace layout ----
    char* ws = (char*)d_ws;
    size_t off = 0;
    auto alloc = [&](size_t bytes) { void* p = ws + off; off += (bytes + 255) & ~size_t(255); return p; };
    ushort_t* condb   = (ushort_t*)alloc((size_t)NG * CONDCH * 2);
    ushort_t* W1aT    = (ushort_t*)alloc((size_t)F1 * INCH * 2);      // [512][768]
    ushort_t* W1cT    = (ushort_t*)alloc((size_t)F1 * CONDCH * 2);    // [512][768]
    ushort_t* W2T     = (ushort_t*)alloc((size_t)F2 * F1 * 2);        // [128][512]
    float*    C2      = (float*)alloc((size_t)NG * F1 * 4);           // [128][512]
    ushort_t* h1b     = (ushort_t*)alloc((size_t)NN * F1 * 2);        // 51.2 MB
    float*    a_src1  = (float*)alloc((size_t)NN * NHEAD * 4);
    float*    a_dst1  = (float*)alloc((size_t)NN * NHEAD * 4);
    int*      cursor  = (int*)alloc((size_t)NN * 4);
    int*      csr_src = (int*)alloc((size_t)NN * CAP * 4);            // 12.8 MB buckets
    ushort_t* g1b     = (ushort_t*)alloc((size_t)MPAD * F1 * 2);      // 51.4 MB
    ushort_t* h2b     = (ushort_t*)alloc((size_t)NN * F2 * 2);        // 12.8 MB
    float*    a_src2  = (float*)alloc((size_t)NN * 4);
    float*    a_dst2  = (float*)alloc((size_t)NN * 4);
    (void)ws_size;

    // ---- prep: cond cvt + weight transposes + bucket seed (cursor=1, self loop) ----
    k_prep<<<(R3 + 255) / 256, 256, 0, stream>>>(W1, W2, cond, W1aT, W1cT, W2T, condb,
                                                 cursor, csr_src);

    // ---- edge scatter ----
    k_scat<<<(NE + 255) / 256, 256, 0, stream>>>(ei, cursor, csr_src);

    // ---- C2 = cond @ W1c  -> f32 [128][512]  (proven bf16 path) ----
    k_mgemm<128, false, false, false, false><<<4, 256, 0, stream>>>(
        condb, nullptr, 0, W1cT, C2, NG, F1, CONDCH, 4,
        nullptr, nullptr, nullptr, nullptr, nullptr, nullptr, 0);
    // ---- h1 = bf16( x @ W1a + C2[batch] ), fused att1 logits; x staged raw f32 ----
    k_mgemm<256, true, true, true, true><<<(MPAD / 256) * 4, 512, 0, stream>>>(
        nullptr, x, NN - 1, W1aT, h1b, NN, F1, INCH, 4,
        C2, batch, att_src1, att_dst1, a_src1, a_dst1, NHEAD);
    // ---- aggregate layer1 (in-kernel softmax, +b1, relu) -> g1 bf16 ----
    k_agg1<<<NN / 4, 256, 0, stream>>>(h1b, a_src1, a_dst1, cursor, csr_src, b1, g1b);
    // ---- h2 = bf16( g1 @ W2 ), fused att2 logits ----
    k_mgemm<128, false, false, true, true><<<MPAD / 128, 256, 0, stream>>>(
        g1b, nullptr, 0, W2T, h2b, NN, F2, F1, 1,
        nullptr, nullptr, att_src2, att_dst2, a_src2, a_dst2, 1);
    // ---- aggregate layer2 (in-kernel softmax) + final linear -> out ----
    k_agg2<<<NN / 4, 256, 0, stream>>>(h2b, a_src2, a_dst2, cursor, csr_src, b2, outW, outb, out);
}